// Round 3
// baseline (997.681 us; speedup 1.0000x reference)
//
#include <hip/hip_runtime.h>
#include <math.h>

#define TT 150
#define BB 64
#define DD 2000
#define SS 3000
#define EE 100000
#define EEPAD 124160   // >= EE + SS*7 (arcs padded per-state to multiple of 8)
#define RESC 16
#define NSLOT 9
#define RESCC 0x1p-46f // exact pow2 rescale every 16 steps (growth ~7.42^16 ~= 2^46.3)

#define NT 1024        // threads per block (16 waves)
#define NBLK 256       // 1 block per CU
#define NG 32          // groups, 2 batch lanes each
#define GB 8           // blocks per group (same XCD iff bid%8 maps to XCD)
#define CAP 14336      // LDS arc slots per block (max slice ~13.9k)
#define ASTRD 3072     // dwords per alpha buffer per group (SS=3000 padded)
#define NSTMAX 2048
#define FLGSTR 32      // dwords between flags (128 B)
#define NEXB 32

// dynamic LDS layout (bytes). Alpha table at byte 0 so the gather's
// ds_read address is just (idx & 0xFFFF); ex base 12288 folds into the
// ds_read offset immediate.
#define OFF_ALPHA  0                 // SS*4 -> 12288 (packed 2xbf16 per state)
#define OFF_EX     12288             // DD*4 -> 8192  (packed 2xbf16 per pdf)
#define OFF_ARC    20480             // CAP*8 = 114688
#define OFF_RBP    135168            // (NSTMAX+1)*4 -> 8208
#define OFF_RED    143376            // 256*4 = 1024
#define OFF_SH     144400            // 16
#define OFF_LSP    144416            // (GB+1)*4 = 36 -> pad 48
#define DYNLDS     144464

// idx = (from<<2) | (pdf<<18): both halves are ready-made BYTE offsets into
// the packed-u32 LDS tables (from*4 <= 11996 fits 14 bits; pdf*4 <= 7996).
struct __align__(8) ArcT2 { unsigned idx; float ew; };

__device__ inline float b2f(unsigned short u) {
    union { unsigned u32; float f; } x; x.u32 = ((unsigned)u) << 16; return x.f;
}
__device__ inline unsigned short f2b(float f) {
    union { float f; unsigned u; } x; x.f = f;
    unsigned r = x.u + 0x7FFF + ((x.u >> 16) & 1);       // RNE, positive finite only
    return (unsigned short)(r >> 16);
}
__device__ inline float u2f(unsigned u) {
    union { unsigned u32; float f; } x; x.u32 = u; return x.f;
}

// ---------------- setup kernels ----------------
__global__ void k_init0(int* __restrict__ counts, unsigned* __restrict__ flags,
                        float* __restrict__ partial)
{
    int i = blockIdx.x * blockDim.x + threadIdx.x;
    if (i < SS) counts[i] = 0;
    if (i < 2 * NBLK * FLGSTR) flags[i] = 0u;
    if (i < NG * 2) partial[i] = 0.f;
}

__global__ void k_zeroarcs(ArcT2* __restrict__ arcs)
{
    int i = blockIdx.x * blockDim.x + threadIdx.x;
    if (i < EEPAD) { ArcT2 z; z.idx = 0; z.ew = 0.f; arcs[i] = z; }
}

__global__ void k_hist(const int* __restrict__ to_state, int* __restrict__ counts)
{
    int e = blockIdx.x * blockDim.x + threadIdx.x;
    if (e < EE) atomicAdd(&counts[to_state[e]], 1);
}

// prefix over counts padded to multiple of 8
__global__ void k_scan(const int* __restrict__ counts, int* __restrict__ rp,
                       int* __restrict__ cur)
{
    __shared__ int ls[1024];
    int tid = threadIdx.x;
    int s0 = tid * 3;
    int a0 = (s0 + 0 < SS) ? ((counts[s0 + 0] + 7) & ~7) : 0;
    int a1 = (s0 + 1 < SS) ? ((counts[s0 + 1] + 7) & ~7) : 0;
    int a2 = (s0 + 2 < SS) ? ((counts[s0 + 2] + 7) & ~7) : 0;
    int tsum = a0 + a1 + a2;
    ls[tid] = tsum;
    __syncthreads();
    for (int off = 1; off < 1024; off <<= 1) {
        int v = ls[tid];
        int add = (tid >= off) ? ls[tid - off] : 0;
        __syncthreads();
        ls[tid] = v + add;
        __syncthreads();
    }
    int excl = ls[tid] - tsum;
    if (s0 + 0 < SS) { rp[s0 + 0] = excl; cur[s0 + 0] = excl; }
    excl += a0;
    if (s0 + 1 < SS) { rp[s0 + 1] = excl; cur[s0 + 1] = excl; }
    excl += a1;
    if (s0 + 2 < SS) { rp[s0 + 2] = excl; cur[s0 + 2] = excl; }
    if (tid == 1023) rp[SS] = ls[1023];
}

// arc-balanced split into GB slices
__global__ void k_split(const int* __restrict__ rp, int* __restrict__ split)
{
    int j = threadIdx.x;
    if (j > GB) return;
    if (j == 0)  { split[0] = 0; return; }
    if (j == GB) { split[GB] = SS; return; }
    long long total = rp[SS];
    int target = (int)((total * j) / GB);
    int lo = 0, hi = SS;
    while (lo < hi) { int mid = (lo + hi) >> 1; if (rp[mid] >= target) hi = mid; else lo = mid + 1; }
    split[j] = lo;
}

__global__ void k_scatter(const int* __restrict__ from_state, const int* __restrict__ to_state,
                          const int* __restrict__ pdf_id, const float* __restrict__ trans_logw,
                          int* __restrict__ cur, ArcT2* __restrict__ arcs)
{
    int e = blockIdx.x * blockDim.x + threadIdx.x;
    if (e >= EE) return;
    int s = to_state[e];
    int pos = atomicAdd(&cur[s], 1);
    ArcT2 a;
    a.idx = ((unsigned)from_state[e] << 2) | ((unsigned)pdf_id[e] << 18);
    a.ew = __expf(trans_logw[e]);
    arcs[pos] = a;
}

// Bank-aware in-place reorder: within each state, put arcs with
// from%8 == position%8 at matching positions. Pure permutation of a
// commutative sum -> correctness-neutral. One wave per state.
__global__ void k_sortbank(const int* __restrict__ rp, const int* __restrict__ counts,
                           ArcT2* __restrict__ arcs)
{
    int w = (blockIdx.x * blockDim.x + threadIdx.x) >> 6;
    int lane = threadIdx.x & 63;
    if (w >= SS) return;
    int n = counts[w];
    if (n < 2 || n > 64) return;
    int base = rp[w];
    bool valid = (lane < n);
    ArcT2 a;
    a.idx = 0; a.ew = 0.f;
    if (valid) a = arcs[base + lane];
    int c = valid ? (int)((a.idx >> 2) & 7) : -1;
    unsigned long long below = (1ull << lane) - 1ull;
    int ncArr[8];
    int myrank = 0;
    #pragma unroll
    for (int c8 = 0; c8 < 8; ++c8) {
        unsigned long long m = __ballot(valid && (c == c8));
        ncArr[c8] = (int)__popcll(m);
        if (c == c8) myrank = (int)__popcll(m & below);
    }
    int pos = -1;
    bool spill = false;
    if (valid) {
        int cap = (n > c) ? (((n - 1 - c) >> 3) + 1) : 0;
        if (myrank < cap) pos = c + (myrank << 3);
        else spill = true;
    }
    unsigned long long sm = __ballot(spill);
    if (spill) {
        int sr = (int)__popcll(sm & below);
        int accum = 0;
        #pragma unroll
        for (int c8 = 0; c8 < 8; ++c8) {
            int cap = (n > c8) ? (((n - 1 - c8) >> 3) + 1) : 0;
            int fr = cap - ncArr[c8]; if (fr < 0) fr = 0;
            if (pos < 0 && sr < accum + fr) {
                int kk = ncArr[c8] + (sr - accum);
                pos = c8 + (kk << 3);
            }
            accum += fr;
        }
    }
    if (valid) arcs[base + pos] = a;   // all lanes loaded before any store (same wave)
}

// ---------------- cooperative mega-kernel, verified XCD-local exchange ----------------
__global__ void __launch_bounds__(NT, 4) k_coop(
    const ArcT2* __restrict__ arcs, const int* __restrict__ rp,
    const int* __restrict__ split,
    const float* __restrict__ input, const float* __restrict__ init_logp,
    const float* __restrict__ final_logp,
    float* __restrict__ partial,         // [NG][2]
    unsigned* __restrict__ A_all,        // [NG][2][ASTRD] packed 2xbf16
    unsigned* __restrict__ flags,        // [2][NBLK][FLGSTR]
    unsigned* __restrict__ xcdbuf,       // [NBLK]
    float* __restrict__ out)
{
    extern __shared__ char dsm[];
    unsigned* la32  = (unsigned*)(dsm + OFF_ALPHA);  // packed 2xbf16 per state
    unsigned* lex32 = (unsigned*)(dsm + OFF_EX);     // packed 2xbf16 per pdf
    ArcT2*    larc  = (ArcT2*)(dsm + OFF_ARC);
    int*      rbp   = (int*)(dsm + OFF_RBP);
    float*    redf  = (float*)(dsm + OFF_RED);
    int*      sh    = (int*)(dsm + OFF_SH);
    int*      lsp   = (int*)(dsm + OFF_LSP);

    int tid = threadIdx.x, bid = blockIdx.x;
    int x = bid & 7, y = (bid >> 3) & 3, j = bid >> 5;   // presumed-XCD, grp-in-XCD, member
    int g = x * 4 + y;                                   // group 0..31
    int lane = tid & 63, wave = tid >> 6;
    int oct = lane >> 3, sub = lane & 7;

    unsigned* Ag       = A_all + (size_t)g * (2 * ASTRD);
    unsigned* stepf    = flags;
    unsigned* auxf     = flags + (size_t)NBLK * FLGSTR;
    unsigned* myflag   = stepf + (size_t)(g * GB + j) * FLGSTR;
    unsigned* grpflag  = stepf + (size_t)(g * GB) * FLGSTR;
    unsigned* myflag2  = auxf + (size_t)(g * GB + j) * FLGSTR;
    unsigned* grpflag2 = auxf + (size_t)(g * GB) * FLGSTR;
    const float* inpG  = input + (size_t)(2 * g) * DD;

    int s0 = split[j], s1 = split[j + 1];
    int nst = s1 - s0;
    if (nst > NSTMAX) nst = NSTMAX;                      // safety (never expected)

    // ---- stage rp slice + split + arcs to LDS ----
    for (int i = tid; i <= nst; i += NT) rbp[i] = rp[s0 + i];
    if (tid <= GB) lsp[tid] = split[tid];
    __syncthreads();
    int rb0 = rbp[0];
    {
        int staged = rbp[nst] - rb0; if (staged > CAP) staged = CAP;
        for (int i = tid; i < staged; i += NT) larc[i] = arcs[rb0 + i];
    }

    // ---- publish XCC_ID (s_getreg id=20, offset=0, width=4 -> imm 6164) ----
    unsigned xcd = __builtin_amdgcn_s_getreg(6164) & 0xF;
    if (tid == 0)
        __hip_atomic_store(&xcdbuf[g * GB + j], xcd, __ATOMIC_RELAXED, __HIP_MEMORY_SCOPE_AGENT);
    __syncthreads();
    if (tid == 0)
        __hip_atomic_store(myflag2, 1u, __ATOMIC_RELAXED, __HIP_MEMORY_SCOPE_AGENT);
    // global aux barrier: wave0 polls all 256 aux flags (4 per lane)
    if (wave == 0) {
        while (true) {
            unsigned ok = 1;
            #pragma unroll
            for (int r = 0; r < 4; ++r) {
                unsigned v = __hip_atomic_load(auxf + (size_t)(lane * 4 + r) * FLGSTR,
                                               __ATOMIC_RELAXED, __HIP_MEMORY_SCOPE_AGENT);
                ok &= (v >= 1u);
            }
            if (__ballot(ok != 0) == ~0ULL) break;
            __builtin_amdgcn_s_sleep(1);
        }
    }
    __syncthreads();
    // decide protocol: fast iff my group is on ONE XCD and getreg is plausible
    {
        int* xint = (int*)redf;
        if (tid < NBLK)
            xint[tid] = (int)__hip_atomic_load(&xcdbuf[tid], __ATOMIC_RELAXED,
                                               __HIP_MEMORY_SCOPE_AGENT);
        __syncthreads();
        if (tid == 0) {
            int x0 = xint[g * GB];
            int uni = 1;
            for (int m = 1; m < GB; ++m) uni &= (xint[g * GB + m] == x0);
            int first = xint[0], distinct = 0;
            for (int i = 1; i < NBLK; ++i) distinct |= (xint[i] != first);
            sh[0] = uni && distinct;
        }
        __syncthreads();
    }
    const bool fast = (sh[0] != 0);
    __syncthreads();

    // Pipelined per-producer exchange: wave m (<GB) polls producer m's flag
    // and copies its slice [lsp[m],lsp[m+1]) into la32 the moment it lands;
    // waves GB..15 build ex for frame `fr`. Caller barriers after.
    auto exchange = [&](unsigned epv, const unsigned* srcbuf, const float* fr) {
        if (wave < GB) {
            int m = wave;
            const unsigned* gf = grpflag + (size_t)m * FLGSTR;
            if (fast) {
                while (*(volatile const unsigned*)gf < epv) __builtin_amdgcn_s_sleep(1);
                int a = lsp[m], b = lsp[m + 1];
                for (int i = a + lane; i < b; i += 64)
                    la32[i] = *(volatile const unsigned*)(srcbuf + i);
            } else {
                while (__hip_atomic_load(gf, __ATOMIC_RELAXED, __HIP_MEMORY_SCOPE_AGENT) < epv)
                    __builtin_amdgcn_s_sleep(1);
                int a = lsp[m], b = lsp[m + 1];
                for (int i = a + lane; i < b; i += 64)
                    la32[i] = __hip_atomic_load(srcbuf + i, __ATOMIC_RELAXED,
                                                __HIP_MEMORY_SCOPE_AGENT);
            }
        } else {
            for (int d = tid - GB * 64; d < DD; d += NT - GB * 64) {
                lex32[d] = (unsigned)f2b(__expf(fr[d])) |
                           ((unsigned)f2b(__expf(fr[DD + d])) << 16);
            }
        }
    };

    // ---- alpha0 (own slice) with protocol-matched stores ----
    for (int i = tid; i < nst; i += NT) {
        int s = s0 + i;
        unsigned short h = f2b(__expf(init_logp[s]));
        unsigned pk = (unsigned)h | ((unsigned)h << 16);
        if (fast) Ag[s] = pk;                            // plain store -> shared L2
        else __hip_atomic_store(Ag + s, pk, __ATOMIC_RELAXED, __HIP_MEMORY_SCOPE_AGENT);
    }
    __syncthreads();                                     // stores drained
    unsigned ep = 1;
    if (tid == 0) {
        if (fast) *(volatile unsigned*)myflag = ep;
        else __hip_atomic_store(myflag, ep, __ATOMIC_RELAXED, __HIP_MEMORY_SCOPE_AGENT);
    }
    exchange(ep, Ag /* buffer 0 holds alpha0 */, inpG /* frame 0 */);
    __syncthreads();

    float vf0 = 0.f, vf1 = 0.f;

    // ---- 150 steps ----
    for (int k = 0; k < TT; ++k) {
        unsigned* An32 = Ag + ((k + 1) & 1) * ASTRD;
        bool last = (k == TT - 1);
        bool resc = (((k + 1) & (RESC - 1)) == 0);

        // gather own states (8 lanes per state, 8 states per wave)
        for (int base = wave * 8; base < nst; base += 128) {
            int li = base + oct;
            bool has = (li < nst);
            float acc0 = 0.f, acc1 = 0.f;
            int sg = 0;
            if (has) {
                sg = s0 + li;
                int ra = rbp[li], re = rbp[li + 1];
                int nit = (re - ra) >> 3;
                if (re - rb0 <= CAP) {
                    int bix = ra - rb0 + sub;
                    for (int t = 0; t < nit; ++t) {
                        ArcT2 a = larc[bix + t * 8];
                        unsigned au = *(const unsigned*)(dsm + (a.idx & 0xFFFFu));
                        unsigned eu = *(const unsigned*)(dsm + OFF_EX + (a.idx >> 16));
                        acc0 = fmaf(u2f(au << 16), a.ew * u2f(eu << 16), acc0);
                        acc1 = fmaf(u2f(au & 0xFFFF0000u), a.ew * u2f(eu & 0xFFFF0000u), acc1);
                    }
                } else {
                    for (int t = 0; t < nit; ++t) {      // safety overflow path
                        ArcT2 a = arcs[ra + t * 8 + sub];
                        unsigned au = *(const unsigned*)(dsm + (a.idx & 0xFFFFu));
                        unsigned eu = *(const unsigned*)(dsm + OFF_EX + (a.idx >> 16));
                        acc0 = fmaf(u2f(au << 16), a.ew * u2f(eu << 16), acc0);
                        acc1 = fmaf(u2f(au & 0xFFFF0000u), a.ew * u2f(eu & 0xFFFF0000u), acc1);
                    }
                }
            }
            acc0 += __shfl_xor(acc0, 1, 64); acc1 += __shfl_xor(acc1, 1, 64);
            acc0 += __shfl_xor(acc0, 2, 64); acc1 += __shfl_xor(acc1, 2, 64);
            acc0 += __shfl_xor(acc0, 4, 64); acc1 += __shfl_xor(acc1, 4, 64);
            if (has && sub == 0) {
                if (resc) { acc0 *= RESCC; acc1 *= RESCC; }
                if (last) {
                    float ef = __expf(final_logp[sg]);
                    vf0 = fmaf(acc0, ef, vf0);
                    vf1 = fmaf(acc1, ef, vf1);
                } else {
                    unsigned pk = (unsigned)f2b(acc0) | ((unsigned)f2b(acc1) << 16);
                    if (fast) An32[sg] = pk;             // plain store -> shared L2
                    else __hip_atomic_store(An32 + sg, pk, __ATOMIC_RELAXED,
                                            __HIP_MEMORY_SCOPE_AGENT);
                }
            }
        }
        if (last) break;
        __syncthreads();                                 // stores drained (vmcnt 0)
        ++ep;
        if (tid == 0) {
            if (fast) *(volatile unsigned*)myflag = ep;
            else __hip_atomic_store(myflag, ep, __ATOMIC_RELAXED, __HIP_MEMORY_SCOPE_AGENT);
        }
        exchange(ep, An32, inpG + (size_t)(k + 1) * BB * DD);
        __syncthreads();
    }

    // ---- epilogue: reduce objf over this block's states ----
    if (sub == 0) {
        redf[(wave * 8 + oct) * 2 + 0] = vf0;
        redf[(wave * 8 + oct) * 2 + 1] = vf1;
    }
    __syncthreads();
    if (tid < 2) {
        float S = 0.f;
        for (int i = 0; i < 128; ++i) S += redf[i * 2 + tid];
        __hip_atomic_fetch_add(&partial[g * 2 + tid], S, __ATOMIC_RELAXED,
                               __HIP_MEMORY_SCOPE_AGENT);
    }
    __syncthreads();
    if (tid == 0)
        __hip_atomic_store(myflag2, 2u, __ATOMIC_RELAXED, __HIP_MEMORY_SCOPE_AGENT);
    if (j == 0) {
        if (wave == 0) {
            while (true) {
                unsigned v = 2;
                if (lane < GB)
                    v = __hip_atomic_load(grpflag2 + lane * FLGSTR, __ATOMIC_RELAXED,
                                          __HIP_MEMORY_SCOPE_AGENT);
                if (__ballot(v >= 2) == ~0ULL) break;
                __builtin_amdgcn_s_sleep(1);
            }
        }
        __syncthreads();
        if (tid < 2) {
            float S = __hip_atomic_load(&partial[g * 2 + tid], __ATOMIC_RELAXED,
                                        __HIP_MEMORY_SCOPE_AGENT);
            float lg = logf(S) + (float)(NSLOT * 46) * 0.69314718055994531f;
            atomicAdd(out, lg);
        }
    }
}

// ---------------- fallback path (round-6 per-step kernels) ----------------
template <int THREADS>
__device__ inline void transpose_exp_t(const float* __restrict__ frame,
                                       unsigned short* __restrict__ dst,
                                       int tile_id, int tid, unsigned short* smem)
{
    int d0 = tile_id * 64;
    #pragma unroll
    for (int it = 0; it < 4096 / THREADS; ++it) {
        int idx = it * THREADS + tid;
        int dl = idx & 63, bl = idx >> 6;
        int d = d0 + dl;
        float v = 0.f;
        if (d < DD) v = __expf(frame[bl * DD + d]);
        smem[dl * 65 + bl] = f2b(v);
    }
    __syncthreads();
    #pragma unroll
    for (int it = 0; it < 4096 / THREADS; ++it) {
        int idx = it * THREADS + tid;
        int bo = idx & 63, dq = idx >> 6;
        int d = d0 + dq;
        if (d < DD) dst[(d << 6) + bo] = smem[dq * 65 + bo];
    }
    __syncthreads();
}

__global__ void k_initA(const float* __restrict__ init_logp,
                        unsigned short* __restrict__ A0, float* __restrict__ M2)
{
    int idx = blockIdx.x * blockDim.x + threadIdx.x;
    if (idx < SS * BB) A0[idx] = f2b(__expf(init_logp[idx >> 6]));
    if (idx < NSLOT * 16 * 64) M2[idx] = 0.f;
}

__global__ void k_transpose0(const float* __restrict__ frame, unsigned short* __restrict__ dst)
{
    __shared__ unsigned short tile[64 * 65];
    transpose_exp_t<256>(frame, dst, blockIdx.x, threadIdx.x, tile);
}

__global__ void __launch_bounds__(256) k_step(
    const ArcT2* __restrict__ arcs, const int* __restrict__ rp,
    const unsigned short* __restrict__ Ap, unsigned short* __restrict__ An,
    const unsigned short* __restrict__ ec,
    const float* __restrict__ frameNext, unsigned short* __restrict__ en,
    float* __restrict__ M2, int maxSlot, int useSlot)
{
    __shared__ unsigned short tile[64 * 65];
    __shared__ float part[256];
    __shared__ float rcpA[64];
    int tid = threadIdx.x, bid = blockIdx.x;
    if (bid >= SS) { transpose_exp_t<256>(frameNext, en, bid - SS, tid, tile); return; }
    int lane = tid & 63, wave = tid >> 6;
    if (useSlot >= 0 && wave == 0) {
        const float* Mrow = M2 + useSlot * (16 * 64);
        float m = Mrow[lane];
        #pragma unroll
        for (int g = 1; g < 16; ++g) m = fmaxf(m, Mrow[g * 64 + lane]);
        rcpA[lane] = 1.0f / m;
    }
    int rbeg = rp[bid], rend = rp[bid + 1];
    float acc = 0.f;
    for (int i = rbeg + wave; i < rend; i += 4) {
        ArcT2 a = arcs[i];
        int from = (a.idx & 0xFFFF) >> 2, pdf = a.idx >> 18;
        acc = fmaf(b2f(Ap[(from << 6) + lane]), a.ew * b2f(ec[(pdf << 6) + lane]), acc);
    }
    part[tid] = acc;
    __syncthreads();
    if (wave == 0) {
        float sum = part[lane] + part[64 + lane] + part[128 + lane] + part[192 + lane];
        if (useSlot >= 0) sum *= rcpA[lane];
        An[(bid << 6) + lane] = f2b(sum);
        if (maxSlot >= 0)
            atomicMax((unsigned*)&M2[maxSlot * (16 * 64) + (bid & 15) * 64 + lane],
                      __float_as_uint(sum));
    }
}

__global__ void k_fin(const unsigned short* __restrict__ AT, const float* __restrict__ final_logp,
                      const float* __restrict__ M2, float* __restrict__ out)
{
    __shared__ float red[1024];
    int tid = threadIdx.x;
    int lane = tid & 63, chunk = tid >> 6;
    float psum = 0.f;
    for (int s = chunk; s < SS; s += 16)
        psum += b2f(AT[(s << 6) + lane]) * __expf(final_logp[s]);
    red[tid] = psum;
    __syncthreads();
    if (tid < 64) {
        float sum = 0.f;
        #pragma unroll
        for (int c = 0; c < 16; ++c) sum += red[c * 64 + tid];
        float lg = logf(sum);
        #pragma unroll
        for (int r = 0; r < NSLOT; ++r) {
            const float* Mrow = M2 + r * (16 * 64);
            float m = Mrow[tid];
            #pragma unroll
            for (int g = 1; g < 16; ++g) m = fmaxf(m, Mrow[g * 64 + tid]);
            lg += logf(m);
        }
        #pragma unroll
        for (int off = 32; off > 0; off >>= 1) lg += __shfl_down(lg, off);
        if (tid == 0) out[0] = lg;
    }
}

extern "C" void kernel_launch(void* const* d_in, const int* in_sizes, int n_in,
                              void* d_out, int out_size, void* d_ws, size_t ws_size,
                              hipStream_t stream)
{
    const float* input      = (const float*)d_in[0];
    const float* trans_logw = (const float*)d_in[1];
    const float* init_logp  = (const float*)d_in[2];
    const float* final_logp = (const float*)d_in[3];
    const int*   from_state = (const int*)d_in[4];
    const int*   to_state   = (const int*)d_in[5];
    const int*   pdf_id     = (const int*)d_in[6];
    float* out = (float*)d_out;

    char* ws = (char*)d_ws;
    size_t off = 0;
    auto alloc = [&](size_t bytes) -> char* {
        char* p = ws + off;
        off = (off + bytes + 255) & ~(size_t)255;
        return p;
    };
    ArcT2* arcs  = (ArcT2*)alloc((size_t)EEPAD * sizeof(ArcT2));
    int* rp      = (int*)alloc((size_t)(SS + 1) * 4);
    int* cur     = (int*)alloc((size_t)SS * 4);
    int* counts  = (int*)alloc((size_t)SS * 4);
    int* split   = (int*)alloc((size_t)(GB + 1) * 4);
    unsigned* A_all = (unsigned*)alloc((size_t)NG * 2 * ASTRD * 4);
    float* partial  = (float*)alloc((size_t)NG * 2 * 4);
    unsigned* flags = (unsigned*)alloc((size_t)2 * NBLK * FLGSTR * 4);
    unsigned* xcdbuf = (unsigned*)alloc((size_t)NBLK * 4);
    // fallback buffers
    unsigned short* A0  = (unsigned short*)alloc((size_t)SS * BB * 2);
    unsigned short* A1  = (unsigned short*)alloc((size_t)SS * BB * 2);
    unsigned short* EX0 = (unsigned short*)alloc((size_t)DD * BB * 2);
    unsigned short* EX1 = (unsigned short*)alloc((size_t)DD * BB * 2);
    float* M2    = (float*)alloc((size_t)NSLOT * 16 * 64 * 4);
    (void)ws_size; (void)in_sizes; (void)n_in; (void)out_size;

    k_init0<<<64, 256, 0, stream>>>(counts, flags, partial);
    k_zeroarcs<<<(EEPAD + 255) / 256, 256, 0, stream>>>(arcs);
    k_hist<<<(EE + 255) / 256, 256, 0, stream>>>(to_state, counts);
    k_scan<<<1, 1024, 0, stream>>>(counts, rp, cur);
    k_split<<<1, 16, 0, stream>>>(rp, split);
    k_scatter<<<(EE + 255) / 256, 256, 0, stream>>>(from_state, to_state, pdf_id,
                                                    trans_logw, cur, arcs);
    k_sortbank<<<(SS * 64 + 255) / 256, 256, 0, stream>>>(rp, counts, arcs);
    hipMemsetAsync(d_out, 0, sizeof(float), stream);

    hipFuncSetAttribute((const void*)k_coop, hipFuncAttributeMaxDynamicSharedMemorySize,
                        DYNLDS);
    int nb = 0;
    hipOccupancyMaxActiveBlocksPerMultiprocessor(&nb, (const void*)k_coop, NT, DYNLDS);
    if (nb >= 1) {
        void* kp[11] = {
            (void*)&arcs, (void*)&rp, (void*)&split, (void*)&input, (void*)&init_logp,
            (void*)&final_logp, (void*)&partial, (void*)&A_all, (void*)&flags,
            (void*)&xcdbuf, (void*)&out
        };
        hipError_t e = hipLaunchCooperativeKernel((const void*)k_coop, dim3(NBLK), dim3(NT),
                                                  kp, DYNLDS, stream);
        if (e == hipSuccess) return;
    }

    // Fallback: per-step kernels (bf16 state), known-passing structure.
    k_initA<<<(SS * BB + 255) / 256, 256, 0, stream>>>(init_logp, A0, M2);
    k_transpose0<<<NEXB, 256, 0, stream>>>(input, EX0);
    unsigned short* A[2]  = {A0, A1};
    unsigned short* EX[2] = {EX0, EX1};
    for (int k = 0; k < TT; ++k) {
        int kn = k + 1;
        int useSlot = (k > 0 && (k % RESC) == 0) ? (k / RESC - 1) : -1;
        int maxSlot = (kn < TT && (kn % RESC) == 0) ? (kn / RESC - 1) : -1;
        int grid = SS + ((kn < TT) ? NEXB : 0);
        const float* fnext = (kn < TT) ? (input + (size_t)kn * BB * DD) : nullptr;
        k_step<<<grid, 256, 0, stream>>>(arcs, rp, A[k & 1], A[kn & 1], EX[k & 1],
                                         fnext, EX[kn & 1], M2, maxSlot, useSlot);
    }
    k_fin<<<1, 1024, 0, stream>>>(A[TT & 1], final_logp, M2, out);
}

// Round 4
// 911.477 us; speedup vs baseline: 1.0946x; 1.0946x over previous
//
#include <hip/hip_runtime.h>
#include <math.h>

#define TT 150
#define BB 64
#define DD 2000
#define SS 3000
#define EE 100000
#define EEPAD 124160   // >= EE + SS*7 (arcs padded per-state to multiple of 8)
#define RESC 16
#define NSLOT 9
#define RESCC 0x1p-46f // exact pow2 rescale every 16 steps (growth ~7.42^16 ~= 2^46.3)

#define NT 1024        // threads per block (16 waves)
#define NBLK 256       // 1 block per CU
#define NG 32          // groups, 2 batch lanes each
#define GB 8           // blocks per group (same XCD iff bid%8 maps to XCD)
#define CAP 14336      // LDS arc slots per block (max slice ~13.9k)
#define ASTRD 3072     // dwords per alpha buffer per group (SS=3000 padded)
#define NSTMAX 2048
#define FLGSTR 32      // dwords between flags (128 B)
#define NEXB 32

// dynamic LDS layout (bytes). Alpha table at byte 0 so the gather's
// ds_read address is just (idx & 0xFFFF); ex base 12288 folds into the
// ds_read offset immediate.
#define OFF_ALPHA  0                 // SS*4 -> 12288 (packed 2xbf16 per state)
#define OFF_EX     12288             // DD*4 -> 8192  (packed 2xbf16 per pdf)
#define OFF_ARC    20480             // CAP*8 = 114688
#define OFF_RBP    135168            // (NSTMAX+1)*4 -> 8208
#define OFF_RED    143376            // 256*4 = 1024
#define OFF_SH     144400            // 16
#define OFF_SORD   144416            // NSTMAX*4 = 8192
#define DYNLDS     152608

// idx = (from<<2) | (pdf<<18): both halves are ready-made BYTE offsets into
// the packed-u32 LDS tables (from*4 <= 11996 fits 14 bits; pdf*4 <= 7996).
struct __align__(8) ArcT2 { unsigned idx; float ew; };

__device__ inline float b2f(unsigned short u) {
    union { unsigned u32; float f; } x; x.u32 = ((unsigned)u) << 16; return x.f;
}
__device__ inline unsigned short f2b(float f) {
    union { float f; unsigned u; } x; x.f = f;
    unsigned r = x.u + 0x7FFF + ((x.u >> 16) & 1);       // RNE, positive finite only
    return (unsigned short)(r >> 16);
}
__device__ inline float u2f(unsigned u) {
    union { unsigned u32; float f; } x; x.u32 = u; return x.f;
}

// ---------------- setup kernels ----------------
__global__ void k_init0(int* __restrict__ counts, unsigned* __restrict__ flags,
                        float* __restrict__ partial)
{
    int i = blockIdx.x * blockDim.x + threadIdx.x;
    if (i < SS) counts[i] = 0;
    if (i < 2 * NBLK * FLGSTR) flags[i] = 0u;
    if (i < NG * 2) partial[i] = 0.f;
}

__global__ void k_zeroarcs(ArcT2* __restrict__ arcs)
{
    int i = blockIdx.x * blockDim.x + threadIdx.x;
    if (i < EEPAD) { ArcT2 z; z.idx = 0; z.ew = 0.f; arcs[i] = z; }
}

__global__ void k_hist(const int* __restrict__ to_state, int* __restrict__ counts)
{
    int e = blockIdx.x * blockDim.x + threadIdx.x;
    if (e < EE) atomicAdd(&counts[to_state[e]], 1);
}

// prefix over counts padded to multiple of 8
__global__ void k_scan(const int* __restrict__ counts, int* __restrict__ rp,
                       int* __restrict__ cur)
{
    __shared__ int ls[1024];
    int tid = threadIdx.x;
    int s0 = tid * 3;
    int a0 = (s0 + 0 < SS) ? ((counts[s0 + 0] + 7) & ~7) : 0;
    int a1 = (s0 + 1 < SS) ? ((counts[s0 + 1] + 7) & ~7) : 0;
    int a2 = (s0 + 2 < SS) ? ((counts[s0 + 2] + 7) & ~7) : 0;
    int tsum = a0 + a1 + a2;
    ls[tid] = tsum;
    __syncthreads();
    for (int off = 1; off < 1024; off <<= 1) {
        int v = ls[tid];
        int add = (tid >= off) ? ls[tid - off] : 0;
        __syncthreads();
        ls[tid] = v + add;
        __syncthreads();
    }
    int excl = ls[tid] - tsum;
    if (s0 + 0 < SS) { rp[s0 + 0] = excl; cur[s0 + 0] = excl; }
    excl += a0;
    if (s0 + 1 < SS) { rp[s0 + 1] = excl; cur[s0 + 1] = excl; }
    excl += a1;
    if (s0 + 2 < SS) { rp[s0 + 2] = excl; cur[s0 + 2] = excl; }
    if (tid == 1023) rp[SS] = ls[1023];
}

// arc-balanced split into GB slices
__global__ void k_split(const int* __restrict__ rp, int* __restrict__ split)
{
    int j = threadIdx.x;
    if (j > GB) return;
    if (j == 0)  { split[0] = 0; return; }
    if (j == GB) { split[GB] = SS; return; }
    long long total = rp[SS];
    int target = (int)((total * j) / GB);
    int lo = 0, hi = SS;
    while (lo < hi) { int mid = (lo + hi) >> 1; if (rp[mid] >= target) hi = mid; else lo = mid + 1; }
    split[j] = lo;
}

// Per-slice counting sort of states by descending arc count. The permutation
// equalizes nit within each oct-group of 8 states (gather wave time = max nit
// over its 8 states -> max ~= mean after sorting). Shared by all groups.
__global__ void k_sortst(const int* __restrict__ rp, const int* __restrict__ split,
                         int* __restrict__ sordg)
{
    __shared__ int hist[64];
    __shared__ int off[64];
    int j = blockIdx.x;                      // slice 0..GB-1
    int s0 = split[j], s1 = split[j + 1];
    int nst = s1 - s0; if (nst > NSTMAX) nst = NSTMAX;
    int tid = threadIdx.x;                   // 256 threads
    if (tid < 64) hist[tid] = 0;
    __syncthreads();
    for (int i = tid; i < nst; i += 256) {
        int nit = (rp[s0 + i + 1] - rp[s0 + i]) >> 3;
        if (nit > 63) nit = 63;
        atomicAdd(&hist[nit], 1);
    }
    __syncthreads();
    if (tid == 0) {
        int acc = 0;
        for (int b = 63; b >= 0; --b) { off[b] = acc; acc += hist[b]; }
    }
    __syncthreads();
    for (int i = tid; i < nst; i += 256) {
        int nit = (rp[s0 + i + 1] - rp[s0 + i]) >> 3;
        if (nit > 63) nit = 63;
        int pos = atomicAdd(&off[nit], 1);
        sordg[j * NSTMAX + pos] = i;
    }
}

__global__ void k_scatter(const int* __restrict__ from_state, const int* __restrict__ to_state,
                          const int* __restrict__ pdf_id, const float* __restrict__ trans_logw,
                          int* __restrict__ cur, ArcT2* __restrict__ arcs)
{
    int e = blockIdx.x * blockDim.x + threadIdx.x;
    if (e >= EE) return;
    int s = to_state[e];
    int pos = atomicAdd(&cur[s], 1);
    ArcT2 a;
    a.idx = ((unsigned)from_state[e] << 2) | ((unsigned)pdf_id[e] << 18);
    a.ew = __expf(trans_logw[e]);
    arcs[pos] = a;
}

// Bank-aware in-place reorder: within each state, put arcs with
// from%8 == position%8 at matching positions. Pure permutation of a
// commutative sum -> correctness-neutral. One wave per state.
__global__ void k_sortbank(const int* __restrict__ rp, const int* __restrict__ counts,
                           ArcT2* __restrict__ arcs)
{
    int w = (blockIdx.x * blockDim.x + threadIdx.x) >> 6;
    int lane = threadIdx.x & 63;
    if (w >= SS) return;
    int n = counts[w];
    if (n < 2 || n > 64) return;
    int base = rp[w];
    bool valid = (lane < n);
    ArcT2 a;
    a.idx = 0; a.ew = 0.f;
    if (valid) a = arcs[base + lane];
    int c = valid ? (int)((a.idx >> 2) & 7) : -1;
    unsigned long long below = (1ull << lane) - 1ull;
    int ncArr[8];
    int myrank = 0;
    #pragma unroll
    for (int c8 = 0; c8 < 8; ++c8) {
        unsigned long long m = __ballot(valid && (c == c8));
        ncArr[c8] = (int)__popcll(m);
        if (c == c8) myrank = (int)__popcll(m & below);
    }
    int pos = -1;
    bool spill = false;
    if (valid) {
        int cap = (n > c) ? (((n - 1 - c) >> 3) + 1) : 0;
        if (myrank < cap) pos = c + (myrank << 3);
        else spill = true;
    }
    unsigned long long sm = __ballot(spill);
    if (spill) {
        int sr = (int)__popcll(sm & below);
        int accum = 0;
        #pragma unroll
        for (int c8 = 0; c8 < 8; ++c8) {
            int cap = (n > c8) ? (((n - 1 - c8) >> 3) + 1) : 0;
            int fr = cap - ncArr[c8]; if (fr < 0) fr = 0;
            if (pos < 0 && sr < accum + fr) {
                int kk = ncArr[c8] + (sr - accum);
                pos = c8 + (kk << 3);
            }
            accum += fr;
        }
    }
    if (valid) arcs[base + pos] = a;   // all lanes loaded before any store (same wave)
}

// ---------------- cooperative mega-kernel, verified XCD-local exchange ----------------
__global__ void __launch_bounds__(NT, 4) k_coop(
    const ArcT2* __restrict__ arcs, const int* __restrict__ rp,
    const int* __restrict__ split, const int* __restrict__ sordg,
    const float* __restrict__ input, const float* __restrict__ init_logp,
    const float* __restrict__ final_logp,
    float* __restrict__ partial,         // [NG][2]
    unsigned* __restrict__ A_all,        // [NG][2][ASTRD] packed 2xbf16
    unsigned* __restrict__ flags,        // [2][NBLK][FLGSTR]
    unsigned* __restrict__ xcdbuf,       // [NBLK]
    float* __restrict__ out)
{
    extern __shared__ char dsm[];
    unsigned* la32  = (unsigned*)(dsm + OFF_ALPHA);  // packed 2xbf16 per state
    unsigned* lex32 = (unsigned*)(dsm + OFF_EX);     // packed 2xbf16 per pdf
    ArcT2*    larc  = (ArcT2*)(dsm + OFF_ARC);
    int*      rbp   = (int*)(dsm + OFF_RBP);
    float*    redf  = (float*)(dsm + OFF_RED);
    int*      sh    = (int*)(dsm + OFF_SH);
    int*      sord  = (int*)(dsm + OFF_SORD);

    int tid = threadIdx.x, bid = blockIdx.x;
    int x = bid & 7, y = (bid >> 3) & 3, j = bid >> 5;   // presumed-XCD, grp-in-XCD, member
    int g = x * 4 + y;                                   // group 0..31
    int lane = tid & 63, wave = tid >> 6;
    int oct = lane >> 3, sub = lane & 7;

    unsigned* Ag       = A_all + (size_t)g * (2 * ASTRD);
    unsigned* stepf    = flags;
    unsigned* auxf     = flags + (size_t)NBLK * FLGSTR;
    unsigned* myflag   = stepf + (size_t)(g * GB + j) * FLGSTR;
    unsigned* grpflag  = stepf + (size_t)(g * GB) * FLGSTR;
    unsigned* myflag2  = auxf + (size_t)(g * GB + j) * FLGSTR;
    unsigned* grpflag2 = auxf + (size_t)(g * GB) * FLGSTR;
    const float* inpG  = input + (size_t)(2 * g) * DD;

    int s0 = split[j], s1 = split[j + 1];
    int nst = s1 - s0;
    if (nst > NSTMAX) nst = NSTMAX;                      // safety (never expected)

    // ---- stage rp slice + sorted order + arcs to LDS ----
    for (int i = tid; i <= nst; i += NT) rbp[i] = rp[s0 + i];
    for (int i = tid; i < nst; i += NT) sord[i] = sordg[j * NSTMAX + i];
    __syncthreads();
    int rb0 = rbp[0];
    {
        int staged = rbp[nst] - rb0; if (staged > CAP) staged = CAP;
        for (int i = tid; i < staged; i += NT) larc[i] = arcs[rb0 + i];
    }

    // ---- publish XCC_ID (s_getreg id=20, offset=0, width=4 -> imm 6164) ----
    unsigned xcd = __builtin_amdgcn_s_getreg(6164) & 0xF;
    if (tid == 0)
        __hip_atomic_store(&xcdbuf[g * GB + j], xcd, __ATOMIC_RELAXED, __HIP_MEMORY_SCOPE_AGENT);
    __syncthreads();
    if (tid == 0)
        __hip_atomic_store(myflag2, 1u, __ATOMIC_RELAXED, __HIP_MEMORY_SCOPE_AGENT);
    // global aux barrier: wave0 polls all 256 aux flags (4 per lane)
    if (wave == 0) {
        while (true) {
            unsigned ok = 1;
            #pragma unroll
            for (int r = 0; r < 4; ++r) {
                unsigned v = __hip_atomic_load(auxf + (size_t)(lane * 4 + r) * FLGSTR,
                                               __ATOMIC_RELAXED, __HIP_MEMORY_SCOPE_AGENT);
                ok &= (v >= 1u);
            }
            if (__ballot(ok != 0) == ~0ULL) break;
            __builtin_amdgcn_s_sleep(1);
        }
    }
    __syncthreads();
    // decide protocol: fast iff my group is on ONE XCD and getreg is plausible
    {
        int* xint = (int*)redf;
        if (tid < NBLK)
            xint[tid] = (int)__hip_atomic_load(&xcdbuf[tid], __ATOMIC_RELAXED,
                                               __HIP_MEMORY_SCOPE_AGENT);
        __syncthreads();
        if (tid == 0) {
            int x0 = xint[g * GB];
            int uni = 1;
            for (int m = 1; m < GB; ++m) uni &= (xint[g * GB + m] == x0);
            int first = xint[0], distinct = 0;
            for (int i = 1; i < NBLK; ++i) distinct |= (xint[i] != first);
            sh[0] = uni && distinct;
        }
        __syncthreads();
    }
    const bool fast = (sh[0] != 0);
    __syncthreads();

    // ---- alpha0 (own slice) with protocol-matched stores ----
    for (int i = tid; i < nst; i += NT) {
        int s = s0 + i;
        unsigned short h = f2b(__expf(init_logp[s]));
        unsigned pk = (unsigned)h | ((unsigned)h << 16);
        if (fast) Ag[s] = pk;                            // plain store -> shared L2
        else __hip_atomic_store(Ag + s, pk, __ATOMIC_RELAXED, __HIP_MEMORY_SCOPE_AGENT);
    }
    __syncthreads();                                     // stores drained
    unsigned ep = 1;
    if (tid == 0) {
        if (fast) *(volatile unsigned*)myflag = ep;
        else __hip_atomic_store(myflag, ep, __ATOMIC_RELAXED, __HIP_MEMORY_SCOPE_AGENT);
    }
    {   // ex frame 0, packed bf16 (overlaps other blocks' arrival)
        for (int r = 0; r < 2; ++r) {
            int d = r * NT + tid;
            if (d < DD)
                lex32[d] = (unsigned)f2b(__expf(inpG[d])) |
                           ((unsigned)f2b(__expf(inpG[DD + d])) << 16);
        }
    }
    if (wave == 0) {
        while (true) {
            unsigned v = ep;
            if (lane < GB) {
                v = fast ? *(volatile const unsigned*)(grpflag + lane * FLGSTR)
                         : __hip_atomic_load(grpflag + lane * FLGSTR, __ATOMIC_RELAXED,
                                             __HIP_MEMORY_SCOPE_AGENT);
            }
            if (__ballot(v >= ep) == ~0ULL) break;
            if (!fast) __builtin_amdgcn_s_sleep(1);
        }
    }
    __syncthreads();

    float vf0 = 0.f, vf1 = 0.f;

    // ---- 150 steps ----
    for (int k = 0; k < TT; ++k) {
        const unsigned* Ap32 = Ag + (k & 1) * ASTRD;
        unsigned*       An32 = Ag + ((k + 1) & 1) * ASTRD;
        bool last = (k == TT - 1);
        bool resc = (((k + 1) & (RESC - 1)) == 0);

        // phase A: alpha_k (12 KB packed bf16) -> LDS, straight u64 copy
        if (fast) {
            for (int idx = tid; idx < SS / 2; idx += NT) {
                unsigned long long v =
                    *(volatile const unsigned long long*)((const unsigned long long*)Ap32 + idx);
                ((unsigned long long*)la32)[idx] = v;
            }
        } else {
            for (int idx = tid; idx < SS / 2; idx += NT) {
                unsigned long long v = __hip_atomic_load(
                    (const unsigned long long*)Ap32 + idx, __ATOMIC_RELAXED,
                    __HIP_MEMORY_SCOPE_AGENT);
                ((unsigned long long*)la32)[idx] = v;
            }
        }
        __syncthreads();

        // phase B: gather own states via sorted order (8 lanes per state,
        // 8 states per wave; sorted -> max nit ~= mean nit within oct-group)
        for (int base = wave * 8; base < nst; base += 128) {
            int li = base + oct;
            bool has = (li < nst);
            float acc0 = 0.f, acc1 = 0.f;
            int sg = 0;
            if (has) {
                int so = sord[li];
                sg = s0 + so;
                int ra = rbp[so], re = rbp[so + 1];
                int nit = (re - ra) >> 3;
                if (re - rb0 <= CAP) {
                    int bix = ra - rb0 + sub;
                    for (int t = 0; t < nit; ++t) {
                        ArcT2 a = larc[bix + t * 8];
                        unsigned au = *(const unsigned*)(dsm + (a.idx & 0xFFFFu));
                        unsigned eu = *(const unsigned*)(dsm + OFF_EX + (a.idx >> 16));
                        acc0 = fmaf(u2f(au << 16), a.ew * u2f(eu << 16), acc0);
                        acc1 = fmaf(u2f(au & 0xFFFF0000u), a.ew * u2f(eu & 0xFFFF0000u), acc1);
                    }
                } else {
                    for (int t = 0; t < nit; ++t) {      // safety overflow path
                        ArcT2 a = arcs[ra + t * 8 + sub];
                        unsigned au = *(const unsigned*)(dsm + (a.idx & 0xFFFFu));
                        unsigned eu = *(const unsigned*)(dsm + OFF_EX + (a.idx >> 16));
                        acc0 = fmaf(u2f(au << 16), a.ew * u2f(eu << 16), acc0);
                        acc1 = fmaf(u2f(au & 0xFFFF0000u), a.ew * u2f(eu & 0xFFFF0000u), acc1);
                    }
                }
            }
            acc0 += __shfl_xor(acc0, 1, 64); acc1 += __shfl_xor(acc1, 1, 64);
            acc0 += __shfl_xor(acc0, 2, 64); acc1 += __shfl_xor(acc1, 2, 64);
            acc0 += __shfl_xor(acc0, 4, 64); acc1 += __shfl_xor(acc1, 4, 64);
            if (has && sub == 0) {
                if (resc) { acc0 *= RESCC; acc1 *= RESCC; }
                if (last) {
                    float ef = __expf(final_logp[sg]);
                    vf0 = fmaf(acc0, ef, vf0);
                    vf1 = fmaf(acc1, ef, vf1);
                } else {
                    unsigned pk = (unsigned)f2b(acc0) | ((unsigned)f2b(acc1) << 16);
                    if (fast) An32[sg] = pk;             // plain store -> shared L2
                    else __hip_atomic_store(An32 + sg, pk, __ATOMIC_RELAXED,
                                            __HIP_MEMORY_SCOPE_AGENT);
                }
            }
        }
        if (last) break;
        __syncthreads();                                 // stores drained (vmcnt 0)
        ++ep;
        if (tid == 0) {
            if (fast) *(volatile unsigned*)myflag = ep;
            else __hip_atomic_store(myflag, ep, __ATOMIC_RELAXED, __HIP_MEMORY_SCOPE_AGENT);
        }
        {   // ex_{k+1} (independent of alpha) — overlaps others' arrival
            const float* fr = inpG + (size_t)(k + 1) * BB * DD;
            for (int r = 0; r < 2; ++r) {
                int d = r * NT + tid;
                if (d < DD)
                    lex32[d] = (unsigned)f2b(__expf(fr[d])) |
                               ((unsigned)f2b(__expf(fr[DD + d])) << 16);
            }
        }
        if (wave == 0) {
            while (true) {
                unsigned v = ep;
                if (lane < GB) {
                    v = fast ? *(volatile const unsigned*)(grpflag + lane * FLGSTR)
                             : __hip_atomic_load(grpflag + lane * FLGSTR, __ATOMIC_RELAXED,
                                                 __HIP_MEMORY_SCOPE_AGENT);
                }
                if (__ballot(v >= ep) == ~0ULL) break;
                if (!fast) __builtin_amdgcn_s_sleep(1);
            }
        }
        __syncthreads();
    }

    // ---- epilogue: reduce objf over this block's states ----
    if (sub == 0) {
        redf[(wave * 8 + oct) * 2 + 0] = vf0;
        redf[(wave * 8 + oct) * 2 + 1] = vf1;
    }
    __syncthreads();
    if (tid < 2) {
        float S = 0.f;
        for (int i = 0; i < 128; ++i) S += redf[i * 2 + tid];
        __hip_atomic_fetch_add(&partial[g * 2 + tid], S, __ATOMIC_RELAXED,
                               __HIP_MEMORY_SCOPE_AGENT);
    }
    __syncthreads();
    if (tid == 0)
        __hip_atomic_store(myflag2, 2u, __ATOMIC_RELAXED, __HIP_MEMORY_SCOPE_AGENT);
    if (j == 0) {
        if (wave == 0) {
            while (true) {
                unsigned v = 2;
                if (lane < GB)
                    v = __hip_atomic_load(grpflag2 + lane * FLGSTR, __ATOMIC_RELAXED,
                                          __HIP_MEMORY_SCOPE_AGENT);
                if (__ballot(v >= 2) == ~0ULL) break;
                __builtin_amdgcn_s_sleep(1);
            }
        }
        __syncthreads();
        if (tid < 2) {
            float S = __hip_atomic_load(&partial[g * 2 + tid], __ATOMIC_RELAXED,
                                        __HIP_MEMORY_SCOPE_AGENT);
            float lg = logf(S) + (float)(NSLOT * 46) * 0.69314718055994531f;
            atomicAdd(out, lg);
        }
    }
}

// ---------------- fallback path (round-6 per-step kernels) ----------------
template <int THREADS>
__device__ inline void transpose_exp_t(const float* __restrict__ frame,
                                       unsigned short* __restrict__ dst,
                                       int tile_id, int tid, unsigned short* smem)
{
    int d0 = tile_id * 64;
    #pragma unroll
    for (int it = 0; it < 4096 / THREADS; ++it) {
        int idx = it * THREADS + tid;
        int dl = idx & 63, bl = idx >> 6;
        int d = d0 + dl;
        float v = 0.f;
        if (d < DD) v = __expf(frame[bl * DD + d]);
        smem[dl * 65 + bl] = f2b(v);
    }
    __syncthreads();
    #pragma unroll
    for (int it = 0; it < 4096 / THREADS; ++it) {
        int idx = it * THREADS + tid;
        int bo = idx & 63, dq = idx >> 6;
        int d = d0 + dq;
        if (d < DD) dst[(d << 6) + bo] = smem[dq * 65 + bo];
    }
    __syncthreads();
}

__global__ void k_initA(const float* __restrict__ init_logp,
                        unsigned short* __restrict__ A0, float* __restrict__ M2)
{
    int idx = blockIdx.x * blockDim.x + threadIdx.x;
    if (idx < SS * BB) A0[idx] = f2b(__expf(init_logp[idx >> 6]));
    if (idx < NSLOT * 16 * 64) M2[idx] = 0.f;
}

__global__ void k_transpose0(const float* __restrict__ frame, unsigned short* __restrict__ dst)
{
    __shared__ unsigned short tile[64 * 65];
    transpose_exp_t<256>(frame, dst, blockIdx.x, threadIdx.x, tile);
}

__global__ void __launch_bounds__(256) k_step(
    const ArcT2* __restrict__ arcs, const int* __restrict__ rp,
    const unsigned short* __restrict__ Ap, unsigned short* __restrict__ An,
    const unsigned short* __restrict__ ec,
    const float* __restrict__ frameNext, unsigned short* __restrict__ en,
    float* __restrict__ M2, int maxSlot, int useSlot)
{
    __shared__ unsigned short tile[64 * 65];
    __shared__ float part[256];
    __shared__ float rcpA[64];
    int tid = threadIdx.x, bid = blockIdx.x;
    if (bid >= SS) { transpose_exp_t<256>(frameNext, en, bid - SS, tid, tile); return; }
    int lane = tid & 63, wave = tid >> 6;
    if (useSlot >= 0 && wave == 0) {
        const float* Mrow = M2 + useSlot * (16 * 64);
        float m = Mrow[lane];
        #pragma unroll
        for (int g = 1; g < 16; ++g) m = fmaxf(m, Mrow[g * 64 + lane]);
        rcpA[lane] = 1.0f / m;
    }
    int rbeg = rp[bid], rend = rp[bid + 1];
    float acc = 0.f;
    for (int i = rbeg + wave; i < rend; i += 4) {
        ArcT2 a = arcs[i];
        int from = (a.idx & 0xFFFF) >> 2, pdf = a.idx >> 18;
        acc = fmaf(b2f(Ap[(from << 6) + lane]), a.ew * b2f(ec[(pdf << 6) + lane]), acc);
    }
    part[tid] = acc;
    __syncthreads();
    if (wave == 0) {
        float sum = part[lane] + part[64 + lane] + part[128 + lane] + part[192 + lane];
        if (useSlot >= 0) sum *= rcpA[lane];
        An[(bid << 6) + lane] = f2b(sum);
        if (maxSlot >= 0)
            atomicMax((unsigned*)&M2[maxSlot * (16 * 64) + (bid & 15) * 64 + lane],
                      __float_as_uint(sum));
    }
}

__global__ void k_fin(const unsigned short* __restrict__ AT, const float* __restrict__ final_logp,
                      const float* __restrict__ M2, float* __restrict__ out)
{
    __shared__ float red[1024];
    int tid = threadIdx.x;
    int lane = tid & 63, chunk = tid >> 6;
    float psum = 0.f;
    for (int s = chunk; s < SS; s += 16)
        psum += b2f(AT[(s << 6) + lane]) * __expf(final_logp[s]);
    red[tid] = psum;
    __syncthreads();
    if (tid < 64) {
        float sum = 0.f;
        #pragma unroll
        for (int c = 0; c < 16; ++c) sum += red[c * 64 + tid];
        float lg = logf(sum);
        #pragma unroll
        for (int r = 0; r < NSLOT; ++r) {
            const float* Mrow = M2 + r * (16 * 64);
            float m = Mrow[tid];
            #pragma unroll
            for (int g = 1; g < 16; ++g) m = fmaxf(m, Mrow[g * 64 + tid]);
            lg += logf(m);
        }
        #pragma unroll
        for (int off = 32; off > 0; off >>= 1) lg += __shfl_down(lg, off);
        if (tid == 0) out[0] = lg;
    }
}

extern "C" void kernel_launch(void* const* d_in, const int* in_sizes, int n_in,
                              void* d_out, int out_size, void* d_ws, size_t ws_size,
                              hipStream_t stream)
{
    const float* input      = (const float*)d_in[0];
    const float* trans_logw = (const float*)d_in[1];
    const float* init_logp  = (const float*)d_in[2];
    const float* final_logp = (const float*)d_in[3];
    const int*   from_state = (const int*)d_in[4];
    const int*   to_state   = (const int*)d_in[5];
    const int*   pdf_id     = (const int*)d_in[6];
    float* out = (float*)d_out;

    char* ws = (char*)d_ws;
    size_t off = 0;
    auto alloc = [&](size_t bytes) -> char* {
        char* p = ws + off;
        off = (off + bytes + 255) & ~(size_t)255;
        return p;
    };
    ArcT2* arcs  = (ArcT2*)alloc((size_t)EEPAD * sizeof(ArcT2));
    int* rp      = (int*)alloc((size_t)(SS + 1) * 4);
    int* cur     = (int*)alloc((size_t)SS * 4);
    int* counts  = (int*)alloc((size_t)SS * 4);
    int* split   = (int*)alloc((size_t)(GB + 1) * 4);
    int* sordg   = (int*)alloc((size_t)GB * NSTMAX * 4);
    unsigned* A_all = (unsigned*)alloc((size_t)NG * 2 * ASTRD * 4);
    float* partial  = (float*)alloc((size_t)NG * 2 * 4);
    unsigned* flags = (unsigned*)alloc((size_t)2 * NBLK * FLGSTR * 4);
    unsigned* xcdbuf = (unsigned*)alloc((size_t)NBLK * 4);
    // fallback buffers
    unsigned short* A0  = (unsigned short*)alloc((size_t)SS * BB * 2);
    unsigned short* A1  = (unsigned short*)alloc((size_t)SS * BB * 2);
    unsigned short* EX0 = (unsigned short*)alloc((size_t)DD * BB * 2);
    unsigned short* EX1 = (unsigned short*)alloc((size_t)DD * BB * 2);
    float* M2    = (float*)alloc((size_t)NSLOT * 16 * 64 * 4);
    (void)ws_size; (void)in_sizes; (void)n_in; (void)out_size;

    k_init0<<<64, 256, 0, stream>>>(counts, flags, partial);
    k_zeroarcs<<<(EEPAD + 255) / 256, 256, 0, stream>>>(arcs);
    k_hist<<<(EE + 255) / 256, 256, 0, stream>>>(to_state, counts);
    k_scan<<<1, 1024, 0, stream>>>(counts, rp, cur);
    k_split<<<1, 16, 0, stream>>>(rp, split);
    k_sortst<<<GB, 256, 0, stream>>>(rp, split, sordg);
    k_scatter<<<(EE + 255) / 256, 256, 0, stream>>>(from_state, to_state, pdf_id,
                                                    trans_logw, cur, arcs);
    k_sortbank<<<(SS * 64 + 255) / 256, 256, 0, stream>>>(rp, counts, arcs);
    hipMemsetAsync(d_out, 0, sizeof(float), stream);

    hipFuncSetAttribute((const void*)k_coop, hipFuncAttributeMaxDynamicSharedMemorySize,
                        DYNLDS);
    int nb = 0;
    hipOccupancyMaxActiveBlocksPerMultiprocessor(&nb, (const void*)k_coop, NT, DYNLDS);
    if (nb >= 1) {
        void* kp[12] = {
            (void*)&arcs, (void*)&rp, (void*)&split, (void*)&sordg, (void*)&input,
            (void*)&init_logp, (void*)&final_logp, (void*)&partial, (void*)&A_all,
            (void*)&flags, (void*)&xcdbuf, (void*)&out
        };
        hipError_t e = hipLaunchCooperativeKernel((const void*)k_coop, dim3(NBLK), dim3(NT),
                                                  kp, DYNLDS, stream);
        if (e == hipSuccess) return;
    }

    // Fallback: per-step kernels (bf16 state), known-passing structure.
    k_initA<<<(SS * BB + 255) / 256, 256, 0, stream>>>(init_logp, A0, M2);
    k_transpose0<<<NEXB, 256, 0, stream>>>(input, EX0);
    unsigned short* A[2]  = {A0, A1};
    unsigned short* EX[2] = {EX0, EX1};
    for (int k = 0; k < TT; ++k) {
        int kn = k + 1;
        int useSlot = (k > 0 && (k % RESC) == 0) ? (k / RESC - 1) : -1;
        int maxSlot = (kn < TT && (kn % RESC) == 0) ? (kn / RESC - 1) : -1;
        int grid = SS + ((kn < TT) ? NEXB : 0);
        const float* fnext = (kn < TT) ? (input + (size_t)kn * BB * DD) : nullptr;
        k_step<<<grid, 256, 0, stream>>>(arcs, rp, A[k & 1], A[kn & 1], EX[k & 1],
                                         fnext, EX[kn & 1], M2, maxSlot, useSlot);
    }
    k_fin<<<1, 1024, 0, stream>>>(A[TT & 1], final_logp, M2, out);
}

// Round 5
// 875.000 us; speedup vs baseline: 1.1402x; 1.0417x over previous
//
#include <hip/hip_runtime.h>
#include <math.h>

#define TT 150
#define BB 64
#define DD 2000
#define SS 3000
#define EE 100000
#define EEPAD 124160   // >= EE + SS*7 (arcs padded per-state to multiple of 8)
#define RESC 16
#define NSLOT 9
#define RESCC 0x1p-46f // exact pow2 rescale every 16 steps (growth ~7.42^16 ~= 2^46.3)

#define NT 1024        // threads per block (16 waves)
#define NBLK 256       // 1 block per CU
#define NG 32          // groups, 2 batch lanes each
#define GB 8           // blocks per group (same XCD iff bid%8 maps to XCD)
#define CAP 14336      // LDS arc slots per block (max slice ~13.9k)
#define ASTRD 3072     // dwords per alpha buffer per group (SS=3000 padded)
#define NSTMAX 2048
#define FLGSTR 32      // dwords between flags (128 B)
#define NEXB 32
#define EXCH 125       // ex dwords per wave (16*125 = 2000 = DD)

// dynamic LDS layout (bytes). Alpha table at byte 0 so the gather's
// ds_read address is just (idx & 0xFFFF); ex base 12288 folds into the
// ds_read offset immediate.
#define OFF_ALPHA  0                 // SS*4 -> 12288 (packed 2xbf16 per state)
#define OFF_EX     12288             // DD*4 -> 8192  (packed 2xbf16 per pdf)
#define OFF_ARC    20480             // CAP*8 = 114688
#define OFF_RBP    135168            // (NSTMAX+1)*4 -> 8208
#define OFF_RED    143376            // 256*4 = 1024
#define OFF_SH     144400            // 16
#define OFF_SORD   144416            // NSTMAX*4 = 8192
#define OFF_LSP    152608            // (GB+1)*4 -> 48
#define DYNLDS     152656

// idx = (from<<2) | (pdf<<18): both halves are ready-made BYTE offsets into
// the packed-u32 LDS tables (from*4 <= 11996 fits 14 bits; pdf*4 <= 7996).
struct __align__(8) ArcT2 { unsigned idx; float ew; };

__device__ inline float b2f(unsigned short u) {
    union { unsigned u32; float f; } x; x.u32 = ((unsigned)u) << 16; return x.f;
}
__device__ inline unsigned short f2b(float f) {
    union { float f; unsigned u; } x; x.f = f;
    unsigned r = x.u + 0x7FFF + ((x.u >> 16) & 1);       // RNE, positive finite only
    return (unsigned short)(r >> 16);
}
__device__ inline float u2f(unsigned u) {
    union { unsigned u32; float f; } x; x.u32 = u; return x.f;
}

// ---------------- setup kernels ----------------
__global__ void k_init0(int* __restrict__ counts, unsigned* __restrict__ flags,
                        float* __restrict__ partial)
{
    int i = blockIdx.x * blockDim.x + threadIdx.x;
    if (i < SS) counts[i] = 0;
    if (i < 2 * NBLK * FLGSTR) flags[i] = 0u;
    if (i < NG * 2) partial[i] = 0.f;
}

__global__ void k_zeroarcs(ArcT2* __restrict__ arcs)
{
    int i = blockIdx.x * blockDim.x + threadIdx.x;
    if (i < EEPAD) { ArcT2 z; z.idx = 0; z.ew = 0.f; arcs[i] = z; }
}

__global__ void k_hist(const int* __restrict__ to_state, int* __restrict__ counts)
{
    int e = blockIdx.x * blockDim.x + threadIdx.x;
    if (e < EE) atomicAdd(&counts[to_state[e]], 1);
}

// prefix over counts padded to multiple of 8
__global__ void k_scan(const int* __restrict__ counts, int* __restrict__ rp,
                       int* __restrict__ cur)
{
    __shared__ int ls[1024];
    int tid = threadIdx.x;
    int s0 = tid * 3;
    int a0 = (s0 + 0 < SS) ? ((counts[s0 + 0] + 7) & ~7) : 0;
    int a1 = (s0 + 1 < SS) ? ((counts[s0 + 1] + 7) & ~7) : 0;
    int a2 = (s0 + 2 < SS) ? ((counts[s0 + 2] + 7) & ~7) : 0;
    int tsum = a0 + a1 + a2;
    ls[tid] = tsum;
    __syncthreads();
    for (int off = 1; off < 1024; off <<= 1) {
        int v = ls[tid];
        int add = (tid >= off) ? ls[tid - off] : 0;
        __syncthreads();
        ls[tid] = v + add;
        __syncthreads();
    }
    int excl = ls[tid] - tsum;
    if (s0 + 0 < SS) { rp[s0 + 0] = excl; cur[s0 + 0] = excl; }
    excl += a0;
    if (s0 + 1 < SS) { rp[s0 + 1] = excl; cur[s0 + 1] = excl; }
    excl += a1;
    if (s0 + 2 < SS) { rp[s0 + 2] = excl; cur[s0 + 2] = excl; }
    if (tid == 1023) rp[SS] = ls[1023];
}

// arc-balanced split into GB slices; boundaries forced EVEN so each slice is
// u64-exact in the packed-alpha array (per-producer u64 copy has no shared
// boundary words).
__global__ void k_split(const int* __restrict__ rp, int* __restrict__ split)
{
    int j = threadIdx.x;
    if (j > GB) return;
    if (j == 0)  { split[0] = 0; return; }
    if (j == GB) { split[GB] = SS; return; }   // SS even
    long long total = rp[SS];
    int target = (int)((total * j) / GB);
    int lo = 0, hi = SS;
    while (lo < hi) { int mid = (lo + hi) >> 1; if (rp[mid] >= target) hi = mid; else lo = mid + 1; }
    split[j] = lo & ~1;
}

// Per-slice counting sort of states by descending arc count. The permutation
// equalizes nit within each oct-group of 8 states (gather wave time = max nit
// over its 8 states -> max ~= mean after sorting). Shared by all groups.
__global__ void k_sortst(const int* __restrict__ rp, const int* __restrict__ split,
                         int* __restrict__ sordg)
{
    __shared__ int hist[64];
    __shared__ int off[64];
    int j = blockIdx.x;                      // slice 0..GB-1
    int s0 = split[j], s1 = split[j + 1];
    int nst = s1 - s0; if (nst > NSTMAX) nst = NSTMAX;
    int tid = threadIdx.x;                   // 256 threads
    if (tid < 64) hist[tid] = 0;
    __syncthreads();
    for (int i = tid; i < nst; i += 256) {
        int nit = (rp[s0 + i + 1] - rp[s0 + i]) >> 3;
        if (nit > 63) nit = 63;
        atomicAdd(&hist[nit], 1);
    }
    __syncthreads();
    if (tid == 0) {
        int acc = 0;
        for (int b = 63; b >= 0; --b) { off[b] = acc; acc += hist[b]; }
    }
    __syncthreads();
    for (int i = tid; i < nst; i += 256) {
        int nit = (rp[s0 + i + 1] - rp[s0 + i]) >> 3;
        if (nit > 63) nit = 63;
        int pos = atomicAdd(&off[nit], 1);
        sordg[j * NSTMAX + pos] = i;
    }
}

__global__ void k_scatter(const int* __restrict__ from_state, const int* __restrict__ to_state,
                          const int* __restrict__ pdf_id, const float* __restrict__ trans_logw,
                          int* __restrict__ cur, ArcT2* __restrict__ arcs)
{
    int e = blockIdx.x * blockDim.x + threadIdx.x;
    if (e >= EE) return;
    int s = to_state[e];
    int pos = atomicAdd(&cur[s], 1);
    ArcT2 a;
    a.idx = ((unsigned)from_state[e] << 2) | ((unsigned)pdf_id[e] << 18);
    a.ew = __expf(trans_logw[e]);
    arcs[pos] = a;
}

// Bank-aware in-place reorder (kept; small positive effect).
__global__ void k_sortbank(const int* __restrict__ rp, const int* __restrict__ counts,
                           ArcT2* __restrict__ arcs)
{
    int w = (blockIdx.x * blockDim.x + threadIdx.x) >> 6;
    int lane = threadIdx.x & 63;
    if (w >= SS) return;
    int n = counts[w];
    if (n < 2 || n > 64) return;
    int base = rp[w];
    bool valid = (lane < n);
    ArcT2 a;
    a.idx = 0; a.ew = 0.f;
    if (valid) a = arcs[base + lane];
    int c = valid ? (int)((a.idx >> 2) & 7) : -1;
    unsigned long long below = (1ull << lane) - 1ull;
    int ncArr[8];
    int myrank = 0;
    #pragma unroll
    for (int c8 = 0; c8 < 8; ++c8) {
        unsigned long long m = __ballot(valid && (c == c8));
        ncArr[c8] = (int)__popcll(m);
        if (c == c8) myrank = (int)__popcll(m & below);
    }
    int pos = -1;
    bool spill = false;
    if (valid) {
        int cap = (n > c) ? (((n - 1 - c) >> 3) + 1) : 0;
        if (myrank < cap) pos = c + (myrank << 3);
        else spill = true;
    }
    unsigned long long sm = __ballot(spill);
    if (spill) {
        int sr = (int)__popcll(sm & below);
        int accum = 0;
        #pragma unroll
        for (int c8 = 0; c8 < 8; ++c8) {
            int cap = (n > c8) ? (((n - 1 - c8) >> 3) + 1) : 0;
            int fr = cap - ncArr[c8]; if (fr < 0) fr = 0;
            if (pos < 0 && sr < accum + fr) {
                int kk = ncArr[c8] + (sr - accum);
                pos = c8 + (kk << 3);
            }
            accum += fr;
        }
    }
    if (valid) arcs[base + pos] = a;   // all lanes loaded before any store (same wave)
}

// ---------------- cooperative mega-kernel, verified XCD-local exchange ----------------
__global__ void __launch_bounds__(NT, 4) k_coop(
    const ArcT2* __restrict__ arcs, const int* __restrict__ rp,
    const int* __restrict__ split, const int* __restrict__ sordg,
    const float* __restrict__ input, const float* __restrict__ init_logp,
    const float* __restrict__ final_logp,
    float* __restrict__ partial,         // [NG][2]
    unsigned* __restrict__ A_all,        // [NG][2][ASTRD] packed 2xbf16
    unsigned* __restrict__ flags,        // [2][NBLK][FLGSTR]
    unsigned* __restrict__ xcdbuf,       // [NBLK]
    float* __restrict__ out)
{
    extern __shared__ char dsm[];
    unsigned* la32  = (unsigned*)(dsm + OFF_ALPHA);  // packed 2xbf16 per state
    unsigned* lex32 = (unsigned*)(dsm + OFF_EX);     // packed 2xbf16 per pdf
    ArcT2*    larc  = (ArcT2*)(dsm + OFF_ARC);
    int*      rbp   = (int*)(dsm + OFF_RBP);
    float*    redf  = (float*)(dsm + OFF_RED);
    int*      sh    = (int*)(dsm + OFF_SH);
    int*      sord  = (int*)(dsm + OFF_SORD);
    int*      lsp   = (int*)(dsm + OFF_LSP);

    int tid = threadIdx.x, bid = blockIdx.x;
    int x = bid & 7, y = (bid >> 3) & 3, j = bid >> 5;   // presumed-XCD, grp-in-XCD, member
    int g = x * 4 + y;                                   // group 0..31
    int lane = tid & 63, wave = tid >> 6;
    int oct = lane >> 3, sub = lane & 7;

    unsigned* Ag       = A_all + (size_t)g * (2 * ASTRD);
    unsigned* stepf    = flags;
    unsigned* auxf     = flags + (size_t)NBLK * FLGSTR;
    unsigned* myflag   = stepf + (size_t)(g * GB + j) * FLGSTR;
    unsigned* grpflag  = stepf + (size_t)(g * GB) * FLGSTR;
    unsigned* myflag2  = auxf + (size_t)(g * GB + j) * FLGSTR;
    unsigned* grpflag2 = auxf + (size_t)(g * GB) * FLGSTR;
    const float* inpG  = input + (size_t)(2 * g) * DD;

    int s0 = split[j], s1 = split[j + 1];
    int nst = s1 - s0;
    if (nst > NSTMAX) nst = NSTMAX;                      // safety (never expected)

    // ---- stage rp slice + sorted order + split + arcs to LDS ----
    for (int i = tid; i <= nst; i += NT) rbp[i] = rp[s0 + i];
    for (int i = tid; i < nst; i += NT) sord[i] = sordg[j * NSTMAX + i];
    if (tid <= GB) lsp[tid] = split[tid];
    __syncthreads();
    int rb0 = rbp[0];
    {
        int staged = rbp[nst] - rb0; if (staged > CAP) staged = CAP;
        for (int i = tid; i < staged; i += NT) larc[i] = arcs[rb0 + i];
    }

    // ---- publish XCC_ID (s_getreg id=20, offset=0, width=4 -> imm 6164) ----
    unsigned xcd = __builtin_amdgcn_s_getreg(6164) & 0xF;
    if (tid == 0)
        __hip_atomic_store(&xcdbuf[g * GB + j], xcd, __ATOMIC_RELAXED, __HIP_MEMORY_SCOPE_AGENT);
    __syncthreads();
    if (tid == 0)
        __hip_atomic_store(myflag2, 1u, __ATOMIC_RELAXED, __HIP_MEMORY_SCOPE_AGENT);
    // global aux barrier: wave0 polls all 256 aux flags (4 per lane)
    if (wave == 0) {
        while (true) {
            unsigned ok = 1;
            #pragma unroll
            for (int r = 0; r < 4; ++r) {
                unsigned v = __hip_atomic_load(auxf + (size_t)(lane * 4 + r) * FLGSTR,
                                               __ATOMIC_RELAXED, __HIP_MEMORY_SCOPE_AGENT);
                ok &= (v >= 1u);
            }
            if (__ballot(ok != 0) == ~0ULL) break;
            __builtin_amdgcn_s_sleep(1);
        }
    }
    __syncthreads();
    // decide protocol: fast iff my group is on ONE XCD and getreg is plausible
    {
        int* xint = (int*)redf;
        if (tid < NBLK)
            xint[tid] = (int)__hip_atomic_load(&xcdbuf[tid], __ATOMIC_RELAXED,
                                               __HIP_MEMORY_SCOPE_AGENT);
        __syncthreads();
        if (tid == 0) {
            int x0 = xint[g * GB];
            int uni = 1;
            for (int m = 1; m < GB; ++m) uni &= (xint[g * GB + m] == x0);
            int first = xint[0], distinct = 0;
            for (int i = 1; i < NBLK; ++i) distinct |= (xint[i] != first);
            sh[0] = uni && distinct;
        }
        __syncthreads();
    }
    const bool fast = (sh[0] != 0);
    __syncthreads();

    // Pipelined exchange (per step, after the post-gather barrier):
    //   every wave: build its 125-dword ex chunk for frame `fr`,
    //   then wave-pair p = wave>>1 polls producer p's flag and copies
    //   producer p's (u64-exact) alpha slice with 128 lanes of b64 loads.
    // Caller barriers after. No barrier between ex and copy.
    auto exchange = [&](unsigned epv, const unsigned* srcbuf, const float* fr) {
        {   // ex chunk: dwords [wave*EXCH, wave*EXCH+EXCH)
            int d0 = wave * EXCH;
            #pragma unroll
            for (int r = 0; r < 2; ++r) {
                int dd = r * 64 + lane;
                if (dd < EXCH) {
                    int d = d0 + dd;
                    lex32[d] = (unsigned)f2b(__expf(fr[d])) |
                               ((unsigned)f2b(__expf(fr[DD + d])) << 16);
                }
            }
        }
        int p = wave >> 1;
        const unsigned* gf = grpflag + (size_t)p * FLGSTR;
        if (fast) {
            while (*(volatile const unsigned*)gf < epv) { }
            int a = lsp[p] >> 1, b = lsp[p + 1] >> 1;    // u64 indices (even splits)
            const unsigned long long* src64 = (const unsigned long long*)srcbuf;
            unsigned long long* dst64 = (unsigned long long*)la32;
            for (int i = a + (wave & 1) * 64 + lane; i < b; i += 128)
                dst64[i] = *(volatile const unsigned long long*)(src64 + i);
        } else {
            while (__hip_atomic_load(gf, __ATOMIC_RELAXED, __HIP_MEMORY_SCOPE_AGENT) < epv)
                __builtin_amdgcn_s_sleep(1);
            int a = lsp[p] >> 1, b = lsp[p + 1] >> 1;
            const unsigned long long* src64 = (const unsigned long long*)srcbuf;
            unsigned long long* dst64 = (unsigned long long*)la32;
            for (int i = a + (wave & 1) * 64 + lane; i < b; i += 128)
                dst64[i] = __hip_atomic_load(src64 + i, __ATOMIC_RELAXED,
                                             __HIP_MEMORY_SCOPE_AGENT);
        }
    };

    // ---- alpha0 (own slice) with protocol-matched stores ----
    for (int i = tid; i < nst; i += NT) {
        int s = s0 + i;
        unsigned short h = f2b(__expf(init_logp[s]));
        unsigned pk = (unsigned)h | ((unsigned)h << 16);
        if (fast) Ag[s] = pk;                            // plain store -> shared L2
        else __hip_atomic_store(Ag + s, pk, __ATOMIC_RELAXED, __HIP_MEMORY_SCOPE_AGENT);
    }
    __syncthreads();                                     // stores drained
    unsigned ep = 1;
    if (tid == 0) {
        if (fast) *(volatile unsigned*)myflag = ep;
        else __hip_atomic_store(myflag, ep, __ATOMIC_RELAXED, __HIP_MEMORY_SCOPE_AGENT);
    }
    exchange(ep, Ag /* buffer 0 holds alpha0 */, inpG /* frame 0 */);
    __syncthreads();

    float vf0 = 0.f, vf1 = 0.f;

    // ---- 150 steps ----
    for (int k = 0; k < TT; ++k) {
        unsigned* An32 = Ag + ((k + 1) & 1) * ASTRD;
        bool last = (k == TT - 1);
        bool resc = (((k + 1) & (RESC - 1)) == 0);

        // gather own states via sorted order (8 lanes per state,
        // 8 states per wave; sorted -> max nit ~= mean nit within oct-group)
        for (int base = wave * 8; base < nst; base += 128) {
            int li = base + oct;
            bool has = (li < nst);
            float acc0 = 0.f, acc1 = 0.f;
            int sg = 0;
            if (has) {
                int so = sord[li];
                sg = s0 + so;
                int ra = rbp[so], re = rbp[so + 1];
                int nit = (re - ra) >> 3;
                if (re - rb0 <= CAP) {
                    int bix = ra - rb0 + sub;
                    for (int t = 0; t < nit; ++t) {
                        ArcT2 a = larc[bix + t * 8];
                        unsigned au = *(const unsigned*)(dsm + (a.idx & 0xFFFFu));
                        unsigned eu = *(const unsigned*)(dsm + OFF_EX + (a.idx >> 16));
                        acc0 = fmaf(u2f(au << 16), a.ew * u2f(eu << 16), acc0);
                        acc1 = fmaf(u2f(au & 0xFFFF0000u), a.ew * u2f(eu & 0xFFFF0000u), acc1);
                    }
                } else {
                    for (int t = 0; t < nit; ++t) {      // safety overflow path
                        ArcT2 a = arcs[ra + t * 8 + sub];
                        unsigned au = *(const unsigned*)(dsm + (a.idx & 0xFFFFu));
                        unsigned eu = *(const unsigned*)(dsm + OFF_EX + (a.idx >> 16));
                        acc0 = fmaf(u2f(au << 16), a.ew * u2f(eu << 16), acc0);
                        acc1 = fmaf(u2f(au & 0xFFFF0000u), a.ew * u2f(eu & 0xFFFF0000u), acc1);
                    }
                }
            }
            acc0 += __shfl_xor(acc0, 1, 64); acc1 += __shfl_xor(acc1, 1, 64);
            acc0 += __shfl_xor(acc0, 2, 64); acc1 += __shfl_xor(acc1, 2, 64);
            acc0 += __shfl_xor(acc0, 4, 64); acc1 += __shfl_xor(acc1, 4, 64);
            if (has && sub == 0) {
                if (resc) { acc0 *= RESCC; acc1 *= RESCC; }
                if (last) {
                    float ef = __expf(final_logp[sg]);
                    vf0 = fmaf(acc0, ef, vf0);
                    vf1 = fmaf(acc1, ef, vf1);
                } else {
                    unsigned pk = (unsigned)f2b(acc0) | ((unsigned)f2b(acc1) << 16);
                    if (fast) An32[sg] = pk;             // plain store -> shared L2
                    else __hip_atomic_store(An32 + sg, pk, __ATOMIC_RELAXED,
                                            __HIP_MEMORY_SCOPE_AGENT);
                }
            }
        }
        if (last) break;
        __syncthreads();                                 // stores drained (vmcnt 0)
        ++ep;
        if (tid == 0) {
            if (fast) *(volatile unsigned*)myflag = ep;
            else __hip_atomic_store(myflag, ep, __ATOMIC_RELAXED, __HIP_MEMORY_SCOPE_AGENT);
        }
        exchange(ep, An32, inpG + (size_t)(k + 1) * BB * DD);
        __syncthreads();
    }

    // ---- epilogue: reduce objf over this block's states ----
    if (sub == 0) {
        redf[(wave * 8 + oct) * 2 + 0] = vf0;
        redf[(wave * 8 + oct) * 2 + 1] = vf1;
    }
    __syncthreads();
    if (tid < 2) {
        float S = 0.f;
        for (int i = 0; i < 128; ++i) S += redf[i * 2 + tid];
        __hip_atomic_fetch_add(&partial[g * 2 + tid], S, __ATOMIC_RELAXED,
                               __HIP_MEMORY_SCOPE_AGENT);
    }
    __syncthreads();
    if (tid == 0)
        __hip_atomic_store(myflag2, 2u, __ATOMIC_RELAXED, __HIP_MEMORY_SCOPE_AGENT);
    if (j == 0) {
        if (wave == 0) {
            while (true) {
                unsigned v = 2;
                if (lane < GB)
                    v = __hip_atomic_load(grpflag2 + lane * FLGSTR, __ATOMIC_RELAXED,
                                          __HIP_MEMORY_SCOPE_AGENT);
                if (__ballot(v >= 2) == ~0ULL) break;
                __builtin_amdgcn_s_sleep(1);
            }
        }
        __syncthreads();
        if (tid < 2) {
            float S = __hip_atomic_load(&partial[g * 2 + tid], __ATOMIC_RELAXED,
                                        __HIP_MEMORY_SCOPE_AGENT);
            float lg = logf(S) + (float)(NSLOT * 46) * 0.69314718055994531f;
            atomicAdd(out, lg);
        }
    }
}

// ---------------- fallback path (round-6 per-step kernels) ----------------
template <int THREADS>
__device__ inline void transpose_exp_t(const float* __restrict__ frame,
                                       unsigned short* __restrict__ dst,
                                       int tile_id, int tid, unsigned short* smem)
{
    int d0 = tile_id * 64;
    #pragma unroll
    for (int it = 0; it < 4096 / THREADS; ++it) {
        int idx = it * THREADS + tid;
        int dl = idx & 63, bl = idx >> 6;
        int d = d0 + dl;
        float v = 0.f;
        if (d < DD) v = __expf(frame[bl * DD + d]);
        smem[dl * 65 + bl] = f2b(v);
    }
    __syncthreads();
    #pragma unroll
    for (int it = 0; it < 4096 / THREADS; ++it) {
        int idx = it * THREADS + tid;
        int bo = idx & 63, dq = idx >> 6;
        int d = d0 + dq;
        if (d < DD) dst[(d << 6) + bo] = smem[dq * 65 + bo];
    }
    __syncthreads();
}

__global__ void k_initA(const float* __restrict__ init_logp,
                        unsigned short* __restrict__ A0, float* __restrict__ M2)
{
    int idx = blockIdx.x * blockDim.x + threadIdx.x;
    if (idx < SS * BB) A0[idx] = f2b(__expf(init_logp[idx >> 6]));
    if (idx < NSLOT * 16 * 64) M2[idx] = 0.f;
}

__global__ void k_transpose0(const float* __restrict__ frame, unsigned short* __restrict__ dst)
{
    __shared__ unsigned short tile[64 * 65];
    transpose_exp_t<256>(frame, dst, blockIdx.x, threadIdx.x, tile);
}

__global__ void __launch_bounds__(256) k_step(
    const ArcT2* __restrict__ arcs, const int* __restrict__ rp,
    const unsigned short* __restrict__ Ap, unsigned short* __restrict__ An,
    const unsigned short* __restrict__ ec,
    const float* __restrict__ frameNext, unsigned short* __restrict__ en,
    float* __restrict__ M2, int maxSlot, int useSlot)
{
    __shared__ unsigned short tile[64 * 65];
    __shared__ float part[256];
    __shared__ float rcpA[64];
    int tid = threadIdx.x, bid = blockIdx.x;
    if (bid >= SS) { transpose_exp_t<256>(frameNext, en, bid - SS, tid, tile); return; }
    int lane = tid & 63, wave = tid >> 6;
    if (useSlot >= 0 && wave == 0) {
        const float* Mrow = M2 + useSlot * (16 * 64);
        float m = Mrow[lane];
        #pragma unroll
        for (int g = 1; g < 16; ++g) m = fmaxf(m, Mrow[g * 64 + lane]);
        rcpA[lane] = 1.0f / m;
    }
    int rbeg = rp[bid], rend = rp[bid + 1];
    float acc = 0.f;
    for (int i = rbeg + wave; i < rend; i += 4) {
        ArcT2 a = arcs[i];
        int from = (a.idx & 0xFFFF) >> 2, pdf = a.idx >> 18;
        acc = fmaf(b2f(Ap[(from << 6) + lane]), a.ew * b2f(ec[(pdf << 6) + lane]), acc);
    }
    part[tid] = acc;
    __syncthreads();
    if (wave == 0) {
        float sum = part[lane] + part[64 + lane] + part[128 + lane] + part[192 + lane];
        if (useSlot >= 0) sum *= rcpA[lane];
        An[(bid << 6) + lane] = f2b(sum);
        if (maxSlot >= 0)
            atomicMax((unsigned*)&M2[maxSlot * (16 * 64) + (bid & 15) * 64 + lane],
                      __float_as_uint(sum));
    }
}

__global__ void k_fin(const unsigned short* __restrict__ AT, const float* __restrict__ final_logp,
                      const float* __restrict__ M2, float* __restrict__ out)
{
    __shared__ float red[1024];
    int tid = threadIdx.x;
    int lane = tid & 63, chunk = tid >> 6;
    float psum = 0.f;
    for (int s = chunk; s < SS; s += 16)
        psum += b2f(AT[(s << 6) + lane]) * __expf(final_logp[s]);
    red[tid] = psum;
    __syncthreads();
    if (tid < 64) {
        float sum = 0.f;
        #pragma unroll
        for (int c = 0; c < 16; ++c) sum += red[c * 64 + tid];
        float lg = logf(sum);
        #pragma unroll
        for (int r = 0; r < NSLOT; ++r) {
            const float* Mrow = M2 + r * (16 * 64);
            float m = Mrow[tid];
            #pragma unroll
            for (int g = 1; g < 16; ++g) m = fmaxf(m, Mrow[g * 64 + tid]);
            lg += logf(m);
        }
        #pragma unroll
        for (int off = 32; off > 0; off >>= 1) lg += __shfl_down(lg, off);
        if (tid == 0) out[0] = lg;
    }
}

extern "C" void kernel_launch(void* const* d_in, const int* in_sizes, int n_in,
                              void* d_out, int out_size, void* d_ws, size_t ws_size,
                              hipStream_t stream)
{
    const float* input      = (const float*)d_in[0];
    const float* trans_logw = (const float*)d_in[1];
    const float* init_logp  = (const float*)d_in[2];
    const float* final_logp = (const float*)d_in[3];
    const int*   from_state = (const int*)d_in[4];
    const int*   to_state   = (const int*)d_in[5];
    const int*   pdf_id     = (const int*)d_in[6];
    float* out = (float*)d_out;

    char* ws = (char*)d_ws;
    size_t off = 0;
    auto alloc = [&](size_t bytes) -> char* {
        char* p = ws + off;
        off = (off + bytes + 255) & ~(size_t)255;
        return p;
    };
    ArcT2* arcs  = (ArcT2*)alloc((size_t)EEPAD * sizeof(ArcT2));
    int* rp      = (int*)alloc((size_t)(SS + 1) * 4);
    int* cur     = (int*)alloc((size_t)SS * 4);
    int* counts  = (int*)alloc((size_t)SS * 4);
    int* split   = (int*)alloc((size_t)(GB + 1) * 4);
    int* sordg   = (int*)alloc((size_t)GB * NSTMAX * 4);
    unsigned* A_all = (unsigned*)alloc((size_t)NG * 2 * ASTRD * 4);
    float* partial  = (float*)alloc((size_t)NG * 2 * 4);
    unsigned* flags = (unsigned*)alloc((size_t)2 * NBLK * FLGSTR * 4);
    unsigned* xcdbuf = (unsigned*)alloc((size_t)NBLK * 4);
    // fallback buffers
    unsigned short* A0  = (unsigned short*)alloc((size_t)SS * BB * 2);
    unsigned short* A1  = (unsigned short*)alloc((size_t)SS * BB * 2);
    unsigned short* EX0 = (unsigned short*)alloc((size_t)DD * BB * 2);
    unsigned short* EX1 = (unsigned short*)alloc((size_t)DD * BB * 2);
    float* M2    = (float*)alloc((size_t)NSLOT * 16 * 64 * 4);
    (void)ws_size; (void)in_sizes; (void)n_in; (void)out_size;

    k_init0<<<64, 256, 0, stream>>>(counts, flags, partial);
    k_zeroarcs<<<(EEPAD + 255) / 256, 256, 0, stream>>>(arcs);
    k_hist<<<(EE + 255) / 256, 256, 0, stream>>>(to_state, counts);
    k_scan<<<1, 1024, 0, stream>>>(counts, rp, cur);
    k_split<<<1, 16, 0, stream>>>(rp, split);
    k_sortst<<<GB, 256, 0, stream>>>(rp, split, sordg);
    k_scatter<<<(EE + 255) / 256, 256, 0, stream>>>(from_state, to_state, pdf_id,
                                                    trans_logw, cur, arcs);
    k_sortbank<<<(SS * 64 + 255) / 256, 256, 0, stream>>>(rp, counts, arcs);
    hipMemsetAsync(d_out, 0, sizeof(float), stream);

    hipFuncSetAttribute((const void*)k_coop, hipFuncAttributeMaxDynamicSharedMemorySize,
                        DYNLDS);
    int nb = 0;
    hipOccupancyMaxActiveBlocksPerMultiprocessor(&nb, (const void*)k_coop, NT, DYNLDS);
    if (nb >= 1) {
        void* kp[12] = {
            (void*)&arcs, (void*)&rp, (void*)&split, (void*)&sordg, (void*)&input,
            (void*)&init_logp, (void*)&final_logp, (void*)&partial, (void*)&A_all,
            (void*)&flags, (void*)&xcdbuf, (void*)&out
        };
        hipError_t e = hipLaunchCooperativeKernel((const void*)k_coop, dim3(NBLK), dim3(NT),
                                                  kp, DYNLDS, stream);
        if (e == hipSuccess) return;
    }

    // Fallback: per-step kernels (bf16 state), known-passing structure.
    k_initA<<<(SS * BB + 255) / 256, 256, 0, stream>>>(init_logp, A0, M2);
    k_transpose0<<<NEXB, 256, 0, stream>>>(input, EX0);
    unsigned short* A[2]  = {A0, A1};
    unsigned short* EX[2] = {EX0, EX1};
    for (int k = 0; k < TT; ++k) {
        int kn = k + 1;
        int useSlot = (k > 0 && (k % RESC) == 0) ? (k / RESC - 1) : -1;
        int maxSlot = (kn < TT && (kn % RESC) == 0) ? (kn / RESC - 1) : -1;
        int grid = SS + ((kn < TT) ? NEXB : 0);
        const float* fnext = (kn < TT) ? (input + (size_t)kn * BB * DD) : nullptr;
        k_step<<<grid, 256, 0, stream>>>(arcs, rp, A[k & 1], A[kn & 1], EX[k & 1],
                                         fnext, EX[kn & 1], M2, maxSlot, useSlot);
    }
    k_fin<<<1, 1024, 0, stream>>>(A[TT & 1], final_logp, M2, out);
}

// Round 6
// 827.439 us; speedup vs baseline: 1.2057x; 1.0575x over previous
//
#include <hip/hip_runtime.h>
#include <math.h>

#define TT 150
#define BB 64
#define DD 2000
#define SS 3000
#define EE 100000
#define EEPAD 124160   // >= EE + SS*7 (arcs padded per-state to multiple of 8)
#define RESC 16
#define NSLOT 9
#define RESCC 0x1p-46f // exact pow2 rescale every 16 steps (growth ~7.42^16 ~= 2^46.3)

#define NT 1024        // threads per block (16 waves)
#define NBLK 256       // 1 block per CU
#define NG 32          // groups, 2 batch lanes each
#define GB 8           // blocks per group (same XCD iff bid%8 maps to XCD)
#define CAP 14336      // LDS arc slots per block (max slice ~13.9k)
#define ASTRD 3072     // dwords per alpha buffer per group (SS=3000 padded)
#define NSTMAX 2048
#define FLGSTR 32      // dwords between flags (128 B)
#define NEXB 32
#define EXCH 125       // ex dwords per wave (16*125 = 2000 = DD)

// dynamic LDS layout (bytes). Alpha table at byte 0 so the gather's
// ds_read address is just (idx & 0xFFFF); ex base 12288 folds into the
// ds_read offset immediate.
#define OFF_ALPHA  0                 // SS*4 -> 12288 (packed 2xbf16 per state)
#define OFF_EX     12288             // DD*4 -> 8192  (packed 2xbf16 per pdf)
#define OFF_ARC    20480             // CAP*8 = 114688
#define OFF_RBP    135168            // (NSTMAX+1)*4 -> 8208
#define OFF_RED    143376            // 256*4 = 1024
#define OFF_SH     144400            // 16
#define OFF_SORD   144416            // NSTMAX*4 = 8192
#define OFF_LSP    152608            // (GB+1)*4 -> 48
#define DYNLDS     152656

// idx = (from<<2) | (pdf<<18): both halves are ready-made BYTE offsets into
// the packed-u32 LDS tables (from*4 <= 11996 fits 14 bits; pdf*4 <= 7996).
struct __align__(8) ArcT2 { unsigned idx; float ew; };

__device__ inline float b2f(unsigned short u) {
    union { unsigned u32; float f; } x; x.u32 = ((unsigned)u) << 16; return x.f;
}
__device__ inline unsigned short f2b(float f) {
    union { float f; unsigned u; } x; x.f = f;
    unsigned r = x.u + 0x7FFF + ((x.u >> 16) & 1);       // RNE, positive finite only
    return (unsigned short)(r >> 16);
}
__device__ inline float u2f(unsigned u) {
    union { unsigned u32; float f; } x; x.u32 = u; return x.f;
}

// ---------------- setup kernels ----------------
__global__ void k_init0(int* __restrict__ counts, unsigned* __restrict__ flags,
                        float* __restrict__ partial)
{
    int i = blockIdx.x * blockDim.x + threadIdx.x;
    if (i < SS) counts[i] = 0;
    if (i < 2 * NBLK * FLGSTR) flags[i] = 0u;
    if (i < NG * 2) partial[i] = 0.f;
}

__global__ void k_zeroarcs(ArcT2* __restrict__ arcs)
{
    int i = blockIdx.x * blockDim.x + threadIdx.x;
    if (i < EEPAD) { ArcT2 z; z.idx = 0; z.ew = 0.f; arcs[i] = z; }
}

__global__ void k_hist(const int* __restrict__ to_state, int* __restrict__ counts)
{
    int e = blockIdx.x * blockDim.x + threadIdx.x;
    if (e < EE) atomicAdd(&counts[to_state[e]], 1);
}

// prefix over counts padded to multiple of 8
__global__ void k_scan(const int* __restrict__ counts, int* __restrict__ rp,
                       int* __restrict__ cur)
{
    __shared__ int ls[1024];
    int tid = threadIdx.x;
    int s0 = tid * 3;
    int a0 = (s0 + 0 < SS) ? ((counts[s0 + 0] + 7) & ~7) : 0;
    int a1 = (s0 + 1 < SS) ? ((counts[s0 + 1] + 7) & ~7) : 0;
    int a2 = (s0 + 2 < SS) ? ((counts[s0 + 2] + 7) & ~7) : 0;
    int tsum = a0 + a1 + a2;
    ls[tid] = tsum;
    __syncthreads();
    for (int off = 1; off < 1024; off <<= 1) {
        int v = ls[tid];
        int add = (tid >= off) ? ls[tid - off] : 0;
        __syncthreads();
        ls[tid] = v + add;
        __syncthreads();
    }
    int excl = ls[tid] - tsum;
    if (s0 + 0 < SS) { rp[s0 + 0] = excl; cur[s0 + 0] = excl; }
    excl += a0;
    if (s0 + 1 < SS) { rp[s0 + 1] = excl; cur[s0 + 1] = excl; }
    excl += a1;
    if (s0 + 2 < SS) { rp[s0 + 2] = excl; cur[s0 + 2] = excl; }
    if (tid == 1023) rp[SS] = ls[1023];
}

// arc-balanced split into GB slices; boundaries forced EVEN so each slice is
// u64-exact in the packed-alpha array (per-producer u64 copy has no shared
// boundary words).
__global__ void k_split(const int* __restrict__ rp, int* __restrict__ split)
{
    int j = threadIdx.x;
    if (j > GB) return;
    if (j == 0)  { split[0] = 0; return; }
    if (j == GB) { split[GB] = SS; return; }   // SS even
    long long total = rp[SS];
    int target = (int)((total * j) / GB);
    int lo = 0, hi = SS;
    while (lo < hi) { int mid = (lo + hi) >> 1; if (rp[mid] >= target) hi = mid; else lo = mid + 1; }
    split[j] = lo & ~1;
}

// Per-slice counting sort of states by descending arc count. The permutation
// equalizes nit within each oct-group of 8 states (gather wave time = max nit
// over its 8 states -> max ~= mean after sorting). Shared by all groups.
__global__ void k_sortst(const int* __restrict__ rp, const int* __restrict__ split,
                         int* __restrict__ sordg)
{
    __shared__ int hist[64];
    __shared__ int off[64];
    int j = blockIdx.x;                      // slice 0..GB-1
    int s0 = split[j], s1 = split[j + 1];
    int nst = s1 - s0; if (nst > NSTMAX) nst = NSTMAX;
    int tid = threadIdx.x;                   // 256 threads
    if (tid < 64) hist[tid] = 0;
    __syncthreads();
    for (int i = tid; i < nst; i += 256) {
        int nit = (rp[s0 + i + 1] - rp[s0 + i]) >> 3;
        if (nit > 63) nit = 63;
        atomicAdd(&hist[nit], 1);
    }
    __syncthreads();
    if (tid == 0) {
        int acc = 0;
        for (int b = 63; b >= 0; --b) { off[b] = acc; acc += hist[b]; }
    }
    __syncthreads();
    for (int i = tid; i < nst; i += 256) {
        int nit = (rp[s0 + i + 1] - rp[s0 + i]) >> 3;
        if (nit > 63) nit = 63;
        int pos = atomicAdd(&off[nit], 1);
        sordg[j * NSTMAX + pos] = i;
    }
}

__global__ void k_scatter(const int* __restrict__ from_state, const int* __restrict__ to_state,
                          const int* __restrict__ pdf_id, const float* __restrict__ trans_logw,
                          int* __restrict__ cur, ArcT2* __restrict__ arcs)
{
    int e = blockIdx.x * blockDim.x + threadIdx.x;
    if (e >= EE) return;
    int s = to_state[e];
    int pos = atomicAdd(&cur[s], 1);
    ArcT2 a;
    a.idx = ((unsigned)from_state[e] << 2) | ((unsigned)pdf_id[e] << 18);
    a.ew = __expf(trans_logw[e]);
    arcs[pos] = a;
}

// Bank-aware in-place reorder (kept; small positive effect).
__global__ void k_sortbank(const int* __restrict__ rp, const int* __restrict__ counts,
                           ArcT2* __restrict__ arcs)
{
    int w = (blockIdx.x * blockDim.x + threadIdx.x) >> 6;
    int lane = threadIdx.x & 63;
    if (w >= SS) return;
    int n = counts[w];
    if (n < 2 || n > 64) return;
    int base = rp[w];
    bool valid = (lane < n);
    ArcT2 a;
    a.idx = 0; a.ew = 0.f;
    if (valid) a = arcs[base + lane];
    int c = valid ? (int)((a.idx >> 2) & 7) : -1;
    unsigned long long below = (1ull << lane) - 1ull;
    int ncArr[8];
    int myrank = 0;
    #pragma unroll
    for (int c8 = 0; c8 < 8; ++c8) {
        unsigned long long m = __ballot(valid && (c == c8));
        ncArr[c8] = (int)__popcll(m);
        if (c == c8) myrank = (int)__popcll(m & below);
    }
    int pos = -1;
    bool spill = false;
    if (valid) {
        int cap = (n > c) ? (((n - 1 - c) >> 3) + 1) : 0;
        if (myrank < cap) pos = c + (myrank << 3);
        else spill = true;
    }
    unsigned long long sm = __ballot(spill);
    if (spill) {
        int sr = (int)__popcll(sm & below);
        int accum = 0;
        #pragma unroll
        for (int c8 = 0; c8 < 8; ++c8) {
            int cap = (n > c8) ? (((n - 1 - c8) >> 3) + 1) : 0;
            int fr = cap - ncArr[c8]; if (fr < 0) fr = 0;
            if (pos < 0 && sr < accum + fr) {
                int kk = ncArr[c8] + (sr - accum);
                pos = c8 + (kk << 3);
            }
            accum += fr;
        }
    }
    if (valid) arcs[base + pos] = a;   // all lanes loaded before any store (same wave)
}

// ---------------- cooperative mega-kernel, verified XCD-local exchange ----------------
__global__ void __launch_bounds__(NT, 4) k_coop(
    const ArcT2* __restrict__ arcs, const int* __restrict__ rp,
    const int* __restrict__ split, const int* __restrict__ sordg,
    const float* __restrict__ input, const float* __restrict__ init_logp,
    const float* __restrict__ final_logp,
    float* __restrict__ partial,         // [NG][2]
    unsigned* __restrict__ A_all,        // [NG][2][ASTRD] packed 2xbf16
    unsigned* __restrict__ flags,        // [2][NBLK][FLGSTR]
    unsigned* __restrict__ xcdbuf,       // [NBLK]
    float* __restrict__ out)
{
    extern __shared__ char dsm[];
    unsigned* la32  = (unsigned*)(dsm + OFF_ALPHA);  // packed 2xbf16 per state
    unsigned* lex32 = (unsigned*)(dsm + OFF_EX);     // packed 2xbf16 per pdf
    ArcT2*    larc  = (ArcT2*)(dsm + OFF_ARC);
    int*      rbp   = (int*)(dsm + OFF_RBP);
    float*    redf  = (float*)(dsm + OFF_RED);
    int*      sh    = (int*)(dsm + OFF_SH);
    int*      sord  = (int*)(dsm + OFF_SORD);
    int*      lsp   = (int*)(dsm + OFF_LSP);

    int tid = threadIdx.x, bid = blockIdx.x;
    int x = bid & 7, y = (bid >> 3) & 3, j = bid >> 5;   // presumed-XCD, grp-in-XCD, member
    int g = x * 4 + y;                                   // group 0..31
    int lane = tid & 63, wave = tid >> 6;
    int oct = lane >> 3, sub = lane & 7;

    unsigned* Ag       = A_all + (size_t)g * (2 * ASTRD);
    unsigned* stepf    = flags;
    unsigned* auxf     = flags + (size_t)NBLK * FLGSTR;
    unsigned* myflag   = stepf + (size_t)(g * GB + j) * FLGSTR;
    unsigned* grpflag  = stepf + (size_t)(g * GB) * FLGSTR;
    unsigned* myflag2  = auxf + (size_t)(g * GB + j) * FLGSTR;
    unsigned* grpflag2 = auxf + (size_t)(g * GB) * FLGSTR;
    const float* inpG  = input + (size_t)(2 * g) * DD;

    int s0 = split[j], s1 = split[j + 1];
    int nst = s1 - s0;
    if (nst > NSTMAX) nst = NSTMAX;                      // safety (never expected)

    // ---- stage rp slice + sorted order + split + arcs to LDS ----
    for (int i = tid; i <= nst; i += NT) rbp[i] = rp[s0 + i];
    for (int i = tid; i < nst; i += NT) sord[i] = sordg[j * NSTMAX + i];
    if (tid <= GB) lsp[tid] = split[tid];
    __syncthreads();
    int rb0 = rbp[0];
    {
        int staged = rbp[nst] - rb0; if (staged > CAP) staged = CAP;
        for (int i = tid; i < staged; i += NT) larc[i] = arcs[rb0 + i];
    }

    // ---- publish XCC_ID (s_getreg id=20, offset=0, width=4 -> imm 6164) ----
    unsigned xcd = __builtin_amdgcn_s_getreg(6164) & 0xF;
    if (tid == 0)
        __hip_atomic_store(&xcdbuf[g * GB + j], xcd, __ATOMIC_RELAXED, __HIP_MEMORY_SCOPE_AGENT);
    __syncthreads();
    if (tid == 0)
        __hip_atomic_store(myflag2, 1u, __ATOMIC_RELAXED, __HIP_MEMORY_SCOPE_AGENT);
    // global aux barrier: wave0 polls all 256 aux flags (4 per lane)
    if (wave == 0) {
        while (true) {
            unsigned ok = 1;
            #pragma unroll
            for (int r = 0; r < 4; ++r) {
                unsigned v = __hip_atomic_load(auxf + (size_t)(lane * 4 + r) * FLGSTR,
                                               __ATOMIC_RELAXED, __HIP_MEMORY_SCOPE_AGENT);
                ok &= (v >= 1u);
            }
            if (__ballot(ok != 0) == ~0ULL) break;
            __builtin_amdgcn_s_sleep(1);
        }
    }
    __syncthreads();
    // decide protocol: fast iff my group is on ONE XCD and getreg is plausible
    {
        int* xint = (int*)redf;
        if (tid < NBLK)
            xint[tid] = (int)__hip_atomic_load(&xcdbuf[tid], __ATOMIC_RELAXED,
                                               __HIP_MEMORY_SCOPE_AGENT);
        __syncthreads();
        if (tid == 0) {
            int x0 = xint[g * GB];
            int uni = 1;
            for (int m = 1; m < GB; ++m) uni &= (xint[g * GB + m] == x0);
            int first = xint[0], distinct = 0;
            for (int i = 1; i < NBLK; ++i) distinct |= (xint[i] != first);
            sh[0] = uni && distinct;
        }
        __syncthreads();
    }
    const bool fast = (sh[0] != 0);
    __syncthreads();

    // Register prefetch of this thread's 4 next-frame floats (issued BEFORE the
    // gather; the data arrives during it, so the exchange's ex-build is pure
    // VALU instead of a serialized L3/HBM latency exposure).
    float pf0[2], pf1[2];
    auto prefetch = [&](const float* fr) {
        int d0 = wave * EXCH;
        #pragma unroll
        for (int r = 0; r < 2; ++r) {
            int dd = r * 64 + lane;
            if (dd < EXCH) {
                int d = d0 + dd;
                pf0[r] = fr[d];
                pf1[r] = fr[DD + d];
            }
        }
    };

    // Pipelined exchange (per step, after the post-gather barrier):
    //   every wave: pack+store its 125-dword ex chunk from prefetched regs,
    //   then wave-pair p = wave>>1 polls producer p's flag and copies
    //   producer p's (u64-exact) alpha slice with 128 lanes of b64 loads.
    // Caller barriers after. No barrier between ex and copy.
    auto exchange = [&](unsigned epv, const unsigned* srcbuf) {
        {   // ex chunk: dwords [wave*EXCH, wave*EXCH+EXCH), from prefetched regs
            int d0 = wave * EXCH;
            #pragma unroll
            for (int r = 0; r < 2; ++r) {
                int dd = r * 64 + lane;
                if (dd < EXCH) {
                    int d = d0 + dd;
                    lex32[d] = (unsigned)f2b(__expf(pf0[r])) |
                               ((unsigned)f2b(__expf(pf1[r])) << 16);
                }
            }
        }
        int p = wave >> 1;
        const unsigned* gf = grpflag + (size_t)p * FLGSTR;
        if (fast) {
            while (*(volatile const unsigned*)gf < epv) { }
            int a = lsp[p] >> 1, b = lsp[p + 1] >> 1;    // u64 indices (even splits)
            const unsigned long long* src64 = (const unsigned long long*)srcbuf;
            unsigned long long* dst64 = (unsigned long long*)la32;
            for (int i = a + (wave & 1) * 64 + lane; i < b; i += 128)
                dst64[i] = *(volatile const unsigned long long*)(src64 + i);
        } else {
            while (__hip_atomic_load(gf, __ATOMIC_RELAXED, __HIP_MEMORY_SCOPE_AGENT) < epv)
                __builtin_amdgcn_s_sleep(1);
            int a = lsp[p] >> 1, b = lsp[p + 1] >> 1;
            const unsigned long long* src64 = (const unsigned long long*)srcbuf;
            unsigned long long* dst64 = (unsigned long long*)la32;
            for (int i = a + (wave & 1) * 64 + lane; i < b; i += 128)
                dst64[i] = __hip_atomic_load(src64 + i, __ATOMIC_RELAXED,
                                             __HIP_MEMORY_SCOPE_AGENT);
        }
    };

    // ---- alpha0 (own slice) with protocol-matched stores ----
    prefetch(inpG);                                      // frame 0 (issue early)
    for (int i = tid; i < nst; i += NT) {
        int s = s0 + i;
        unsigned short h = f2b(__expf(init_logp[s]));
        unsigned pk = (unsigned)h | ((unsigned)h << 16);
        if (fast) Ag[s] = pk;                            // plain store -> shared L2
        else __hip_atomic_store(Ag + s, pk, __ATOMIC_RELAXED, __HIP_MEMORY_SCOPE_AGENT);
    }
    __syncthreads();                                     // stores drained
    unsigned ep = 1;
    if (tid == 0) {
        if (fast) *(volatile unsigned*)myflag = ep;
        else __hip_atomic_store(myflag, ep, __ATOMIC_RELAXED, __HIP_MEMORY_SCOPE_AGENT);
    }
    exchange(ep, Ag /* buffer 0 holds alpha0 */);
    __syncthreads();

    float vf0 = 0.f, vf1 = 0.f;

    // ---- 150 steps ----
    for (int k = 0; k < TT; ++k) {
        unsigned* An32 = Ag + ((k + 1) & 1) * ASTRD;
        bool last = (k == TT - 1);
        bool resc = (((k + 1) & (RESC - 1)) == 0);

        if (!last) prefetch(inpG + (size_t)(k + 1) * BB * DD);  // issue next frame

        // gather own states via sorted order (8 lanes per state,
        // 8 states per wave; sorted -> max nit ~= mean nit within oct-group)
        for (int base = wave * 8; base < nst; base += 128) {
            int li = base + oct;
            bool has = (li < nst);
            float acc0 = 0.f, acc1 = 0.f;
            int sg = 0;
            if (has) {
                int so = sord[li];
                sg = s0 + so;
                int ra = rbp[so], re = rbp[so + 1];
                int nit = (re - ra) >> 3;
                if (re - rb0 <= CAP) {
                    int bix = ra - rb0 + sub;
                    for (int t = 0; t < nit; ++t) {
                        ArcT2 a = larc[bix + t * 8];
                        unsigned au = *(const unsigned*)(dsm + (a.idx & 0xFFFFu));
                        unsigned eu = *(const unsigned*)(dsm + OFF_EX + (a.idx >> 16));
                        acc0 = fmaf(u2f(au << 16), a.ew * u2f(eu << 16), acc0);
                        acc1 = fmaf(u2f(au & 0xFFFF0000u), a.ew * u2f(eu & 0xFFFF0000u), acc1);
                    }
                } else {
                    for (int t = 0; t < nit; ++t) {      // safety overflow path
                        ArcT2 a = arcs[ra + t * 8 + sub];
                        unsigned au = *(const unsigned*)(dsm + (a.idx & 0xFFFFu));
                        unsigned eu = *(const unsigned*)(dsm + OFF_EX + (a.idx >> 16));
                        acc0 = fmaf(u2f(au << 16), a.ew * u2f(eu << 16), acc0);
                        acc1 = fmaf(u2f(au & 0xFFFF0000u), a.ew * u2f(eu & 0xFFFF0000u), acc1);
                    }
                }
            }
            acc0 += __shfl_xor(acc0, 1, 64); acc1 += __shfl_xor(acc1, 1, 64);
            acc0 += __shfl_xor(acc0, 2, 64); acc1 += __shfl_xor(acc1, 2, 64);
            acc0 += __shfl_xor(acc0, 4, 64); acc1 += __shfl_xor(acc1, 4, 64);
            if (has && sub == 0) {
                if (resc) { acc0 *= RESCC; acc1 *= RESCC; }
                if (last) {
                    float ef = __expf(final_logp[sg]);
                    vf0 = fmaf(acc0, ef, vf0);
                    vf1 = fmaf(acc1, ef, vf1);
                } else {
                    unsigned pk = (unsigned)f2b(acc0) | ((unsigned)f2b(acc1) << 16);
                    if (fast) An32[sg] = pk;             // plain store -> shared L2
                    else __hip_atomic_store(An32 + sg, pk, __ATOMIC_RELAXED,
                                            __HIP_MEMORY_SCOPE_AGENT);
                }
            }
        }
        if (last) break;
        __syncthreads();                                 // stores drained (vmcnt 0)
        ++ep;
        if (tid == 0) {
            if (fast) *(volatile unsigned*)myflag = ep;
            else __hip_atomic_store(myflag, ep, __ATOMIC_RELAXED, __HIP_MEMORY_SCOPE_AGENT);
        }
        exchange(ep, An32);
        __syncthreads();
    }

    // ---- epilogue: reduce objf over this block's states ----
    if (sub == 0) {
        redf[(wave * 8 + oct) * 2 + 0] = vf0;
        redf[(wave * 8 + oct) * 2 + 1] = vf1;
    }
    __syncthreads();
    if (tid < 2) {
        float S = 0.f;
        for (int i = 0; i < 128; ++i) S += redf[i * 2 + tid];
        __hip_atomic_fetch_add(&partial[g * 2 + tid], S, __ATOMIC_RELAXED,
                               __HIP_MEMORY_SCOPE_AGENT);
    }
    __syncthreads();
    if (tid == 0)
        __hip_atomic_store(myflag2, 2u, __ATOMIC_RELAXED, __HIP_MEMORY_SCOPE_AGENT);
    if (j == 0) {
        if (wave == 0) {
            while (true) {
                unsigned v = 2;
                if (lane < GB)
                    v = __hip_atomic_load(grpflag2 + lane * FLGSTR, __ATOMIC_RELAXED,
                                          __HIP_MEMORY_SCOPE_AGENT);
                if (__ballot(v >= 2) == ~0ULL) break;
                __builtin_amdgcn_s_sleep(1);
            }
        }
        __syncthreads();
        if (tid < 2) {
            float S = __hip_atomic_load(&partial[g * 2 + tid], __ATOMIC_RELAXED,
                                        __HIP_MEMORY_SCOPE_AGENT);
            float lg = logf(S) + (float)(NSLOT * 46) * 0.69314718055994531f;
            atomicAdd(out, lg);
        }
    }
}

// ---------------- fallback path (round-6 per-step kernels) ----------------
template <int THREADS>
__device__ inline void transpose_exp_t(const float* __restrict__ frame,
                                       unsigned short* __restrict__ dst,
                                       int tile_id, int tid, unsigned short* smem)
{
    int d0 = tile_id * 64;
    #pragma unroll
    for (int it = 0; it < 4096 / THREADS; ++it) {
        int idx = it * THREADS + tid;
        int dl = idx & 63, bl = idx >> 6;
        int d = d0 + dl;
        float v = 0.f;
        if (d < DD) v = __expf(frame[bl * DD + d]);
        smem[dl * 65 + bl] = f2b(v);
    }
    __syncthreads();
    #pragma unroll
    for (int it = 0; it < 4096 / THREADS; ++it) {
        int idx = it * THREADS + tid;
        int bo = idx & 63, dq = idx >> 6;
        int d = d0 + dq;
        if (d < DD) dst[(d << 6) + bo] = smem[dq * 65 + bo];
    }
    __syncthreads();
}

__global__ void k_initA(const float* __restrict__ init_logp,
                        unsigned short* __restrict__ A0, float* __restrict__ M2)
{
    int idx = blockIdx.x * blockDim.x + threadIdx.x;
    if (idx < SS * BB) A0[idx] = f2b(__expf(init_logp[idx >> 6]));
    if (idx < NSLOT * 16 * 64) M2[idx] = 0.f;
}

__global__ void k_transpose0(const float* __restrict__ frame, unsigned short* __restrict__ dst)
{
    __shared__ unsigned short tile[64 * 65];
    transpose_exp_t<256>(frame, dst, blockIdx.x, threadIdx.x, tile);
}

__global__ void __launch_bounds__(256) k_step(
    const ArcT2* __restrict__ arcs, const int* __restrict__ rp,
    const unsigned short* __restrict__ Ap, unsigned short* __restrict__ An,
    const unsigned short* __restrict__ ec,
    const float* __restrict__ frameNext, unsigned short* __restrict__ en,
    float* __restrict__ M2, int maxSlot, int useSlot)
{
    __shared__ unsigned short tile[64 * 65];
    __shared__ float part[256];
    __shared__ float rcpA[64];
    int tid = threadIdx.x, bid = blockIdx.x;
    if (bid >= SS) { transpose_exp_t<256>(frameNext, en, bid - SS, tid, tile); return; }
    int lane = tid & 63, wave = tid >> 6;
    if (useSlot >= 0 && wave == 0) {
        const float* Mrow = M2 + useSlot * (16 * 64);
        float m = Mrow[lane];
        #pragma unroll
        for (int g = 1; g < 16; ++g) m = fmaxf(m, Mrow[g * 64 + lane]);
        rcpA[lane] = 1.0f / m;
    }
    int rbeg = rp[bid], rend = rp[bid + 1];
    float acc = 0.f;
    for (int i = rbeg + wave; i < rend; i += 4) {
        ArcT2 a = arcs[i];
        int from = (a.idx & 0xFFFF) >> 2, pdf = a.idx >> 18;
        acc = fmaf(b2f(Ap[(from << 6) + lane]), a.ew * b2f(ec[(pdf << 6) + lane]), acc);
    }
    part[tid] = acc;
    __syncthreads();
    if (wave == 0) {
        float sum = part[lane] + part[64 + lane] + part[128 + lane] + part[192 + lane];
        if (useSlot >= 0) sum *= rcpA[lane];
        An[(bid << 6) + lane] = f2b(sum);
        if (maxSlot >= 0)
            atomicMax((unsigned*)&M2[maxSlot * (16 * 64) + (bid & 15) * 64 + lane],
                      __float_as_uint(sum));
    }
}

__global__ void k_fin(const unsigned short* __restrict__ AT, const float* __restrict__ final_logp,
                      const float* __restrict__ M2, float* __restrict__ out)
{
    __shared__ float red[1024];
    int tid = threadIdx.x;
    int lane = tid & 63, chunk = tid >> 6;
    float psum = 0.f;
    for (int s = chunk; s < SS; s += 16)
        psum += b2f(AT[(s << 6) + lane]) * __expf(final_logp[s]);
    red[tid] = psum;
    __syncthreads();
    if (tid < 64) {
        float sum = 0.f;
        #pragma unroll
        for (int c = 0; c < 16; ++c) sum += red[c * 64 + tid];
        float lg = logf(sum);
        #pragma unroll
        for (int r = 0; r < NSLOT; ++r) {
            const float* Mrow = M2 + r * (16 * 64);
            float m = Mrow[tid];
            #pragma unroll
            for (int g = 1; g < 16; ++g) m = fmaxf(m, Mrow[g * 64 + tid]);
            lg += logf(m);
        }
        #pragma unroll
        for (int off = 32; off > 0; off >>= 1) lg += __shfl_down(lg, off);
        if (tid == 0) out[0] = lg;
    }
}

extern "C" void kernel_launch(void* const* d_in, const int* in_sizes, int n_in,
                              void* d_out, int out_size, void* d_ws, size_t ws_size,
                              hipStream_t stream)
{
    const float* input      = (const float*)d_in[0];
    const float* trans_logw = (const float*)d_in[1];
    const float* init_logp  = (const float*)d_in[2];
    const float* final_logp = (const float*)d_in[3];
    const int*   from_state = (const int*)d_in[4];
    const int*   to_state   = (const int*)d_in[5];
    const int*   pdf_id     = (const int*)d_in[6];
    float* out = (float*)d_out;

    char* ws = (char*)d_ws;
    size_t off = 0;
    auto alloc = [&](size_t bytes) -> char* {
        char* p = ws + off;
        off = (off + bytes + 255) & ~(size_t)255;
        return p;
    };
    ArcT2* arcs  = (ArcT2*)alloc((size_t)EEPAD * sizeof(ArcT2));
    int* rp      = (int*)alloc((size_t)(SS + 1) * 4);
    int* cur     = (int*)alloc((size_t)SS * 4);
    int* counts  = (int*)alloc((size_t)SS * 4);
    int* split   = (int*)alloc((size_t)(GB + 1) * 4);
    int* sordg   = (int*)alloc((size_t)GB * NSTMAX * 4);
    unsigned* A_all = (unsigned*)alloc((size_t)NG * 2 * ASTRD * 4);
    float* partial  = (float*)alloc((size_t)NG * 2 * 4);
    unsigned* flags = (unsigned*)alloc((size_t)2 * NBLK * FLGSTR * 4);
    unsigned* xcdbuf = (unsigned*)alloc((size_t)NBLK * 4);
    // fallback buffers
    unsigned short* A0  = (unsigned short*)alloc((size_t)SS * BB * 2);
    unsigned short* A1  = (unsigned short*)alloc((size_t)SS * BB * 2);
    unsigned short* EX0 = (unsigned short*)alloc((size_t)DD * BB * 2);
    unsigned short* EX1 = (unsigned short*)alloc((size_t)DD * BB * 2);
    float* M2    = (float*)alloc((size_t)NSLOT * 16 * 64 * 4);
    (void)ws_size; (void)in_sizes; (void)n_in; (void)out_size;

    k_init0<<<64, 256, 0, stream>>>(counts, flags, partial);
    k_zeroarcs<<<(EEPAD + 255) / 256, 256, 0, stream>>>(arcs);
    k_hist<<<(EE + 255) / 256, 256, 0, stream>>>(to_state, counts);
    k_scan<<<1, 1024, 0, stream>>>(counts, rp, cur);
    k_split<<<1, 16, 0, stream>>>(rp, split);
    k_sortst<<<GB, 256, 0, stream>>>(rp, split, sordg);
    k_scatter<<<(EE + 255) / 256, 256, 0, stream>>>(from_state, to_state, pdf_id,
                                                    trans_logw, cur, arcs);
    k_sortbank<<<(SS * 64 + 255) / 256, 256, 0, stream>>>(rp, counts, arcs);
    hipMemsetAsync(d_out, 0, sizeof(float), stream);

    hipFuncSetAttribute((const void*)k_coop, hipFuncAttributeMaxDynamicSharedMemorySize,
                        DYNLDS);
    int nb = 0;
    hipOccupancyMaxActiveBlocksPerMultiprocessor(&nb, (const void*)k_coop, NT, DYNLDS);
    if (nb >= 1) {
        void* kp[12] = {
            (void*)&arcs, (void*)&rp, (void*)&split, (void*)&sordg, (void*)&input,
            (void*)&init_logp, (void*)&final_logp, (void*)&partial, (void*)&A_all,
            (void*)&flags, (void*)&xcdbuf, (void*)&out
        };
        hipError_t e = hipLaunchCooperativeKernel((const void*)k_coop, dim3(NBLK), dim3(NT),
                                                  kp, DYNLDS, stream);
        if (e == hipSuccess) return;
    }

    // Fallback: per-step kernels (bf16 state), known-passing structure.
    k_initA<<<(SS * BB + 255) / 256, 256, 0, stream>>>(init_logp, A0, M2);
    k_transpose0<<<NEXB, 256, 0, stream>>>(input, EX0);
    unsigned short* A[2]  = {A0, A1};
    unsigned short* EX[2] = {EX0, EX1};
    for (int k = 0; k < TT; ++k) {
        int kn = k + 1;
        int useSlot = (k > 0 && (k % RESC) == 0) ? (k / RESC - 1) : -1;
        int maxSlot = (kn < TT && (kn % RESC) == 0) ? (kn / RESC - 1) : -1;
        int grid = SS + ((kn < TT) ? NEXB : 0);
        const float* fnext = (kn < TT) ? (input + (size_t)kn * BB * DD) : nullptr;
        k_step<<<grid, 256, 0, stream>>>(arcs, rp, A[k & 1], A[kn & 1], EX[k & 1],
                                         fnext, EX[kn & 1], M2, maxSlot, useSlot);
    }
    k_fin<<<1, 1024, 0, stream>>>(A[TT & 1], final_logp, M2, out);
}

// Round 7
// 712.900 us; speedup vs baseline: 1.3995x; 1.1607x over previous
//
#include <hip/hip_runtime.h>
#include <math.h>

#define TT 150
#define BB 64
#define DD 2000
#define SS 3000
#define EE 100000
#define EEPAD 124160   // >= EE + SS*7 (arcs padded per-state to multiple of 8)
#define RESC 16
#define NSLOT 9
#define RESCC 0x1p-46f // exact pow2 rescale every 16 steps (growth ~7.42^16 ~= 2^46.3)

#define NT 1024        // threads per block (16 waves)
#define NBLK 256       // 1 block per CU
#define NG 16          // groups, 4 batch lanes each
#define GB 16          // blocks per group (bid = x + 8y + 16j -> same XCD x)
#define CAP 8192       // LDS arc slots per block (max slice ~7k)
#define ASTRD 3072     // u64 words per alpha buffer per group (SS=3000 padded)
#define NSTMAX 1024
#define FLGSTR 32      // dwords between flags (128 B)
#define NEXB 32
#define EXCH 125       // ex pdfs per wave (16*125 = 2000 = DD)

// dynamic LDS layout (bytes). Alpha table at byte 0 so the gather's
// ds_read address is just (idx & 0xFFFF); ex base folds into the offset.
#define OFF_ALPHA  0                 // SS*8  -> 24064 (u64: 4xbf16 per state)
#define OFF_EX     24064             // DD*8  -> 16128 (u64: 4xbf16 per pdf)
#define OFF_ARC    40192             // CAP*8 = 65536
#define OFF_RBP    105728            // (NSTMAX+1)*4 -> 4112
#define OFF_SORD   109840            // NSTMAX*4 = 4096
#define OFF_RED    113936            // 128*4*4 = 2048
#define OFF_SH     115984            // 16
#define OFF_LSP    116000            // (GB+1)*4 -> 80
#define DYNLDS     116080

// idx = (from<<3) | (pdf<<19): both halves are ready-made BYTE offsets into
// the u64 LDS tables (from*8 <= 23992 < 2^15; idx>>16 == pdf*8 <= 15992).
struct __align__(8) ArcT2 { unsigned idx; float ew; };

__device__ inline float b2f(unsigned short u) {
    union { unsigned u32; float f; } x; x.u32 = ((unsigned)u) << 16; return x.f;
}
__device__ inline unsigned short f2b(float f) {
    union { float f; unsigned u; } x; x.f = f;
    unsigned r = x.u + 0x7FFF + ((x.u >> 16) & 1);       // RNE, positive finite only
    return (unsigned short)(r >> 16);
}
__device__ inline float u2f(unsigned u) {
    union { unsigned u32; float f; } x; x.u32 = u; return x.f;
}

// ---------------- setup kernels ----------------
__global__ void k_init0(int* __restrict__ counts, unsigned* __restrict__ flags,
                        float* __restrict__ partial)
{
    int i = blockIdx.x * blockDim.x + threadIdx.x;
    if (i < SS) counts[i] = 0;
    if (i < 2 * NBLK * FLGSTR) flags[i] = 0u;
    if (i < NG * 4) partial[i] = 0.f;
}

__global__ void k_zeroarcs(ArcT2* __restrict__ arcs)
{
    int i = blockIdx.x * blockDim.x + threadIdx.x;
    if (i < EEPAD) { ArcT2 z; z.idx = 0; z.ew = 0.f; arcs[i] = z; }
}

__global__ void k_hist(const int* __restrict__ to_state, int* __restrict__ counts)
{
    int e = blockIdx.x * blockDim.x + threadIdx.x;
    if (e < EE) atomicAdd(&counts[to_state[e]], 1);
}

// prefix over counts padded to multiple of 8
__global__ void k_scan(const int* __restrict__ counts, int* __restrict__ rp,
                       int* __restrict__ cur)
{
    __shared__ int ls[1024];
    int tid = threadIdx.x;
    int s0 = tid * 3;
    int a0 = (s0 + 0 < SS) ? ((counts[s0 + 0] + 7) & ~7) : 0;
    int a1 = (s0 + 1 < SS) ? ((counts[s0 + 1] + 7) & ~7) : 0;
    int a2 = (s0 + 2 < SS) ? ((counts[s0 + 2] + 7) & ~7) : 0;
    int tsum = a0 + a1 + a2;
    ls[tid] = tsum;
    __syncthreads();
    for (int off = 1; off < 1024; off <<= 1) {
        int v = ls[tid];
        int add = (tid >= off) ? ls[tid - off] : 0;
        __syncthreads();
        ls[tid] = v + add;
        __syncthreads();
    }
    int excl = ls[tid] - tsum;
    if (s0 + 0 < SS) { rp[s0 + 0] = excl; cur[s0 + 0] = excl; }
    excl += a0;
    if (s0 + 1 < SS) { rp[s0 + 1] = excl; cur[s0 + 1] = excl; }
    excl += a1;
    if (s0 + 2 < SS) { rp[s0 + 2] = excl; cur[s0 + 2] = excl; }
    if (tid == 1023) rp[SS] = ls[1023];
}

// arc-balanced split into GB slices
__global__ void k_split(const int* __restrict__ rp, int* __restrict__ split)
{
    int j = threadIdx.x;
    if (j > GB) return;
    if (j == 0)  { split[0] = 0; return; }
    if (j == GB) { split[GB] = SS; return; }
    long long total = rp[SS];
    int target = (int)((total * j) / GB);
    int lo = 0, hi = SS;
    while (lo < hi) { int mid = (lo + hi) >> 1; if (rp[mid] >= target) hi = mid; else lo = mid + 1; }
    split[j] = lo;
}

// Per-slice counting sort of states by descending arc count (gather wave time
// = max nit over its 8 states -> max ~= mean after sorting). Shared by groups.
__global__ void k_sortst(const int* __restrict__ rp, const int* __restrict__ split,
                         int* __restrict__ sordg)
{
    __shared__ int hist[64];
    __shared__ int off[64];
    int j = blockIdx.x;                      // slice 0..GB-1
    int s0 = split[j], s1 = split[j + 1];
    int nst = s1 - s0; if (nst > NSTMAX) nst = NSTMAX;
    int tid = threadIdx.x;                   // 256 threads
    if (tid < 64) hist[tid] = 0;
    __syncthreads();
    for (int i = tid; i < nst; i += 256) {
        int nit = (rp[s0 + i + 1] - rp[s0 + i]) >> 3;
        if (nit > 63) nit = 63;
        atomicAdd(&hist[nit], 1);
    }
    __syncthreads();
    if (tid == 0) {
        int acc = 0;
        for (int b = 63; b >= 0; --b) { off[b] = acc; acc += hist[b]; }
    }
    __syncthreads();
    for (int i = tid; i < nst; i += 256) {
        int nit = (rp[s0 + i + 1] - rp[s0 + i]) >> 3;
        if (nit > 63) nit = 63;
        int pos = atomicAdd(&off[nit], 1);
        sordg[j * NSTMAX + pos] = i;
    }
}

__global__ void k_scatter(const int* __restrict__ from_state, const int* __restrict__ to_state,
                          const int* __restrict__ pdf_id, const float* __restrict__ trans_logw,
                          int* __restrict__ cur, ArcT2* __restrict__ arcs)
{
    int e = blockIdx.x * blockDim.x + threadIdx.x;
    if (e >= EE) return;
    int s = to_state[e];
    int pos = atomicAdd(&cur[s], 1);
    ArcT2 a;
    a.idx = ((unsigned)from_state[e] << 3) | ((unsigned)pdf_id[e] << 19);
    a.ew = __expf(trans_logw[e]);
    arcs[pos] = a;
}

// Bank-aware in-place reorder: within each state, put arcs with
// from%8 == position%8 at matching positions (u64 alpha reads of a sub-class
// then hit a 4-bank set -> ~2 lanes/bank). Pure permutation, one wave/state.
__global__ void k_sortbank(const int* __restrict__ rp, const int* __restrict__ counts,
                           ArcT2* __restrict__ arcs)
{
    int w = (blockIdx.x * blockDim.x + threadIdx.x) >> 6;
    int lane = threadIdx.x & 63;
    if (w >= SS) return;
    int n = counts[w];
    if (n < 2 || n > 64) return;
    int base = rp[w];
    bool valid = (lane < n);
    ArcT2 a;
    a.idx = 0; a.ew = 0.f;
    if (valid) a = arcs[base + lane];
    int c = valid ? (int)((a.idx >> 3) & 7) : -1;
    unsigned long long below = (1ull << lane) - 1ull;
    int ncArr[8];
    int myrank = 0;
    #pragma unroll
    for (int c8 = 0; c8 < 8; ++c8) {
        unsigned long long m = __ballot(valid && (c == c8));
        ncArr[c8] = (int)__popcll(m);
        if (c == c8) myrank = (int)__popcll(m & below);
    }
    int pos = -1;
    bool spill = false;
    if (valid) {
        int cap = (n > c) ? (((n - 1 - c) >> 3) + 1) : 0;
        if (myrank < cap) pos = c + (myrank << 3);
        else spill = true;
    }
    unsigned long long sm = __ballot(spill);
    if (spill) {
        int sr = (int)__popcll(sm & below);
        int accum = 0;
        #pragma unroll
        for (int c8 = 0; c8 < 8; ++c8) {
            int cap = (n > c8) ? (((n - 1 - c8) >> 3) + 1) : 0;
            int fr = cap - ncArr[c8]; if (fr < 0) fr = 0;
            if (pos < 0 && sr < accum + fr) {
                int kk = ncArr[c8] + (sr - accum);
                pos = c8 + (kk << 3);
            }
            accum += fr;
        }
    }
    if (valid) arcs[base + pos] = a;   // all lanes loaded before any store (same wave)
}

// ---------------- cooperative mega-kernel, verified XCD-local exchange ----------------
__global__ void __launch_bounds__(NT, 4) k_coop(
    const ArcT2* __restrict__ arcs, const int* __restrict__ rp,
    const int* __restrict__ split, const int* __restrict__ sordg,
    const float* __restrict__ input, const float* __restrict__ init_logp,
    const float* __restrict__ final_logp,
    float* __restrict__ partial,             // [NG][4]
    unsigned long long* __restrict__ A_all,  // [NG][2][ASTRD] u64 = 4xbf16
    unsigned* __restrict__ flags,            // [2][NBLK][FLGSTR]
    unsigned* __restrict__ xcdbuf,           // [NBLK]
    float* __restrict__ out)
{
    extern __shared__ char dsm[];
    unsigned long long* la64  = (unsigned long long*)(dsm + OFF_ALPHA);
    unsigned long long* lex64 = (unsigned long long*)(dsm + OFF_EX);
    ArcT2*    larc  = (ArcT2*)(dsm + OFF_ARC);
    int*      rbp   = (int*)(dsm + OFF_RBP);
    float*    redf  = (float*)(dsm + OFF_RED);
    int*      sh    = (int*)(dsm + OFF_SH);
    int*      sord  = (int*)(dsm + OFF_SORD);
    int*      lsp   = (int*)(dsm + OFF_LSP);

    int tid = threadIdx.x, bid = blockIdx.x;
    int x = bid & 7, y = (bid >> 3) & 1, j = bid >> 4;   // presumed-XCD, grp-in-XCD, member
    int g = x * 2 + y;                                   // group 0..15
    int lane = tid & 63, wave = tid >> 6;
    int oct = lane >> 3, sub = lane & 7;

    unsigned long long* Ag = A_all + (size_t)g * (2 * ASTRD);
    unsigned* stepf    = flags;
    unsigned* auxf     = flags + (size_t)NBLK * FLGSTR;
    unsigned* myflag   = stepf + (size_t)(g * GB + j) * FLGSTR;
    unsigned* grpflag  = stepf + (size_t)(g * GB) * FLGSTR;
    unsigned* myflag2  = auxf + (size_t)(g * GB + j) * FLGSTR;
    unsigned* grpflag2 = auxf + (size_t)(g * GB) * FLGSTR;
    const float* inpG  = input + (size_t)(4 * g) * DD;

    int s0 = split[j], s1 = split[j + 1];
    int nst = s1 - s0;
    if (nst > NSTMAX) nst = NSTMAX;                      // safety (never expected)

    // ---- stage rp slice + sorted order + split + arcs to LDS ----
    for (int i = tid; i <= nst; i += NT) rbp[i] = rp[s0 + i];
    for (int i = tid; i < nst; i += NT) sord[i] = sordg[j * NSTMAX + i];
    if (tid <= GB) lsp[tid] = split[tid];
    __syncthreads();
    int rb0 = rbp[0];
    {
        int staged = rbp[nst] - rb0; if (staged > CAP) staged = CAP;
        for (int i = tid; i < staged; i += NT) larc[i] = arcs[rb0 + i];
    }

    // ---- publish XCC_ID (s_getreg id=20, offset=0, width=4 -> imm 6164) ----
    unsigned xcd = __builtin_amdgcn_s_getreg(6164) & 0xF;
    if (tid == 0)
        __hip_atomic_store(&xcdbuf[g * GB + j], xcd, __ATOMIC_RELAXED, __HIP_MEMORY_SCOPE_AGENT);
    __syncthreads();
    if (tid == 0)
        __hip_atomic_store(myflag2, 1u, __ATOMIC_RELAXED, __HIP_MEMORY_SCOPE_AGENT);
    // global aux barrier: wave0 polls all 256 aux flags (4 per lane)
    if (wave == 0) {
        while (true) {
            unsigned ok = 1;
            #pragma unroll
            for (int r = 0; r < 4; ++r) {
                unsigned v = __hip_atomic_load(auxf + (size_t)(lane * 4 + r) * FLGSTR,
                                               __ATOMIC_RELAXED, __HIP_MEMORY_SCOPE_AGENT);
                ok &= (v >= 1u);
            }
            if (__ballot(ok != 0) == ~0ULL) break;
            __builtin_amdgcn_s_sleep(1);
        }
    }
    __syncthreads();
    // decide protocol: fast iff my group is on ONE XCD and getreg is plausible
    {
        int* xint = (int*)redf;
        if (tid < NBLK)
            xint[tid] = (int)__hip_atomic_load(&xcdbuf[tid], __ATOMIC_RELAXED,
                                               __HIP_MEMORY_SCOPE_AGENT);
        __syncthreads();
        if (tid == 0) {
            int x0 = xint[g * GB];
            int uni = 1;
            for (int m = 1; m < GB; ++m) uni &= (xint[g * GB + m] == x0);
            int first = xint[0], distinct = 0;
            for (int i = 1; i < NBLK; ++i) distinct |= (xint[i] != first);
            sh[0] = uni && distinct;
        }
        __syncthreads();
    }
    const bool fast = (sh[0] != 0);
    __syncthreads();

    // Register prefetch of this thread's next-frame floats (4 batch rows).
    float pf[2][4];
    auto prefetch = [&](const float* fr) {
        int d0 = wave * EXCH;
        #pragma unroll
        for (int r = 0; r < 2; ++r) {
            int dd = r * 64 + lane;
            if (dd < EXCH) {
                int d = d0 + dd;
                #pragma unroll
                for (int c = 0; c < 4; ++c) pf[r][c] = fr[c * DD + d];
            }
        }
    };

    // Pipelined exchange (per step, after the post-gather barrier):
    //   every wave: pack+store its 125-pdf ex chunk (u64 each) from prefetched
    //   regs, then wave p polls producer p's flag and copies producer p's
    //   alpha slice (1 u64 per state) with 64 lanes.
    auto exchange = [&](unsigned epv, const unsigned long long* src64) {
        {   // ex chunk: pdfs [wave*EXCH, wave*EXCH+EXCH)
            int d0 = wave * EXCH;
            #pragma unroll
            for (int r = 0; r < 2; ++r) {
                int dd = r * 64 + lane;
                if (dd < EXCH) {
                    int d = d0 + dd;
                    unsigned w0 = (unsigned)f2b(__expf(pf[r][0])) |
                                  ((unsigned)f2b(__expf(pf[r][1])) << 16);
                    unsigned w1 = (unsigned)f2b(__expf(pf[r][2])) |
                                  ((unsigned)f2b(__expf(pf[r][3])) << 16);
                    lex64[d] = (unsigned long long)w0 | ((unsigned long long)w1 << 32);
                }
            }
        }
        int p = wave;
        const unsigned* gf = grpflag + (size_t)p * FLGSTR;
        if (fast) {
            while (*(volatile const unsigned*)gf < epv) { }
            int a = lsp[p], b = lsp[p + 1];
            for (int i = a + lane; i < b; i += 64)
                la64[i] = *(volatile const unsigned long long*)(src64 + i);
        } else {
            while (__hip_atomic_load(gf, __ATOMIC_RELAXED, __HIP_MEMORY_SCOPE_AGENT) < epv)
                __builtin_amdgcn_s_sleep(1);
            int a = lsp[p], b = lsp[p + 1];
            for (int i = a + lane; i < b; i += 64)
                la64[i] = __hip_atomic_load(src64 + i, __ATOMIC_RELAXED,
                                            __HIP_MEMORY_SCOPE_AGENT);
        }
    };

    // ---- alpha0 (own slice) with protocol-matched stores ----
    prefetch(inpG);                                      // frame 0 (issue early)
    for (int i = tid; i < nst; i += NT) {
        int s = s0 + i;
        unsigned short h = f2b(__expf(init_logp[s]));
        unsigned w = (unsigned)h | ((unsigned)h << 16);
        unsigned long long pk = (unsigned long long)w | ((unsigned long long)w << 32);
        if (fast) Ag[s] = pk;                            // plain store -> shared L2
        else __hip_atomic_store(Ag + s, pk, __ATOMIC_RELAXED, __HIP_MEMORY_SCOPE_AGENT);
    }
    __syncthreads();                                     // stores drained
    unsigned ep = 1;
    if (tid == 0) {
        if (fast) *(volatile unsigned*)myflag = ep;
        else __hip_atomic_store(myflag, ep, __ATOMIC_RELAXED, __HIP_MEMORY_SCOPE_AGENT);
    }
    exchange(ep, Ag /* buffer 0 holds alpha0 */);
    __syncthreads();

    float vf0 = 0.f, vf1 = 0.f, vf2 = 0.f, vf3 = 0.f;

    // ---- 150 steps ----
    for (int k = 0; k < TT; ++k) {
        unsigned long long* An64 = Ag + ((k + 1) & 1) * ASTRD;
        bool last = (k == TT - 1);
        bool resc = (((k + 1) & (RESC - 1)) == 0);

        if (!last) prefetch(inpG + (size_t)(k + 1) * BB * DD);  // issue next frame

        // gather own states via sorted order (8 lanes per state, 8 states/wave;
        // one u64 alpha + one u64 ex read feeds 4 batch FMAs per arc)
        for (int base = wave * 8; base < nst; base += 128) {
            int li = base + oct;
            bool has = (li < nst);
            float acc0 = 0.f, acc1 = 0.f, acc2 = 0.f, acc3 = 0.f;
            int sg = 0;
            if (has) {
                int so = sord[li];
                sg = s0 + so;
                int ra = rbp[so], re = rbp[so + 1];
                int nit = (re - ra) >> 3;
                if (re - rb0 <= CAP) {
                    int bix = ra - rb0 + sub;
                    for (int t = 0; t < nit; ++t) {
                        ArcT2 a = larc[bix + t * 8];
                        uint2 au = *(const uint2*)(dsm + (a.idx & 0xFFFFu));
                        uint2 eu = *(const uint2*)(dsm + OFF_EX + (a.idx >> 16));
                        acc0 = fmaf(u2f(au.x << 16), a.ew * u2f(eu.x << 16), acc0);
                        acc1 = fmaf(u2f(au.x & 0xFFFF0000u), a.ew * u2f(eu.x & 0xFFFF0000u), acc1);
                        acc2 = fmaf(u2f(au.y << 16), a.ew * u2f(eu.y << 16), acc2);
                        acc3 = fmaf(u2f(au.y & 0xFFFF0000u), a.ew * u2f(eu.y & 0xFFFF0000u), acc3);
                    }
                } else {
                    for (int t = 0; t < nit; ++t) {      // safety overflow path
                        ArcT2 a = arcs[ra + t * 8 + sub];
                        uint2 au = *(const uint2*)(dsm + (a.idx & 0xFFFFu));
                        uint2 eu = *(const uint2*)(dsm + OFF_EX + (a.idx >> 16));
                        acc0 = fmaf(u2f(au.x << 16), a.ew * u2f(eu.x << 16), acc0);
                        acc1 = fmaf(u2f(au.x & 0xFFFF0000u), a.ew * u2f(eu.x & 0xFFFF0000u), acc1);
                        acc2 = fmaf(u2f(au.y << 16), a.ew * u2f(eu.y << 16), acc2);
                        acc3 = fmaf(u2f(au.y & 0xFFFF0000u), a.ew * u2f(eu.y & 0xFFFF0000u), acc3);
                    }
                }
            }
            acc0 += __shfl_xor(acc0, 1, 64); acc1 += __shfl_xor(acc1, 1, 64);
            acc2 += __shfl_xor(acc2, 1, 64); acc3 += __shfl_xor(acc3, 1, 64);
            acc0 += __shfl_xor(acc0, 2, 64); acc1 += __shfl_xor(acc1, 2, 64);
            acc2 += __shfl_xor(acc2, 2, 64); acc3 += __shfl_xor(acc3, 2, 64);
            acc0 += __shfl_xor(acc0, 4, 64); acc1 += __shfl_xor(acc1, 4, 64);
            acc2 += __shfl_xor(acc2, 4, 64); acc3 += __shfl_xor(acc3, 4, 64);
            if (has && sub == 0) {
                if (resc) { acc0 *= RESCC; acc1 *= RESCC; acc2 *= RESCC; acc3 *= RESCC; }
                if (last) {
                    float ef = __expf(final_logp[sg]);
                    vf0 = fmaf(acc0, ef, vf0);
                    vf1 = fmaf(acc1, ef, vf1);
                    vf2 = fmaf(acc2, ef, vf2);
                    vf3 = fmaf(acc3, ef, vf3);
                } else {
                    unsigned w0 = (unsigned)f2b(acc0) | ((unsigned)f2b(acc1) << 16);
                    unsigned w1 = (unsigned)f2b(acc2) | ((unsigned)f2b(acc3) << 16);
                    unsigned long long pk = (unsigned long long)w0 |
                                            ((unsigned long long)w1 << 32);
                    if (fast) An64[sg] = pk;             // plain store -> shared L2
                    else __hip_atomic_store(An64 + sg, pk, __ATOMIC_RELAXED,
                                            __HIP_MEMORY_SCOPE_AGENT);
                }
            }
        }
        if (last) break;
        __syncthreads();                                 // stores drained (vmcnt 0)
        ++ep;
        if (tid == 0) {
            if (fast) *(volatile unsigned*)myflag = ep;
            else __hip_atomic_store(myflag, ep, __ATOMIC_RELAXED, __HIP_MEMORY_SCOPE_AGENT);
        }
        exchange(ep, An64);
        __syncthreads();
    }

    // ---- epilogue: reduce objf over this block's states ----
    if (sub == 0) {
        int r0 = (wave * 8 + oct) * 4;
        redf[r0 + 0] = vf0; redf[r0 + 1] = vf1;
        redf[r0 + 2] = vf2; redf[r0 + 3] = vf3;
    }
    __syncthreads();
    if (tid < 4) {
        float S = 0.f;
        for (int i = 0; i < 128; ++i) S += redf[i * 4 + tid];
        __hip_atomic_fetch_add(&partial[g * 4 + tid], S, __ATOMIC_RELAXED,
                               __HIP_MEMORY_SCOPE_AGENT);
    }
    __syncthreads();
    if (tid == 0)
        __hip_atomic_store(myflag2, 2u, __ATOMIC_RELAXED, __HIP_MEMORY_SCOPE_AGENT);
    if (j == 0) {
        if (wave == 0) {
            while (true) {
                unsigned v = 2;
                if (lane < GB)
                    v = __hip_atomic_load(grpflag2 + lane * FLGSTR, __ATOMIC_RELAXED,
                                          __HIP_MEMORY_SCOPE_AGENT);
                if (__ballot(v >= 2) == ~0ULL) break;
                __builtin_amdgcn_s_sleep(1);
            }
        }
        __syncthreads();
        if (tid < 4) {
            float S = __hip_atomic_load(&partial[g * 4 + tid], __ATOMIC_RELAXED,
                                        __HIP_MEMORY_SCOPE_AGENT);
            float lg = logf(S) + (float)(NSLOT * 46) * 0.69314718055994531f;
            atomicAdd(out, lg);
        }
    }
}

// ---------------- fallback path (round-6 per-step kernels) ----------------
template <int THREADS>
__device__ inline void transpose_exp_t(const float* __restrict__ frame,
                                       unsigned short* __restrict__ dst,
                                       int tile_id, int tid, unsigned short* smem)
{
    int d0 = tile_id * 64;
    #pragma unroll
    for (int it = 0; it < 4096 / THREADS; ++it) {
        int idx = it * THREADS + tid;
        int dl = idx & 63, bl = idx >> 6;
        int d = d0 + dl;
        float v = 0.f;
        if (d < DD) v = __expf(frame[bl * DD + d]);
        smem[dl * 65 + bl] = f2b(v);
    }
    __syncthreads();
    #pragma unroll
    for (int it = 0; it < 4096 / THREADS; ++it) {
        int idx = it * THREADS + tid;
        int bo = idx & 63, dq = idx >> 6;
        int d = d0 + dq;
        if (d < DD) dst[(d << 6) + bo] = smem[dq * 65 + bo];
    }
    __syncthreads();
}

__global__ void k_initA(const float* __restrict__ init_logp,
                        unsigned short* __restrict__ A0, float* __restrict__ M2)
{
    int idx = blockIdx.x * blockDim.x + threadIdx.x;
    if (idx < SS * BB) A0[idx] = f2b(__expf(init_logp[idx >> 6]));
    if (idx < NSLOT * 16 * 64) M2[idx] = 0.f;
}

__global__ void k_transpose0(const float* __restrict__ frame, unsigned short* __restrict__ dst)
{
    __shared__ unsigned short tile[64 * 65];
    transpose_exp_t<256>(frame, dst, blockIdx.x, threadIdx.x, tile);
}

__global__ void __launch_bounds__(256) k_step(
    const ArcT2* __restrict__ arcs, const int* __restrict__ rp,
    const unsigned short* __restrict__ Ap, unsigned short* __restrict__ An,
    const unsigned short* __restrict__ ec,
    const float* __restrict__ frameNext, unsigned short* __restrict__ en,
    float* __restrict__ M2, int maxSlot, int useSlot)
{
    __shared__ unsigned short tile[64 * 65];
    __shared__ float part[256];
    __shared__ float rcpA[64];
    int tid = threadIdx.x, bid = blockIdx.x;
    if (bid >= SS) { transpose_exp_t<256>(frameNext, en, bid - SS, tid, tile); return; }
    int lane = tid & 63, wave = tid >> 6;
    if (useSlot >= 0 && wave == 0) {
        const float* Mrow = M2 + useSlot * (16 * 64);
        float m = Mrow[lane];
        #pragma unroll
        for (int g = 1; g < 16; ++g) m = fmaxf(m, Mrow[g * 64 + lane]);
        rcpA[lane] = 1.0f / m;
    }
    int rbeg = rp[bid], rend = rp[bid + 1];
    float acc = 0.f;
    for (int i = rbeg + wave; i < rend; i += 4) {
        ArcT2 a = arcs[i];
        int from = (a.idx & 0xFFFF) >> 3, pdf = a.idx >> 19;
        acc = fmaf(b2f(Ap[(from << 6) + lane]), a.ew * b2f(ec[(pdf << 6) + lane]), acc);
    }
    part[tid] = acc;
    __syncthreads();
    if (wave == 0) {
        float sum = part[lane] + part[64 + lane] + part[128 + lane] + part[192 + lane];
        if (useSlot >= 0) sum *= rcpA[lane];
        An[(bid << 6) + lane] = f2b(sum);
        if (maxSlot >= 0)
            atomicMax((unsigned*)&M2[maxSlot * (16 * 64) + (bid & 15) * 64 + lane],
                      __float_as_uint(sum));
    }
}

__global__ void k_fin(const unsigned short* __restrict__ AT, const float* __restrict__ final_logp,
                      const float* __restrict__ M2, float* __restrict__ out)
{
    __shared__ float red[1024];
    int tid = threadIdx.x;
    int lane = tid & 63, chunk = tid >> 6;
    float psum = 0.f;
    for (int s = chunk; s < SS; s += 16)
        psum += b2f(AT[(s << 6) + lane]) * __expf(final_logp[s]);
    red[tid] = psum;
    __syncthreads();
    if (tid < 64) {
        float sum = 0.f;
        #pragma unroll
        for (int c = 0; c < 16; ++c) sum += red[c * 64 + tid];
        float lg = logf(sum);
        #pragma unroll
        for (int r = 0; r < NSLOT; ++r) {
            const float* Mrow = M2 + r * (16 * 64);
            float m = Mrow[tid];
            #pragma unroll
            for (int g = 1; g < 16; ++g) m = fmaxf(m, Mrow[g * 64 + tid]);
            lg += logf(m);
        }
        #pragma unroll
        for (int off = 32; off > 0; off >>= 1) lg += __shfl_down(lg, off);
        if (tid == 0) out[0] = lg;
    }
}

extern "C" void kernel_launch(void* const* d_in, const int* in_sizes, int n_in,
                              void* d_out, int out_size, void* d_ws, size_t ws_size,
                              hipStream_t stream)
{
    const float* input      = (const float*)d_in[0];
    const float* trans_logw = (const float*)d_in[1];
    const float* init_logp  = (const float*)d_in[2];
    const float* final_logp = (const float*)d_in[3];
    const int*   from_state = (const int*)d_in[4];
    const int*   to_state   = (const int*)d_in[5];
    const int*   pdf_id     = (const int*)d_in[6];
    float* out = (float*)d_out;

    char* ws = (char*)d_ws;
    size_t off = 0;
    auto alloc = [&](size_t bytes) -> char* {
        char* p = ws + off;
        off = (off + bytes + 255) & ~(size_t)255;
        return p;
    };
    ArcT2* arcs  = (ArcT2*)alloc((size_t)EEPAD * sizeof(ArcT2));
    int* rp      = (int*)alloc((size_t)(SS + 1) * 4);
    int* cur     = (int*)alloc((size_t)SS * 4);
    int* counts  = (int*)alloc((size_t)SS * 4);
    int* split   = (int*)alloc((size_t)(GB + 1) * 4);
    int* sordg   = (int*)alloc((size_t)GB * NSTMAX * 4);
    unsigned long long* A_all = (unsigned long long*)alloc((size_t)NG * 2 * ASTRD * 8);
    float* partial  = (float*)alloc((size_t)NG * 4 * 4);
    unsigned* flags = (unsigned*)alloc((size_t)2 * NBLK * FLGSTR * 4);
    unsigned* xcdbuf = (unsigned*)alloc((size_t)NBLK * 4);
    // fallback buffers
    unsigned short* A0  = (unsigned short*)alloc((size_t)SS * BB * 2);
    unsigned short* A1  = (unsigned short*)alloc((size_t)SS * BB * 2);
    unsigned short* EX0 = (unsigned short*)alloc((size_t)DD * BB * 2);
    unsigned short* EX1 = (unsigned short*)alloc((size_t)DD * BB * 2);
    float* M2    = (float*)alloc((size_t)NSLOT * 16 * 64 * 4);
    (void)ws_size; (void)in_sizes; (void)n_in; (void)out_size;

    k_init0<<<64, 256, 0, stream>>>(counts, flags, partial);
    k_zeroarcs<<<(EEPAD + 255) / 256, 256, 0, stream>>>(arcs);
    k_hist<<<(EE + 255) / 256, 256, 0, stream>>>(to_state, counts);
    k_scan<<<1, 1024, 0, stream>>>(counts, rp, cur);
    k_split<<<1, 32, 0, stream>>>(rp, split);
    k_sortst<<<GB, 256, 0, stream>>>(rp, split, sordg);
    k_scatter<<<(EE + 255) / 256, 256, 0, stream>>>(from_state, to_state, pdf_id,
                                                    trans_logw, cur, arcs);
    k_sortbank<<<(SS * 64 + 255) / 256, 256, 0, stream>>>(rp, counts, arcs);
    hipMemsetAsync(d_out, 0, sizeof(float), stream);

    hipFuncSetAttribute((const void*)k_coop, hipFuncAttributeMaxDynamicSharedMemorySize,
                        DYNLDS);
    int nb = 0;
    hipOccupancyMaxActiveBlocksPerMultiprocessor(&nb, (const void*)k_coop, NT, DYNLDS);
    if (nb >= 1) {
        void* kp[12] = {
            (void*)&arcs, (void*)&rp, (void*)&split, (void*)&sordg, (void*)&input,
            (void*)&init_logp, (void*)&final_logp, (void*)&partial, (void*)&A_all,
            (void*)&flags, (void*)&xcdbuf, (void*)&out
        };
        hipError_t e = hipLaunchCooperativeKernel((const void*)k_coop, dim3(NBLK), dim3(NT),
                                                  kp, DYNLDS, stream);
        if (e == hipSuccess) return;
    }

    // Fallback: per-step kernels (bf16 state), known-passing structure.
    k_initA<<<(SS * BB + 255) / 256, 256, 0, stream>>>(init_logp, A0, M2);
    k_transpose0<<<NEXB, 256, 0, stream>>>(input, EX0);
    unsigned short* A[2]  = {A0, A1};
    unsigned short* EX[2] = {EX0, EX1};
    for (int k = 0; k < TT; ++k) {
        int kn = k + 1;
        int useSlot = (k > 0 && (k % RESC) == 0) ? (k / RESC - 1) : -1;
        int maxSlot = (kn < TT && (kn % RESC) == 0) ? (kn / RESC - 1) : -1;
        int grid = SS + ((kn < TT) ? NEXB : 0);
        const float* fnext = (kn < TT) ? (input + (size_t)kn * BB * DD) : nullptr;
        k_step<<<grid, 256, 0, stream>>>(arcs, rp, A[k & 1], A[kn & 1], EX[k & 1],
                                         fnext, EX[kn & 1], M2, maxSlot, useSlot);
    }
    k_fin<<<1, 1024, 0, stream>>>(A[TT & 1], final_logp, M2, out);
}

// Round 9
// 656.394 us; speedup vs baseline: 1.5199x; 1.0861x over previous
//
#include <hip/hip_runtime.h>
#include <math.h>

#define TT 150
#define BB 64
#define DD 2000
#define SS 3000
#define EE 100000
#define EEPAD 124160   // >= EE + SS*7 (arcs padded per-state to multiple of 8)
#define RESC 16
#define NSLOT 9
#define RESCC 0x1p-46f // exact pow2 rescale every 16 steps (growth ~7.42^16 ~= 2^46.3)

#define NT 1024        // threads per block (16 waves)
#define NBLK 256       // 1 block per CU
#define NG 16          // groups, 4 batch lanes each
#define GB 16          // blocks per group (bid = x + 8y + 16j -> same XCD x)
#define CAP 8192       // LDS arc slots per block (max slice ~7k)
#define ASTRD 3072     // u64 words per alpha buffer per group (SS=3000 padded)
#define NSTMAX 1024
#define FLGSTR 32      // dwords between flags (128 B)
#define NEXB 32
#define EXCH 125       // ex pdfs per wave (16*125 = 2000 = DD)

// dynamic LDS layout (bytes). Alpha table at byte 0 so the gather's
// ds_read address is just (idx & 0xFFFF); ex base folds into the offset.
#define OFF_ALPHA  0                 // SS*8  -> 24064 (u64: 4xbf16 per state)
#define OFF_EX     24064             // DD*8  -> 16128 (u64: 4xbf16 per pdf)
#define OFF_ARC    40192             // CAP*8 = 65536
#define OFF_RBP    105728            // (NSTMAX+1)*4 -> 4112
#define OFF_SORD   109840            // NSTMAX*4 = 4096
#define OFF_RED    113936            // 256*4*4 = 4096
#define OFF_SH     118032            // 16
#define OFF_LSP    118048            // (GB+1)*4 -> 80
#define DYNLDS     118128

// idx = (from<<3) | (pdf<<19): both halves are ready-made BYTE offsets into
// the u64 LDS tables (from*8 <= 23992 < 2^15; idx>>16 == pdf*8 <= 15992).
struct __align__(8) ArcT2 { unsigned idx; float ew; };

__device__ inline float b2f(unsigned short u) {
    union { unsigned u32; float f; } x; x.u32 = ((unsigned)u) << 16; return x.f;
}
__device__ inline unsigned short f2b(float f) {
    union { float f; unsigned u; } x; x.f = f;
    unsigned r = x.u + 0x7FFF + ((x.u >> 16) & 1);       // RNE, positive finite only
    return (unsigned short)(r >> 16);
}
__device__ inline float u2f(unsigned u) {
    union { unsigned u32; float f; } x; x.u32 = u; return x.f;
}

// Cross-lane add via DPP quad_perm (pure VALU, no DS-pipe traffic).
// 0xB1 = quad_perm(1,0,3,2) = xor1; 0x4E = quad_perm(2,3,0,1) = xor2.
// NOTE: dpp_ctrl must be a compile-time constant -> template parameter.
template <int CTRL>
__device__ inline float dpp_add(float v) {
    int x = __builtin_amdgcn_update_dpp(0, __float_as_int(v), CTRL, 0xF, 0xF, true);
    return v + __int_as_float(x);
}

// ---------------- setup kernels ----------------
__global__ void k_init0(int* __restrict__ counts, unsigned* __restrict__ flags,
                        float* __restrict__ partial)
{
    int i = blockIdx.x * blockDim.x + threadIdx.x;
    if (i < SS) counts[i] = 0;
    if (i < 2 * NBLK * FLGSTR) flags[i] = 0u;
    if (i < NG * 4) partial[i] = 0.f;
}

__global__ void k_zeroarcs(ArcT2* __restrict__ arcs)
{
    int i = blockIdx.x * blockDim.x + threadIdx.x;
    if (i < EEPAD) { ArcT2 z; z.idx = 0; z.ew = 0.f; arcs[i] = z; }
}

__global__ void k_hist(const int* __restrict__ to_state, int* __restrict__ counts)
{
    int e = blockIdx.x * blockDim.x + threadIdx.x;
    if (e < EE) atomicAdd(&counts[to_state[e]], 1);
}

// prefix over counts padded to multiple of 8
__global__ void k_scan(const int* __restrict__ counts, int* __restrict__ rp,
                       int* __restrict__ cur)
{
    __shared__ int ls[1024];
    int tid = threadIdx.x;
    int s0 = tid * 3;
    int a0 = (s0 + 0 < SS) ? ((counts[s0 + 0] + 7) & ~7) : 0;
    int a1 = (s0 + 1 < SS) ? ((counts[s0 + 1] + 7) & ~7) : 0;
    int a2 = (s0 + 2 < SS) ? ((counts[s0 + 2] + 7) & ~7) : 0;
    int tsum = a0 + a1 + a2;
    ls[tid] = tsum;
    __syncthreads();
    for (int off = 1; off < 1024; off <<= 1) {
        int v = ls[tid];
        int add = (tid >= off) ? ls[tid - off] : 0;
        __syncthreads();
        ls[tid] = v + add;
        __syncthreads();
    }
    int excl = ls[tid] - tsum;
    if (s0 + 0 < SS) { rp[s0 + 0] = excl; cur[s0 + 0] = excl; }
    excl += a0;
    if (s0 + 1 < SS) { rp[s0 + 1] = excl; cur[s0 + 1] = excl; }
    excl += a1;
    if (s0 + 2 < SS) { rp[s0 + 2] = excl; cur[s0 + 2] = excl; }
    if (tid == 1023) rp[SS] = ls[1023];
}

// arc-balanced split into GB slices
__global__ void k_split(const int* __restrict__ rp, int* __restrict__ split)
{
    int j = threadIdx.x;
    if (j > GB) return;
    if (j == 0)  { split[0] = 0; return; }
    if (j == GB) { split[GB] = SS; return; }
    long long total = rp[SS];
    int target = (int)((total * j) / GB);
    int lo = 0, hi = SS;
    while (lo < hi) { int mid = (lo + hi) >> 1; if (rp[mid] >= target) hi = mid; else lo = mid + 1; }
    split[j] = lo;
}

// Per-slice counting sort of states by descending arc count (gather wave time
// = max nit over its 16 states -> max ~= mean after sorting). Shared by groups.
__global__ void k_sortst(const int* __restrict__ rp, const int* __restrict__ split,
                         int* __restrict__ sordg)
{
    __shared__ int hist[128];
    __shared__ int off[128];
    int j = blockIdx.x;                      // slice 0..GB-1
    int s0 = split[j], s1 = split[j + 1];
    int nst = s1 - s0; if (nst > NSTMAX) nst = NSTMAX;
    int tid = threadIdx.x;                   // 256 threads
    if (tid < 128) hist[tid] = 0;
    __syncthreads();
    for (int i = tid; i < nst; i += 256) {
        int nit = (rp[s0 + i + 1] - rp[s0 + i]) >> 2;
        if (nit > 127) nit = 127;
        atomicAdd(&hist[nit], 1);
    }
    __syncthreads();
    if (tid == 0) {
        int acc = 0;
        for (int b = 127; b >= 0; --b) { off[b] = acc; acc += hist[b]; }
    }
    __syncthreads();
    for (int i = tid; i < nst; i += 256) {
        int nit = (rp[s0 + i + 1] - rp[s0 + i]) >> 2;
        if (nit > 127) nit = 127;
        int pos = atomicAdd(&off[nit], 1);
        sordg[j * NSTMAX + pos] = i;
    }
}

__global__ void k_scatter(const int* __restrict__ from_state, const int* __restrict__ to_state,
                          const int* __restrict__ pdf_id, const float* __restrict__ trans_logw,
                          int* __restrict__ cur, ArcT2* __restrict__ arcs)
{
    int e = blockIdx.x * blockDim.x + threadIdx.x;
    if (e >= EE) return;
    int s = to_state[e];
    int pos = atomicAdd(&cur[s], 1);
    ArcT2 a;
    a.idx = ((unsigned)from_state[e] << 3) | ((unsigned)pdf_id[e] << 19);
    a.ew = __expf(trans_logw[e]);
    arcs[pos] = a;
}

// Bank-aware in-place reorder: within each state, put arcs with
// from%8 == position%8 at matching positions. Pure permutation, one wave/state.
__global__ void k_sortbank(const int* __restrict__ rp, const int* __restrict__ counts,
                           ArcT2* __restrict__ arcs)
{
    int w = (blockIdx.x * blockDim.x + threadIdx.x) >> 6;
    int lane = threadIdx.x & 63;
    if (w >= SS) return;
    int n = counts[w];
    if (n < 2 || n > 64) return;
    int base = rp[w];
    bool valid = (lane < n);
    ArcT2 a;
    a.idx = 0; a.ew = 0.f;
    if (valid) a = arcs[base + lane];
    int c = valid ? (int)((a.idx >> 3) & 7) : -1;
    unsigned long long below = (1ull << lane) - 1ull;
    int ncArr[8];
    int myrank = 0;
    #pragma unroll
    for (int c8 = 0; c8 < 8; ++c8) {
        unsigned long long m = __ballot(valid && (c == c8));
        ncArr[c8] = (int)__popcll(m);
        if (c == c8) myrank = (int)__popcll(m & below);
    }
    int pos = -1;
    bool spill = false;
    if (valid) {
        int cap = (n > c) ? (((n - 1 - c) >> 3) + 1) : 0;
        if (myrank < cap) pos = c + (myrank << 3);
        else spill = true;
    }
    unsigned long long sm = __ballot(spill);
    if (spill) {
        int sr = (int)__popcll(sm & below);
        int accum = 0;
        #pragma unroll
        for (int c8 = 0; c8 < 8; ++c8) {
            int cap = (n > c8) ? (((n - 1 - c8) >> 3) + 1) : 0;
            int fr = cap - ncArr[c8]; if (fr < 0) fr = 0;
            if (pos < 0 && sr < accum + fr) {
                int kk = ncArr[c8] + (sr - accum);
                pos = c8 + (kk << 3);
            }
            accum += fr;
        }
    }
    if (valid) arcs[base + pos] = a;   // all lanes loaded before any store (same wave)
}

// ---------------- cooperative mega-kernel, verified XCD-local exchange ----------------
__global__ void __launch_bounds__(NT, 4) k_coop(
    const ArcT2* __restrict__ arcs, const int* __restrict__ rp,
    const int* __restrict__ split, const int* __restrict__ sordg,
    const float* __restrict__ input, const float* __restrict__ init_logp,
    const float* __restrict__ final_logp,
    float* __restrict__ partial,             // [NG][4]
    unsigned long long* __restrict__ A_all,  // [NG][2][ASTRD] u64 = 4xbf16
    unsigned* __restrict__ flags,            // [2][NBLK][FLGSTR]
    unsigned* __restrict__ xcdbuf,           // [NBLK]
    float* __restrict__ out)
{
    extern __shared__ char dsm[];
    unsigned long long* la64  = (unsigned long long*)(dsm + OFF_ALPHA);
    unsigned long long* lex64 = (unsigned long long*)(dsm + OFF_EX);
    ArcT2*    larc  = (ArcT2*)(dsm + OFF_ARC);
    int*      rbp   = (int*)(dsm + OFF_RBP);
    float*    redf  = (float*)(dsm + OFF_RED);
    int*      sh    = (int*)(dsm + OFF_SH);
    int*      sord  = (int*)(dsm + OFF_SORD);
    int*      lsp   = (int*)(dsm + OFF_LSP);

    int tid = threadIdx.x, bid = blockIdx.x;
    int x = bid & 7, y = (bid >> 3) & 1, j = bid >> 4;   // presumed-XCD, grp-in-XCD, member
    int g = x * 2 + y;                                   // group 0..15
    int lane = tid & 63, wave = tid >> 6;
    int qid = lane >> 2, sub = lane & 3;                 // 16 states/wave, 4 lanes/state

    unsigned long long* Ag = A_all + (size_t)g * (2 * ASTRD);
    unsigned* stepf    = flags;
    unsigned* auxf     = flags + (size_t)NBLK * FLGSTR;
    unsigned* myflag   = stepf + (size_t)(g * GB + j) * FLGSTR;
    unsigned* grpflag  = stepf + (size_t)(g * GB) * FLGSTR;
    unsigned* myflag2  = auxf + (size_t)(g * GB + j) * FLGSTR;
    unsigned* grpflag2 = auxf + (size_t)(g * GB) * FLGSTR;
    const float* inpG  = input + (size_t)(4 * g) * DD;

    int s0 = split[j], s1 = split[j + 1];
    int nst = s1 - s0;
    if (nst > NSTMAX) nst = NSTMAX;                      // safety (never expected)

    // ---- stage rp slice + sorted order + split + arcs to LDS ----
    for (int i = tid; i <= nst; i += NT) rbp[i] = rp[s0 + i];
    for (int i = tid; i < nst; i += NT) sord[i] = sordg[j * NSTMAX + i];
    if (tid <= GB) lsp[tid] = split[tid];
    __syncthreads();
    int rb0 = rbp[0];
    {
        int staged = rbp[nst] - rb0; if (staged > CAP) staged = CAP;
        for (int i = tid; i < staged; i += NT) larc[i] = arcs[rb0 + i];
    }

    // ---- publish XCC_ID (s_getreg id=20, offset=0, width=4 -> imm 6164) ----
    unsigned xcd = __builtin_amdgcn_s_getreg(6164) & 0xF;
    if (tid == 0)
        __hip_atomic_store(&xcdbuf[g * GB + j], xcd, __ATOMIC_RELAXED, __HIP_MEMORY_SCOPE_AGENT);
    __syncthreads();
    if (tid == 0)
        __hip_atomic_store(myflag2, 1u, __ATOMIC_RELAXED, __HIP_MEMORY_SCOPE_AGENT);
    // global aux barrier: wave0 polls all 256 aux flags (4 per lane)
    if (wave == 0) {
        while (true) {
            unsigned ok = 1;
            #pragma unroll
            for (int r = 0; r < 4; ++r) {
                unsigned v = __hip_atomic_load(auxf + (size_t)(lane * 4 + r) * FLGSTR,
                                               __ATOMIC_RELAXED, __HIP_MEMORY_SCOPE_AGENT);
                ok &= (v >= 1u);
            }
            if (__ballot(ok != 0) == ~0ULL) break;
            __builtin_amdgcn_s_sleep(1);
        }
    }
    __syncthreads();
    // decide protocol: fast iff my group is on ONE XCD and getreg is plausible
    {
        int* xint = (int*)redf;
        if (tid < NBLK)
            xint[tid] = (int)__hip_atomic_load(&xcdbuf[tid], __ATOMIC_RELAXED,
                                               __HIP_MEMORY_SCOPE_AGENT);
        __syncthreads();
        if (tid == 0) {
            int x0 = xint[g * GB];
            int uni = 1;
            for (int m = 1; m < GB; ++m) uni &= (xint[g * GB + m] == x0);
            int first = xint[0], distinct = 0;
            for (int i = 1; i < NBLK; ++i) distinct |= (xint[i] != first);
            sh[0] = uni && distinct;
        }
        __syncthreads();
    }
    const bool fast = (sh[0] != 0);
    __syncthreads();

    // Register prefetch of this thread's next-frame floats (4 batch rows).
    float pf[2][4];
    auto prefetch = [&](const float* fr) {
        int d0 = wave * EXCH;
        #pragma unroll
        for (int r = 0; r < 2; ++r) {
            int dd = r * 64 + lane;
            if (dd < EXCH) {
                int d = d0 + dd;
                #pragma unroll
                for (int c = 0; c < 4; ++c) pf[r][c] = fr[c * DD + d];
            }
        }
    };

    // Pipelined exchange (per step, after the post-gather barrier):
    //   every wave: pack+store its 125-pdf ex chunk (u64 each) from prefetched
    //   regs, then wave p polls producer p's flag and copies producer p's
    //   alpha slice (1 u64 per state) with 64 lanes.
    auto exchange = [&](unsigned epv, const unsigned long long* src64) {
        {   // ex chunk: pdfs [wave*EXCH, wave*EXCH+EXCH)
            int d0 = wave * EXCH;
            #pragma unroll
            for (int r = 0; r < 2; ++r) {
                int dd = r * 64 + lane;
                if (dd < EXCH) {
                    int d = d0 + dd;
                    unsigned w0 = (unsigned)f2b(__expf(pf[r][0])) |
                                  ((unsigned)f2b(__expf(pf[r][1])) << 16);
                    unsigned w1 = (unsigned)f2b(__expf(pf[r][2])) |
                                  ((unsigned)f2b(__expf(pf[r][3])) << 16);
                    lex64[d] = (unsigned long long)w0 | ((unsigned long long)w1 << 32);
                }
            }
        }
        int p = wave;
        const unsigned* gf = grpflag + (size_t)p * FLGSTR;
        if (fast) {
            while (*(volatile const unsigned*)gf < epv) { }
            int a = lsp[p], b = lsp[p + 1];
            for (int i = a + lane; i < b; i += 64)
                la64[i] = *(volatile const unsigned long long*)(src64 + i);
        } else {
            while (__hip_atomic_load(gf, __ATOMIC_RELAXED, __HIP_MEMORY_SCOPE_AGENT) < epv)
                __builtin_amdgcn_s_sleep(1);
            int a = lsp[p], b = lsp[p + 1];
            for (int i = a + lane; i < b; i += 64)
                la64[i] = __hip_atomic_load(src64 + i, __ATOMIC_RELAXED,
                                            __HIP_MEMORY_SCOPE_AGENT);
        }
    };

    // ---- alpha0 (own slice) with protocol-matched stores ----
    prefetch(inpG);                                      // frame 0 (issue early)
    for (int i = tid; i < nst; i += NT) {
        int s = s0 + i;
        unsigned short h = f2b(__expf(init_logp[s]));
        unsigned w = (unsigned)h | ((unsigned)h << 16);
        unsigned long long pk = (unsigned long long)w | ((unsigned long long)w << 32);
        if (fast) Ag[s] = pk;                            // plain store -> shared L2
        else __hip_atomic_store(Ag + s, pk, __ATOMIC_RELAXED, __HIP_MEMORY_SCOPE_AGENT);
    }
    __syncthreads();                                     // stores drained
    unsigned ep = 1;
    if (tid == 0) {
        if (fast) *(volatile unsigned*)myflag = ep;
        else __hip_atomic_store(myflag, ep, __ATOMIC_RELAXED, __HIP_MEMORY_SCOPE_AGENT);
    }
    exchange(ep, Ag /* buffer 0 holds alpha0 */);
    __syncthreads();

    float vf0 = 0.f, vf1 = 0.f, vf2 = 0.f, vf3 = 0.f;

    // ---- 150 steps ----
    for (int k = 0; k < TT; ++k) {
        unsigned long long* An64 = Ag + ((k + 1) & 1) * ASTRD;
        bool last = (k == TT - 1);
        bool resc = (((k + 1) & (RESC - 1)) == 0);

        if (!last) prefetch(inpG + (size_t)(k + 1) * BB * DD);  // issue next frame

        // gather own states via sorted order (4 lanes per state, 16 states/wave;
        // one u64 alpha + one u64 ex read feeds 4 batch FMAs per arc; the 4-lane
        // partial-sum reduce is 2 DPP quad_perm adds -> zero DS-pipe traffic)
        for (int base = wave * 16; base < nst; base += 256) {
            int li = base + qid;
            bool has = (li < nst);
            float acc0 = 0.f, acc1 = 0.f, acc2 = 0.f, acc3 = 0.f;
            int sg = 0;
            if (has) {
                int so = sord[li];
                sg = s0 + so;
                int ra = rbp[so], re = rbp[so + 1];
                int nit = (re - ra) >> 2;
                if (re - rb0 <= CAP) {
                    int bix = ra - rb0 + sub;
                    for (int t = 0; t < nit; ++t) {
                        ArcT2 a = larc[bix + t * 4];
                        uint2 au = *(const uint2*)(dsm + (a.idx & 0xFFFFu));
                        uint2 eu = *(const uint2*)(dsm + OFF_EX + (a.idx >> 16));
                        acc0 = fmaf(u2f(au.x << 16), a.ew * u2f(eu.x << 16), acc0);
                        acc1 = fmaf(u2f(au.x & 0xFFFF0000u), a.ew * u2f(eu.x & 0xFFFF0000u), acc1);
                        acc2 = fmaf(u2f(au.y << 16), a.ew * u2f(eu.y << 16), acc2);
                        acc3 = fmaf(u2f(au.y & 0xFFFF0000u), a.ew * u2f(eu.y & 0xFFFF0000u), acc3);
                    }
                } else {
                    for (int t = 0; t < nit; ++t) {      // safety overflow path
                        ArcT2 a = arcs[ra + t * 4 + sub];
                        uint2 au = *(const uint2*)(dsm + (a.idx & 0xFFFFu));
                        uint2 eu = *(const uint2*)(dsm + OFF_EX + (a.idx >> 16));
                        acc0 = fmaf(u2f(au.x << 16), a.ew * u2f(eu.x << 16), acc0);
                        acc1 = fmaf(u2f(au.x & 0xFFFF0000u), a.ew * u2f(eu.x & 0xFFFF0000u), acc1);
                        acc2 = fmaf(u2f(au.y << 16), a.ew * u2f(eu.y << 16), acc2);
                        acc3 = fmaf(u2f(au.y & 0xFFFF0000u), a.ew * u2f(eu.y & 0xFFFF0000u), acc3);
                    }
                }
            }
            // quad reduce: xor1 then xor2, pure VALU (DPP quad_perm)
            acc0 = dpp_add<0xB1>(acc0); acc1 = dpp_add<0xB1>(acc1);
            acc2 = dpp_add<0xB1>(acc2); acc3 = dpp_add<0xB1>(acc3);
            acc0 = dpp_add<0x4E>(acc0); acc1 = dpp_add<0x4E>(acc1);
            acc2 = dpp_add<0x4E>(acc2); acc3 = dpp_add<0x4E>(acc3);
            if (has && sub == 0) {
                if (resc) { acc0 *= RESCC; acc1 *= RESCC; acc2 *= RESCC; acc3 *= RESCC; }
                if (last) {
                    float ef = __expf(final_logp[sg]);
                    vf0 = fmaf(acc0, ef, vf0);
                    vf1 = fmaf(acc1, ef, vf1);
                    vf2 = fmaf(acc2, ef, vf2);
                    vf3 = fmaf(acc3, ef, vf3);
                } else {
                    unsigned w0 = (unsigned)f2b(acc0) | ((unsigned)f2b(acc1) << 16);
                    unsigned w1 = (unsigned)f2b(acc2) | ((unsigned)f2b(acc3) << 16);
                    unsigned long long pk = (unsigned long long)w0 |
                                            ((unsigned long long)w1 << 32);
                    if (fast) An64[sg] = pk;             // plain store -> shared L2
                    else __hip_atomic_store(An64 + sg, pk, __ATOMIC_RELAXED,
                                            __HIP_MEMORY_SCOPE_AGENT);
                }
            }
        }
        if (last) break;
        __syncthreads();                                 // stores drained (vmcnt 0)
        ++ep;
        if (tid == 0) {
            if (fast) *(volatile unsigned*)myflag = ep;
            else __hip_atomic_store(myflag, ep, __ATOMIC_RELAXED, __HIP_MEMORY_SCOPE_AGENT);
        }
        exchange(ep, An64);
        __syncthreads();
    }

    // ---- epilogue: reduce objf over this block's states ----
    if (sub == 0) {
        int r0 = (wave * 16 + qid) * 4;
        redf[r0 + 0] = vf0; redf[r0 + 1] = vf1;
        redf[r0 + 2] = vf2; redf[r0 + 3] = vf3;
    }
    __syncthreads();
    if (tid < 4) {
        float S = 0.f;
        for (int i = 0; i < 256; ++i) S += redf[i * 4 + tid];
        __hip_atomic_fetch_add(&partial[g * 4 + tid], S, __ATOMIC_RELAXED,
                               __HIP_MEMORY_SCOPE_AGENT);
    }
    __syncthreads();
    if (tid == 0)
        __hip_atomic_store(myflag2, 2u, __ATOMIC_RELAXED, __HIP_MEMORY_SCOPE_AGENT);
    if (j == 0) {
        if (wave == 0) {
            while (true) {
                unsigned v = 2;
                if (lane < GB)
                    v = __hip_atomic_load(grpflag2 + lane * FLGSTR, __ATOMIC_RELAXED,
                                          __HIP_MEMORY_SCOPE_AGENT);
                if (__ballot(v >= 2) == ~0ULL) break;
                __builtin_amdgcn_s_sleep(1);
            }
        }
        __syncthreads();
        if (tid < 4) {
            float S = __hip_atomic_load(&partial[g * 4 + tid], __ATOMIC_RELAXED,
                                        __HIP_MEMORY_SCOPE_AGENT);
            float lg = logf(S) + (float)(NSLOT * 46) * 0.69314718055994531f;
            atomicAdd(out, lg);
        }
    }
}

// ---------------- fallback path (round-6 per-step kernels) ----------------
template <int THREADS>
__device__ inline void transpose_exp_t(const float* __restrict__ frame,
                                       unsigned short* __restrict__ dst,
                                       int tile_id, int tid, unsigned short* smem)
{
    int d0 = tile_id * 64;
    #pragma unroll
    for (int it = 0; it < 4096 / THREADS; ++it) {
        int idx = it * THREADS + tid;
        int dl = idx & 63, bl = idx >> 6;
        int d = d0 + dl;
        float v = 0.f;
        if (d < DD) v = __expf(frame[bl * DD + d]);
        smem[dl * 65 + bl] = f2b(v);
    }
    __syncthreads();
    #pragma unroll
    for (int it = 0; it < 4096 / THREADS; ++it) {
        int idx = it * THREADS + tid;
        int bo = idx & 63, dq = idx >> 6;
        int d = d0 + dq;
        if (d < DD) dst[(d << 6) + bo] = smem[dq * 65 + bo];
    }
    __syncthreads();
}

__global__ void k_initA(const float* __restrict__ init_logp,
                        unsigned short* __restrict__ A0, float* __restrict__ M2)
{
    int idx = blockIdx.x * blockDim.x + threadIdx.x;
    if (idx < SS * BB) A0[idx] = f2b(__expf(init_logp[idx >> 6]));
    if (idx < NSLOT * 16 * 64) M2[idx] = 0.f;
}

__global__ void k_transpose0(const float* __restrict__ frame, unsigned short* __restrict__ dst)
{
    __shared__ unsigned short tile[64 * 65];
    transpose_exp_t<256>(frame, dst, blockIdx.x, threadIdx.x, tile);
}

__global__ void __launch_bounds__(256) k_step(
    const ArcT2* __restrict__ arcs, const int* __restrict__ rp,
    const unsigned short* __restrict__ Ap, unsigned short* __restrict__ An,
    const unsigned short* __restrict__ ec,
    const float* __restrict__ frameNext, unsigned short* __restrict__ en,
    float* __restrict__ M2, int maxSlot, int useSlot)
{
    __shared__ unsigned short tile[64 * 65];
    __shared__ float part[256];
    __shared__ float rcpA[64];
    int tid = threadIdx.x, bid = blockIdx.x;
    if (bid >= SS) { transpose_exp_t<256>(frameNext, en, bid - SS, tid, tile); return; }
    int lane = tid & 63, wave = tid >> 6;
    if (useSlot >= 0 && wave == 0) {
        const float* Mrow = M2 + useSlot * (16 * 64);
        float m = Mrow[lane];
        #pragma unroll
        for (int g = 1; g < 16; ++g) m = fmaxf(m, Mrow[g * 64 + lane]);
        rcpA[lane] = 1.0f / m;
    }
    int rbeg = rp[bid], rend = rp[bid + 1];
    float acc = 0.f;
    for (int i = rbeg + wave; i < rend; i += 4) {
        ArcT2 a = arcs[i];
        int from = (a.idx & 0xFFFF) >> 3, pdf = a.idx >> 19;
        acc = fmaf(b2f(Ap[(from << 6) + lane]), a.ew * b2f(ec[(pdf << 6) + lane]), acc);
    }
    part[tid] = acc;
    __syncthreads();
    if (wave == 0) {
        float sum = part[lane] + part[64 + lane] + part[128 + lane] + part[192 + lane];
        if (useSlot >= 0) sum *= rcpA[lane];
        An[(bid << 6) + lane] = f2b(sum);
        if (maxSlot >= 0)
            atomicMax((unsigned*)&M2[maxSlot * (16 * 64) + (bid & 15) * 64 + lane],
                      __float_as_uint(sum));
    }
}

__global__ void k_fin(const unsigned short* __restrict__ AT, const float* __restrict__ final_logp,
                      const float* __restrict__ M2, float* __restrict__ out)
{
    __shared__ float red[1024];
    int tid = threadIdx.x;
    int lane = tid & 63, chunk = tid >> 6;
    float psum = 0.f;
    for (int s = chunk; s < SS; s += 16)
        psum += b2f(AT[(s << 6) + lane]) * __expf(final_logp[s]);
    red[tid] = psum;
    __syncthreads();
    if (tid < 64) {
        float sum = 0.f;
        #pragma unroll
        for (int c = 0; c < 16; ++c) sum += red[c * 64 + tid];
        float lg = logf(sum);
        #pragma unroll
        for (int r = 0; r < NSLOT; ++r) {
            const float* Mrow = M2 + r * (16 * 64);
            float m = Mrow[tid];
            #pragma unroll
            for (int g = 1; g < 16; ++g) m = fmaxf(m, Mrow[g * 64 + tid]);
            lg += logf(m);
        }
        #pragma unroll
        for (int off = 32; off > 0; off >>= 1) lg += __shfl_down(lg, off);
        if (tid == 0) out[0] = lg;
    }
}

extern "C" void kernel_launch(void* const* d_in, const int* in_sizes, int n_in,
                              void* d_out, int out_size, void* d_ws, size_t ws_size,
                              hipStream_t stream)
{
    const float* input      = (const float*)d_in[0];
    const float* trans_logw = (const float*)d_in[1];
    const float* init_logp  = (const float*)d_in[2];
    const float* final_logp = (const float*)d_in[3];
    const int*   from_state = (const int*)d_in[4];
    const int*   to_state   = (const int*)d_in[5];
    const int*   pdf_id     = (const int*)d_in[6];
    float* out = (float*)d_out;

    char* ws = (char*)d_ws;
    size_t off = 0;
    auto alloc = [&](size_t bytes) -> char* {
        char* p = ws + off;
        off = (off + bytes + 255) & ~(size_t)255;
        return p;
    };
    ArcT2* arcs  = (ArcT2*)alloc((size_t)EEPAD * sizeof(ArcT2));
    int* rp      = (int*)alloc((size_t)(SS + 1) * 4);
    int* cur     = (int*)alloc((size_t)SS * 4);
    int* counts  = (int*)alloc((size_t)SS * 4);
    int* split   = (int*)alloc((size_t)(GB + 1) * 4);
    int* sordg   = (int*)alloc((size_t)GB * NSTMAX * 4);
    unsigned long long* A_all = (unsigned long long*)alloc((size_t)NG * 2 * ASTRD * 8);
    float* partial  = (float*)alloc((size_t)NG * 4 * 4);
    unsigned* flags = (unsigned*)alloc((size_t)2 * NBLK * FLGSTR * 4);
    unsigned* xcdbuf = (unsigned*)alloc((size_t)NBLK * 4);
    // fallback buffers
    unsigned short* A0  = (unsigned short*)alloc((size_t)SS * BB * 2);
    unsigned short* A1  = (unsigned short*)alloc((size_t)SS * BB * 2);
    unsigned short* EX0 = (unsigned short*)alloc((size_t)DD * BB * 2);
    unsigned short* EX1 = (unsigned short*)alloc((size_t)DD * BB * 2);
    float* M2    = (float*)alloc((size_t)NSLOT * 16 * 64 * 4);
    (void)ws_size; (void)in_sizes; (void)n_in; (void)out_size;

    k_init0<<<64, 256, 0, stream>>>(counts, flags, partial);
    k_zeroarcs<<<(EEPAD + 255) / 256, 256, 0, stream>>>(arcs);
    k_hist<<<(EE + 255) / 256, 256, 0, stream>>>(to_state, counts);
    k_scan<<<1, 1024, 0, stream>>>(counts, rp, cur);
    k_split<<<1, 32, 0, stream>>>(rp, split);
    k_sortst<<<GB, 256, 0, stream>>>(rp, split, sordg);
    k_scatter<<<(EE + 255) / 256, 256, 0, stream>>>(from_state, to_state, pdf_id,
                                                    trans_logw, cur, arcs);
    k_sortbank<<<(SS * 64 + 255) / 256, 256, 0, stream>>>(rp, counts, arcs);
    hipMemsetAsync(d_out, 0, sizeof(float), stream);

    hipFuncSetAttribute((const void*)k_coop, hipFuncAttributeMaxDynamicSharedMemorySize,
                        DYNLDS);
    int nb = 0;
    hipOccupancyMaxActiveBlocksPerMultiprocessor(&nb, (const void*)k_coop, NT, DYNLDS);
    if (nb >= 1) {
        void* kp[12] = {
            (void*)&arcs, (void*)&rp, (void*)&split, (void*)&sordg, (void*)&input,
            (void*)&init_logp, (void*)&final_logp, (void*)&partial, (void*)&A_all,
            (void*)&flags, (void*)&xcdbuf, (void*)&out
        };
        hipError_t e = hipLaunchCooperativeKernel((const void*)k_coop, dim3(NBLK), dim3(NT),
                                                  kp, DYNLDS, stream);
        if (e == hipSuccess) return;
    }

    // Fallback: per-step kernels (bf16 state), known-passing structure.
    k_initA<<<(SS * BB + 255) / 256, 256, 0, stream>>>(init_logp, A0, M2);
    k_transpose0<<<NEXB, 256, 0, stream>>>(input, EX0);
    unsigned short* A[2]  = {A0, A1};
    unsigned short* EX[2] = {EX0, EX1};
    for (int k = 0; k < TT; ++k) {
        int kn = k + 1;
        int useSlot = (k > 0 && (k % RESC) == 0) ? (k / RESC - 1) : -1;
        int maxSlot = (kn < TT && (kn % RESC) == 0) ? (kn / RESC - 1) : -1;
        int grid = SS + ((kn < TT) ? NEXB : 0);
        const float* fnext = (kn < TT) ? (input + (size_t)kn * BB * DD) : nullptr;
        k_step<<<grid, 256, 0, stream>>>(arcs, rp, A[k & 1], A[kn & 1], EX[k & 1],
                                         fnext, EX[kn & 1], M2, maxSlot, useSlot);
    }
    k_fin<<<1, 1024, 0, stream>>>(A[TT & 1], final_logp, M2, out);
}

// Round 10
// 639.966 us; speedup vs baseline: 1.5590x; 1.0257x over previous
//
#include <hip/hip_runtime.h>
#include <math.h>

#define TT 150
#define BB 64
#define DD 2000
#define SS 3000
#define EE 100000
#define EEPAD 124160   // >= EE + SS*7 (arcs padded per-state to multiple of 8)
#define RESC 16
#define NSLOT 9
#define RESCC 0x1p-46f // exact pow2 rescale every 16 steps (growth ~7.42^16 ~= 2^46.3)

#define NT 1024        // threads per block (16 waves)
#define NBLK 256       // 1 block per CU
#define NG 16          // groups, 4 batch lanes each
#define GB 16          // blocks per group (bid = x + 8y + 16j -> same XCD x)
#define CAP 8192       // LDS arc slots per block (max slice ~7k)
#define ASTRD 3072     // u64 words per alpha buffer per group (SS=3000 padded)
#define NSTMAX 1024
#define FLGSTR 32      // dwords between flags (128 B)
#define NEXB 32
#define EXCH 125       // ex pdfs per wave (16*125 = 2000 = DD)

// dynamic LDS layout (bytes). Alpha table at byte 0 so the gather's
// ds_read address is just (idx & 0xFFFF); ex base folds into the offset.
#define OFF_ALPHA  0                 // SS*8  -> 24064 (u64: 4xbf16 per state)
#define OFF_EX     24064             // DD*8  -> 16128 (u64: 4xbf16 per pdf)
#define OFF_ARC    40192             // CAP*8 = 65536
#define OFF_RBP    105728            // (NSTMAX+1)*4 -> 4112
#define OFF_SORD   109840            // NSTMAX*4 = 4096
#define OFF_RED    113936            // 256*4*4 = 4096
#define OFF_SH     118032            // 16
#define OFF_LSP    118048            // (GB+1)*4 -> 80
#define DYNLDS     118128

// idx = (from<<3) | (pdf<<19): both halves are ready-made BYTE offsets into
// the u64 LDS tables (from*8 <= 23992 < 2^15; idx>>16 == pdf*8 <= 15992).
// NOTE (r10): arcs stay in scatter order. The old k_sortbank (from%8==pos%8)
// was designed for the 8-lane/stride-8 gather; with 4 lanes/state and rp
// multiples of 8 it concentrated even-t alpha reads onto 2 bank-pairs per
// sub-class (8-way conflict). Random order ~2-way expected.
struct __align__(8) ArcT2 { unsigned idx; float ew; };

__device__ inline float b2f(unsigned short u) {
    union { unsigned u32; float f; } x; x.u32 = ((unsigned)u) << 16; return x.f;
}
__device__ inline unsigned short f2b(float f) {
    union { float f; unsigned u; } x; x.f = f;
    unsigned r = x.u + 0x7FFF + ((x.u >> 16) & 1);       // RNE, positive finite only
    return (unsigned short)(r >> 16);
}
__device__ inline float u2f(unsigned u) {
    union { unsigned u32; float f; } x; x.u32 = u; return x.f;
}

// Cross-lane add via DPP quad_perm (pure VALU, no DS-pipe traffic).
// 0xB1 = quad_perm(1,0,3,2) = xor1; 0x4E = quad_perm(2,3,0,1) = xor2.
// NOTE: dpp_ctrl must be a compile-time constant -> template parameter.
template <int CTRL>
__device__ inline float dpp_add(float v) {
    int x = __builtin_amdgcn_update_dpp(0, __float_as_int(v), CTRL, 0xF, 0xF, true);
    return v + __int_as_float(x);
}

// ---------------- setup kernels ----------------
__global__ void k_init0(int* __restrict__ counts, unsigned* __restrict__ flags,
                        float* __restrict__ partial)
{
    int i = blockIdx.x * blockDim.x + threadIdx.x;
    if (i < SS) counts[i] = 0;
    if (i < 2 * NBLK * FLGSTR) flags[i] = 0u;
    if (i < NG * 4) partial[i] = 0.f;
}

__global__ void k_zeroarcs(ArcT2* __restrict__ arcs)
{
    int i = blockIdx.x * blockDim.x + threadIdx.x;
    if (i < EEPAD) { ArcT2 z; z.idx = 0; z.ew = 0.f; arcs[i] = z; }
}

__global__ void k_hist(const int* __restrict__ to_state, int* __restrict__ counts)
{
    int e = blockIdx.x * blockDim.x + threadIdx.x;
    if (e < EE) atomicAdd(&counts[to_state[e]], 1);
}

// prefix over counts padded to multiple of 8
__global__ void k_scan(const int* __restrict__ counts, int* __restrict__ rp,
                       int* __restrict__ cur)
{
    __shared__ int ls[1024];
    int tid = threadIdx.x;
    int s0 = tid * 3;
    int a0 = (s0 + 0 < SS) ? ((counts[s0 + 0] + 7) & ~7) : 0;
    int a1 = (s0 + 1 < SS) ? ((counts[s0 + 1] + 7) & ~7) : 0;
    int a2 = (s0 + 2 < SS) ? ((counts[s0 + 2] + 7) & ~7) : 0;
    int tsum = a0 + a1 + a2;
    ls[tid] = tsum;
    __syncthreads();
    for (int off = 1; off < 1024; off <<= 1) {
        int v = ls[tid];
        int add = (tid >= off) ? ls[tid - off] : 0;
        __syncthreads();
        ls[tid] = v + add;
        __syncthreads();
    }
    int excl = ls[tid] - tsum;
    if (s0 + 0 < SS) { rp[s0 + 0] = excl; cur[s0 + 0] = excl; }
    excl += a0;
    if (s0 + 1 < SS) { rp[s0 + 1] = excl; cur[s0 + 1] = excl; }
    excl += a1;
    if (s0 + 2 < SS) { rp[s0 + 2] = excl; cur[s0 + 2] = excl; }
    if (tid == 1023) rp[SS] = ls[1023];
}

// arc-balanced split into GB slices
__global__ void k_split(const int* __restrict__ rp, int* __restrict__ split)
{
    int j = threadIdx.x;
    if (j > GB) return;
    if (j == 0)  { split[0] = 0; return; }
    if (j == GB) { split[GB] = SS; return; }
    long long total = rp[SS];
    int target = (int)((total * j) / GB);
    int lo = 0, hi = SS;
    while (lo < hi) { int mid = (lo + hi) >> 1; if (rp[mid] >= target) hi = mid; else lo = mid + 1; }
    split[j] = lo;
}

// Per-slice counting sort of states by descending arc count (gather wave time
// = max nit over its 16 states -> max ~= mean after sorting). Shared by groups.
__global__ void k_sortst(const int* __restrict__ rp, const int* __restrict__ split,
                         int* __restrict__ sordg)
{
    __shared__ int hist[128];
    __shared__ int off[128];
    int j = blockIdx.x;                      // slice 0..GB-1
    int s0 = split[j], s1 = split[j + 1];
    int nst = s1 - s0; if (nst > NSTMAX) nst = NSTMAX;
    int tid = threadIdx.x;                   // 256 threads
    if (tid < 128) hist[tid] = 0;
    __syncthreads();
    for (int i = tid; i < nst; i += 256) {
        int nit = (rp[s0 + i + 1] - rp[s0 + i]) >> 2;
        if (nit > 127) nit = 127;
        atomicAdd(&hist[nit], 1);
    }
    __syncthreads();
    if (tid == 0) {
        int acc = 0;
        for (int b = 127; b >= 0; --b) { off[b] = acc; acc += hist[b]; }
    }
    __syncthreads();
    for (int i = tid; i < nst; i += 256) {
        int nit = (rp[s0 + i + 1] - rp[s0 + i]) >> 2;
        if (nit > 127) nit = 127;
        int pos = atomicAdd(&off[nit], 1);
        sordg[j * NSTMAX + pos] = i;
    }
}

__global__ void k_scatter(const int* __restrict__ from_state, const int* __restrict__ to_state,
                          const int* __restrict__ pdf_id, const float* __restrict__ trans_logw,
                          int* __restrict__ cur, ArcT2* __restrict__ arcs)
{
    int e = blockIdx.x * blockDim.x + threadIdx.x;
    if (e >= EE) return;
    int s = to_state[e];
    int pos = atomicAdd(&cur[s], 1);
    ArcT2 a;
    a.idx = ((unsigned)from_state[e] << 3) | ((unsigned)pdf_id[e] << 19);
    a.ew = __expf(trans_logw[e]);
    arcs[pos] = a;
}

// ---------------- cooperative mega-kernel, verified XCD-local exchange ----------------
__global__ void __launch_bounds__(NT, 4) k_coop(
    const ArcT2* __restrict__ arcs, const int* __restrict__ rp,
    const int* __restrict__ split, const int* __restrict__ sordg,
    const float* __restrict__ input, const float* __restrict__ init_logp,
    const float* __restrict__ final_logp,
    float* __restrict__ partial,             // [NG][4]
    unsigned long long* __restrict__ A_all,  // [NG][2][ASTRD] u64 = 4xbf16
    unsigned* __restrict__ flags,            // [2][NBLK][FLGSTR]
    unsigned* __restrict__ xcdbuf,           // [NBLK]
    float* __restrict__ out)
{
    extern __shared__ char dsm[];
    unsigned long long* la64  = (unsigned long long*)(dsm + OFF_ALPHA);
    unsigned long long* lex64 = (unsigned long long*)(dsm + OFF_EX);
    ArcT2*    larc  = (ArcT2*)(dsm + OFF_ARC);
    int*      rbp   = (int*)(dsm + OFF_RBP);
    float*    redf  = (float*)(dsm + OFF_RED);
    int*      sh    = (int*)(dsm + OFF_SH);
    int*      sord  = (int*)(dsm + OFF_SORD);
    int*      lsp   = (int*)(dsm + OFF_LSP);

    int tid = threadIdx.x, bid = blockIdx.x;
    int x = bid & 7, y = (bid >> 3) & 1, j = bid >> 4;   // presumed-XCD, grp-in-XCD, member
    int g = x * 2 + y;                                   // group 0..15
    int lane = tid & 63, wave = tid >> 6;
    int qid = lane >> 2, sub = lane & 3;                 // 16 states/wave, 4 lanes/state

    unsigned long long* Ag = A_all + (size_t)g * (2 * ASTRD);
    unsigned* stepf    = flags;
    unsigned* auxf     = flags + (size_t)NBLK * FLGSTR;
    unsigned* myflag   = stepf + (size_t)(g * GB + j) * FLGSTR;
    unsigned* grpflag  = stepf + (size_t)(g * GB) * FLGSTR;
    unsigned* myflag2  = auxf + (size_t)(g * GB + j) * FLGSTR;
    unsigned* grpflag2 = auxf + (size_t)(g * GB) * FLGSTR;
    const float* inpG  = input + (size_t)(4 * g) * DD;

    int s0 = split[j], s1 = split[j + 1];
    int nst = s1 - s0;
    if (nst > NSTMAX) nst = NSTMAX;                      // safety (never expected)

    // ---- stage rp slice + sorted order + split + arcs to LDS ----
    for (int i = tid; i <= nst; i += NT) rbp[i] = rp[s0 + i];
    for (int i = tid; i < nst; i += NT) sord[i] = sordg[j * NSTMAX + i];
    if (tid <= GB) lsp[tid] = split[tid];
    __syncthreads();
    int rb0 = rbp[0];
    {
        int staged = rbp[nst] - rb0; if (staged > CAP) staged = CAP;
        for (int i = tid; i < staged; i += NT) larc[i] = arcs[rb0 + i];
    }

    // ---- publish XCC_ID (s_getreg id=20, offset=0, width=4 -> imm 6164) ----
    unsigned xcd = __builtin_amdgcn_s_getreg(6164) & 0xF;
    if (tid == 0)
        __hip_atomic_store(&xcdbuf[g * GB + j], xcd, __ATOMIC_RELAXED, __HIP_MEMORY_SCOPE_AGENT);
    __syncthreads();
    if (tid == 0)
        __hip_atomic_store(myflag2, 1u, __ATOMIC_RELAXED, __HIP_MEMORY_SCOPE_AGENT);
    // global aux barrier: wave0 polls all 256 aux flags (4 per lane)
    if (wave == 0) {
        while (true) {
            unsigned ok = 1;
            #pragma unroll
            for (int r = 0; r < 4; ++r) {
                unsigned v = __hip_atomic_load(auxf + (size_t)(lane * 4 + r) * FLGSTR,
                                               __ATOMIC_RELAXED, __HIP_MEMORY_SCOPE_AGENT);
                ok &= (v >= 1u);
            }
            if (__ballot(ok != 0) == ~0ULL) break;
            __builtin_amdgcn_s_sleep(1);
        }
    }
    __syncthreads();
    // decide protocol: fast iff my group is on ONE XCD and getreg is plausible
    {
        int* xint = (int*)redf;
        if (tid < NBLK)
            xint[tid] = (int)__hip_atomic_load(&xcdbuf[tid], __ATOMIC_RELAXED,
                                               __HIP_MEMORY_SCOPE_AGENT);
        __syncthreads();
        if (tid == 0) {
            int x0 = xint[g * GB];
            int uni = 1;
            for (int m = 1; m < GB; ++m) uni &= (xint[g * GB + m] == x0);
            int first = xint[0], distinct = 0;
            for (int i = 1; i < NBLK; ++i) distinct |= (xint[i] != first);
            sh[0] = uni && distinct;
        }
        __syncthreads();
    }
    const bool fast = (sh[0] != 0);
    __syncthreads();

    // Register prefetch of this thread's next-frame floats (4 batch rows).
    float pf[2][4];
    auto prefetch = [&](const float* fr) {
        int d0 = wave * EXCH;
        #pragma unroll
        for (int r = 0; r < 2; ++r) {
            int dd = r * 64 + lane;
            if (dd < EXCH) {
                int d = d0 + dd;
                #pragma unroll
                for (int c = 0; c < 4; ++c) pf[r][c] = fr[c * DD + d];
            }
        }
    };

    // Pipelined exchange (per step, after the post-gather barrier):
    //   every wave: pack+store its 125-pdf ex chunk (u64 each) from prefetched
    //   regs, then wave p polls producer p's flag and copies producer p's
    //   alpha slice (1 u64 per state) with 64 lanes.
    auto exchange = [&](unsigned epv, const unsigned long long* src64) {
        {   // ex chunk: pdfs [wave*EXCH, wave*EXCH+EXCH)
            int d0 = wave * EXCH;
            #pragma unroll
            for (int r = 0; r < 2; ++r) {
                int dd = r * 64 + lane;
                if (dd < EXCH) {
                    int d = d0 + dd;
                    unsigned w0 = (unsigned)f2b(__expf(pf[r][0])) |
                                  ((unsigned)f2b(__expf(pf[r][1])) << 16);
                    unsigned w1 = (unsigned)f2b(__expf(pf[r][2])) |
                                  ((unsigned)f2b(__expf(pf[r][3])) << 16);
                    lex64[d] = (unsigned long long)w0 | ((unsigned long long)w1 << 32);
                }
            }
        }
        int p = wave;
        const unsigned* gf = grpflag + (size_t)p * FLGSTR;
        if (fast) {
            while (*(volatile const unsigned*)gf < epv) { }
            int a = lsp[p], b = lsp[p + 1];
            for (int i = a + lane; i < b; i += 64)
                la64[i] = *(volatile const unsigned long long*)(src64 + i);
        } else {
            while (__hip_atomic_load(gf, __ATOMIC_RELAXED, __HIP_MEMORY_SCOPE_AGENT) < epv)
                __builtin_amdgcn_s_sleep(1);
            int a = lsp[p], b = lsp[p + 1];
            for (int i = a + lane; i < b; i += 64)
                la64[i] = __hip_atomic_load(src64 + i, __ATOMIC_RELAXED,
                                            __HIP_MEMORY_SCOPE_AGENT);
        }
    };

    // ---- alpha0 (own slice) with protocol-matched stores ----
    prefetch(inpG);                                      // frame 0 (issue early)
    for (int i = tid; i < nst; i += NT) {
        int s = s0 + i;
        unsigned short h = f2b(__expf(init_logp[s]));
        unsigned w = (unsigned)h | ((unsigned)h << 16);
        unsigned long long pk = (unsigned long long)w | ((unsigned long long)w << 32);
        if (fast) Ag[s] = pk;                            // plain store -> shared L2
        else __hip_atomic_store(Ag + s, pk, __ATOMIC_RELAXED, __HIP_MEMORY_SCOPE_AGENT);
    }
    __syncthreads();                                     // stores drained
    unsigned ep = 1;
    if (tid == 0) {
        if (fast) *(volatile unsigned*)myflag = ep;
        else __hip_atomic_store(myflag, ep, __ATOMIC_RELAXED, __HIP_MEMORY_SCOPE_AGENT);
    }
    exchange(ep, Ag /* buffer 0 holds alpha0 */);
    __syncthreads();

    float vf0 = 0.f, vf1 = 0.f, vf2 = 0.f, vf3 = 0.f;

    // ---- 150 steps ----
    for (int k = 0; k < TT; ++k) {
        unsigned long long* An64 = Ag + ((k + 1) & 1) * ASTRD;
        bool last = (k == TT - 1);
        bool resc = (((k + 1) & (RESC - 1)) == 0);

        if (!last) prefetch(inpG + (size_t)(k + 1) * BB * DD);  // issue next frame

        // gather own states via sorted order (4 lanes per state, 16 states/wave;
        // one u64 alpha + one u64 ex read feeds 4 batch FMAs per arc; the 4-lane
        // partial-sum reduce is 2 DPP quad_perm adds -> zero DS-pipe traffic)
        for (int base = wave * 16; base < nst; base += 256) {
            int li = base + qid;
            bool has = (li < nst);
            float acc0 = 0.f, acc1 = 0.f, acc2 = 0.f, acc3 = 0.f;
            int sg = 0;
            if (has) {
                int so = sord[li];
                sg = s0 + so;
                int ra = rbp[so], re = rbp[so + 1];
                int nit = (re - ra) >> 2;
                if (re - rb0 <= CAP) {
                    int bix = ra - rb0 + sub;
                    for (int t = 0; t < nit; ++t) {
                        ArcT2 a = larc[bix + t * 4];
                        uint2 au = *(const uint2*)(dsm + (a.idx & 0xFFFFu));
                        uint2 eu = *(const uint2*)(dsm + OFF_EX + (a.idx >> 16));
                        acc0 = fmaf(u2f(au.x << 16), a.ew * u2f(eu.x << 16), acc0);
                        acc1 = fmaf(u2f(au.x & 0xFFFF0000u), a.ew * u2f(eu.x & 0xFFFF0000u), acc1);
                        acc2 = fmaf(u2f(au.y << 16), a.ew * u2f(eu.y << 16), acc2);
                        acc3 = fmaf(u2f(au.y & 0xFFFF0000u), a.ew * u2f(eu.y & 0xFFFF0000u), acc3);
                    }
                } else {
                    for (int t = 0; t < nit; ++t) {      // safety overflow path
                        ArcT2 a = arcs[ra + t * 4 + sub];
                        uint2 au = *(const uint2*)(dsm + (a.idx & 0xFFFFu));
                        uint2 eu = *(const uint2*)(dsm + OFF_EX + (a.idx >> 16));
                        acc0 = fmaf(u2f(au.x << 16), a.ew * u2f(eu.x << 16), acc0);
                        acc1 = fmaf(u2f(au.x & 0xFFFF0000u), a.ew * u2f(eu.x & 0xFFFF0000u), acc1);
                        acc2 = fmaf(u2f(au.y << 16), a.ew * u2f(eu.y << 16), acc2);
                        acc3 = fmaf(u2f(au.y & 0xFFFF0000u), a.ew * u2f(eu.y & 0xFFFF0000u), acc3);
                    }
                }
            }
            // quad reduce: xor1 then xor2, pure VALU (DPP quad_perm)
            acc0 = dpp_add<0xB1>(acc0); acc1 = dpp_add<0xB1>(acc1);
            acc2 = dpp_add<0xB1>(acc2); acc3 = dpp_add<0xB1>(acc3);
            acc0 = dpp_add<0x4E>(acc0); acc1 = dpp_add<0x4E>(acc1);
            acc2 = dpp_add<0x4E>(acc2); acc3 = dpp_add<0x4E>(acc3);
            if (has && sub == 0) {
                if (resc) { acc0 *= RESCC; acc1 *= RESCC; acc2 *= RESCC; acc3 *= RESCC; }
                if (last) {
                    float ef = __expf(final_logp[sg]);
                    vf0 = fmaf(acc0, ef, vf0);
                    vf1 = fmaf(acc1, ef, vf1);
                    vf2 = fmaf(acc2, ef, vf2);
                    vf3 = fmaf(acc3, ef, vf3);
                } else {
                    unsigned w0 = (unsigned)f2b(acc0) | ((unsigned)f2b(acc1) << 16);
                    unsigned w1 = (unsigned)f2b(acc2) | ((unsigned)f2b(acc3) << 16);
                    unsigned long long pk = (unsigned long long)w0 |
                                            ((unsigned long long)w1 << 32);
                    if (fast) An64[sg] = pk;             // plain store -> shared L2
                    else __hip_atomic_store(An64 + sg, pk, __ATOMIC_RELAXED,
                                            __HIP_MEMORY_SCOPE_AGENT);
                }
            }
        }
        if (last) break;
        __syncthreads();                                 // stores drained (vmcnt 0)
        ++ep;
        if (tid == 0) {
            if (fast) *(volatile unsigned*)myflag = ep;
            else __hip_atomic_store(myflag, ep, __ATOMIC_RELAXED, __HIP_MEMORY_SCOPE_AGENT);
        }
        exchange(ep, An64);
        __syncthreads();
    }

    // ---- epilogue: reduce objf over this block's states ----
    if (sub == 0) {
        int r0 = (wave * 16 + qid) * 4;
        redf[r0 + 0] = vf0; redf[r0 + 1] = vf1;
        redf[r0 + 2] = vf2; redf[r0 + 3] = vf3;
    }
    __syncthreads();
    if (tid < 4) {
        float S = 0.f;
        for (int i = 0; i < 256; ++i) S += redf[i * 4 + tid];
        __hip_atomic_fetch_add(&partial[g * 4 + tid], S, __ATOMIC_RELAXED,
                               __HIP_MEMORY_SCOPE_AGENT);
    }
    __syncthreads();
    if (tid == 0)
        __hip_atomic_store(myflag2, 2u, __ATOMIC_RELAXED, __HIP_MEMORY_SCOPE_AGENT);
    if (j == 0) {
        if (wave == 0) {
            while (true) {
                unsigned v = 2;
                if (lane < GB)
                    v = __hip_atomic_load(grpflag2 + lane * FLGSTR, __ATOMIC_RELAXED,
                                          __HIP_MEMORY_SCOPE_AGENT);
                if (__ballot(v >= 2) == ~0ULL) break;
                __builtin_amdgcn_s_sleep(1);
            }
        }
        __syncthreads();
        if (tid < 4) {
            float S = __hip_atomic_load(&partial[g * 4 + tid], __ATOMIC_RELAXED,
                                        __HIP_MEMORY_SCOPE_AGENT);
            float lg = logf(S) + (float)(NSLOT * 46) * 0.69314718055994531f;
            atomicAdd(out, lg);
        }
    }
}

// ---------------- fallback path (round-6 per-step kernels) ----------------
template <int THREADS>
__device__ inline void transpose_exp_t(const float* __restrict__ frame,
                                       unsigned short* __restrict__ dst,
                                       int tile_id, int tid, unsigned short* smem)
{
    int d0 = tile_id * 64;
    #pragma unroll
    for (int it = 0; it < 4096 / THREADS; ++it) {
        int idx = it * THREADS + tid;
        int dl = idx & 63, bl = idx >> 6;
        int d = d0 + dl;
        float v = 0.f;
        if (d < DD) v = __expf(frame[bl * DD + d]);
        smem[dl * 65 + bl] = f2b(v);
    }
    __syncthreads();
    #pragma unroll
    for (int it = 0; it < 4096 / THREADS; ++it) {
        int idx = it * THREADS + tid;
        int bo = idx & 63, dq = idx >> 6;
        int d = d0 + dq;
        if (d < DD) dst[(d << 6) + bo] = smem[dq * 65 + bo];
    }
    __syncthreads();
}

__global__ void k_initA(const float* __restrict__ init_logp,
                        unsigned short* __restrict__ A0, float* __restrict__ M2)
{
    int idx = blockIdx.x * blockDim.x + threadIdx.x;
    if (idx < SS * BB) A0[idx] = f2b(__expf(init_logp[idx >> 6]));
    if (idx < NSLOT * 16 * 64) M2[idx] = 0.f;
}

__global__ void k_transpose0(const float* __restrict__ frame, unsigned short* __restrict__ dst)
{
    __shared__ unsigned short tile[64 * 65];
    transpose_exp_t<256>(frame, dst, blockIdx.x, threadIdx.x, tile);
}

__global__ void __launch_bounds__(256) k_step(
    const ArcT2* __restrict__ arcs, const int* __restrict__ rp,
    const unsigned short* __restrict__ Ap, unsigned short* __restrict__ An,
    const unsigned short* __restrict__ ec,
    const float* __restrict__ frameNext, unsigned short* __restrict__ en,
    float* __restrict__ M2, int maxSlot, int useSlot)
{
    __shared__ unsigned short tile[64 * 65];
    __shared__ float part[256];
    __shared__ float rcpA[64];
    int tid = threadIdx.x, bid = blockIdx.x;
    if (bid >= SS) { transpose_exp_t<256>(frameNext, en, bid - SS, tid, tile); return; }
    int lane = tid & 63, wave = tid >> 6;
    if (useSlot >= 0 && wave == 0) {
        const float* Mrow = M2 + useSlot * (16 * 64);
        float m = Mrow[lane];
        #pragma unroll
        for (int g = 1; g < 16; ++g) m = fmaxf(m, Mrow[g * 64 + lane]);
        rcpA[lane] = 1.0f / m;
    }
    int rbeg = rp[bid], rend = rp[bid + 1];
    float acc = 0.f;
    for (int i = rbeg + wave; i < rend; i += 4) {
        ArcT2 a = arcs[i];
        int from = (a.idx & 0xFFFF) >> 3, pdf = a.idx >> 19;
        acc = fmaf(b2f(Ap[(from << 6) + lane]), a.ew * b2f(ec[(pdf << 6) + lane]), acc);
    }
    part[tid] = acc;
    __syncthreads();
    if (wave == 0) {
        float sum = part[lane] + part[64 + lane] + part[128 + lane] + part[192 + lane];
        if (useSlot >= 0) sum *= rcpA[lane];
        An[(bid << 6) + lane] = f2b(sum);
        if (maxSlot >= 0)
            atomicMax((unsigned*)&M2[maxSlot * (16 * 64) + (bid & 15) * 64 + lane],
                      __float_as_uint(sum));
    }
}

__global__ void k_fin(const unsigned short* __restrict__ AT, const float* __restrict__ final_logp,
                      const float* __restrict__ M2, float* __restrict__ out)
{
    __shared__ float red[1024];
    int tid = threadIdx.x;
    int lane = tid & 63, chunk = tid >> 6;
    float psum = 0.f;
    for (int s = chunk; s < SS; s += 16)
        psum += b2f(AT[(s << 6) + lane]) * __expf(final_logp[s]);
    red[tid] = psum;
    __syncthreads();
    if (tid < 64) {
        float sum = 0.f;
        #pragma unroll
        for (int c = 0; c < 16; ++c) sum += red[c * 64 + tid];
        float lg = logf(sum);
        #pragma unroll
        for (int r = 0; r < NSLOT; ++r) {
            const float* Mrow = M2 + r * (16 * 64);
            float m = Mrow[tid];
            #pragma unroll
            for (int g = 1; g < 16; ++g) m = fmaxf(m, Mrow[g * 64 + tid]);
            lg += logf(m);
        }
        #pragma unroll
        for (int off = 32; off > 0; off >>= 1) lg += __shfl_down(lg, off);
        if (tid == 0) out[0] = lg;
    }
}

extern "C" void kernel_launch(void* const* d_in, const int* in_sizes, int n_in,
                              void* d_out, int out_size, void* d_ws, size_t ws_size,
                              hipStream_t stream)
{
    const float* input      = (const float*)d_in[0];
    const float* trans_logw = (const float*)d_in[1];
    const float* init_logp  = (const float*)d_in[2];
    const float* final_logp = (const float*)d_in[3];
    const int*   from_state = (const int*)d_in[4];
    const int*   to_state   = (const int*)d_in[5];
    const int*   pdf_id     = (const int*)d_in[6];
    float* out = (float*)d_out;

    char* ws = (char*)d_ws;
    size_t off = 0;
    auto alloc = [&](size_t bytes) -> char* {
        char* p = ws + off;
        off = (off + bytes + 255) & ~(size_t)255;
        return p;
    };
    ArcT2* arcs  = (ArcT2*)alloc((size_t)EEPAD * sizeof(ArcT2));
    int* rp      = (int*)alloc((size_t)(SS + 1) * 4);
    int* cur     = (int*)alloc((size_t)SS * 4);
    int* counts  = (int*)alloc((size_t)SS * 4);
    int* split   = (int*)alloc((size_t)(GB + 1) * 4);
    int* sordg   = (int*)alloc((size_t)GB * NSTMAX * 4);
    unsigned long long* A_all = (unsigned long long*)alloc((size_t)NG * 2 * ASTRD * 8);
    float* partial  = (float*)alloc((size_t)NG * 4 * 4);
    unsigned* flags = (unsigned*)alloc((size_t)2 * NBLK * FLGSTR * 4);
    unsigned* xcdbuf = (unsigned*)alloc((size_t)NBLK * 4);
    // fallback buffers
    unsigned short* A0  = (unsigned short*)alloc((size_t)SS * BB * 2);
    unsigned short* A1  = (unsigned short*)alloc((size_t)SS * BB * 2);
    unsigned short* EX0 = (unsigned short*)alloc((size_t)DD * BB * 2);
    unsigned short* EX1 = (unsigned short*)alloc((size_t)DD * BB * 2);
    float* M2    = (float*)alloc((size_t)NSLOT * 16 * 64 * 4);
    (void)ws_size; (void)in_sizes; (void)n_in; (void)out_size;

    k_init0<<<64, 256, 0, stream>>>(counts, flags, partial);
    k_zeroarcs<<<(EEPAD + 255) / 256, 256, 0, stream>>>(arcs);
    k_hist<<<(EE + 255) / 256, 256, 0, stream>>>(to_state, counts);
    k_scan<<<1, 1024, 0, stream>>>(counts, rp, cur);
    k_split<<<1, 32, 0, stream>>>(rp, split);
    k_sortst<<<GB, 256, 0, stream>>>(rp, split, sordg);
    k_scatter<<<(EE + 255) / 256, 256, 0, stream>>>(from_state, to_state, pdf_id,
                                                    trans_logw, cur, arcs);
    hipMemsetAsync(d_out, 0, sizeof(float), stream);

    hipFuncSetAttribute((const void*)k_coop, hipFuncAttributeMaxDynamicSharedMemorySize,
                        DYNLDS);
    int nb = 0;
    hipOccupancyMaxActiveBlocksPerMultiprocessor(&nb, (const void*)k_coop, NT, DYNLDS);
    if (nb >= 1) {
        void* kp[12] = {
            (void*)&arcs, (void*)&rp, (void*)&split, (void*)&sordg, (void*)&input,
            (void*)&init_logp, (void*)&final_logp, (void*)&partial, (void*)&A_all,
            (void*)&flags, (void*)&xcdbuf, (void*)&out
        };
        hipError_t e = hipLaunchCooperativeKernel((const void*)k_coop, dim3(NBLK), dim3(NT),
                                                  kp, DYNLDS, stream);
        if (e == hipSuccess) return;
    }

    // Fallback: per-step kernels (bf16 state), known-passing structure.
    k_initA<<<(SS * BB + 255) / 256, 256, 0, stream>>>(init_logp, A0, M2);
    k_transpose0<<<NEXB, 256, 0, stream>>>(input, EX0);
    unsigned short* A[2]  = {A0, A1};
    unsigned short* EX[2] = {EX0, EX1};
    for (int k = 0; k < TT; ++k) {
        int kn = k + 1;
        int useSlot = (k > 0 && (k % RESC) == 0) ? (k / RESC - 1) : -1;
        int maxSlot = (kn < TT && (kn % RESC) == 0) ? (kn / RESC - 1) : -1;
        int grid = SS + ((kn < TT) ? NEXB : 0);
        const float* fnext = (kn < TT) ? (input + (size_t)kn * BB * DD) : nullptr;
        k_step<<<grid, 256, 0, stream>>>(arcs, rp, A[k & 1], A[kn & 1], EX[k & 1],
                                         fnext, EX[kn & 1], M2, maxSlot, useSlot);
    }
    k_fin<<<1, 1024, 0, stream>>>(A[TT & 1], final_logp, M2, out);
}